// Round 11
// baseline (198.295 us; speedup 1.0000x reference)
//
#include <hip/hip_runtime.h>
#include <math.h>

// Problem constants (fixed by the reference)
constexpr int NN  = 4096;   // instances
constexpr int PP  = 2048;   // phrases
constexpr int EE  = 65536;  // edges
constexpr int DD  = 1024;   // feature dim
constexpr int OUTF = 128;   // gate MLP out dim
constexpr int G4  = 512;    // 4 gates * 128

typedef __attribute__((ext_vector_type(8))) short short8v;
typedef __attribute__((ext_vector_type(4))) float f32x4;

__device__ __forceinline__ float sigmoid_relu(float z) {
    z = fmaxf(z, 0.0f);
    return 1.0f / (1.0f + __expf(-z));
}
__device__ __forceinline__ float b2f(ushort u) {
    return __uint_as_float(((unsigned int)u) << 16);
}
__device__ __forceinline__ ushort f2b(float f) {  // RNE
    unsigned int x = __float_as_uint(f);
    return (ushort)((x + 0x7fffu + ((x >> 16) & 1u)) >> 16);
}
__device__ __forceinline__ unsigned int pack2(float a, float b) {
    return (unsigned int)f2b(a) | ((unsigned int)f2b(b) << 16);
}
__device__ __forceinline__ float lo16(unsigned int u) { return __uint_as_float(u << 16); }
__device__ __forceinline__ float hi16(unsigned int u) { return __uint_as_float(u & 0xffff0000u); }

#define GLD16(gptr, lptr) \
    __builtin_amdgcn_global_load_lds((__attribute__((address_space(1))) const void*)(gptr), \
                                     (__attribute__((address_space(3))) void*)(lptr), 16, 0, 0)
// Counted-vmcnt pipeline primitives (T4): keep just-issued loads in flight.
#define ASM_VMCNT(n) asm volatile("s_waitcnt vmcnt(" #n ")" ::: "memory")
#define BARRIER() do { asm volatile("" ::: "memory"); \
                       __builtin_amdgcn_s_barrier();  \
                       asm volatile("" ::: "memory"); } while (0)

// ---------------------------------------------------------------------------
// Fused prep: counter zeroing, f32->bf16 features, gate-weight pack,
// refine-weight transpose.
constexpr int NCNT    = 2 * (NN + NN + PP);        // 20480 ints (cnt + cur)
constexpr int NB_ZERO = NCNT / 256;                // 80
constexpr int NB_F2B  = (NN + PP) * DD / 4 / 256;  // 6144
constexpr int NB_PACK = G4 * DD / 256;             // 2048
constexpr int NB_WT   = 4 * (DD / 64) * (DD / 64); // 1024

__global__ __launch_bounds__(256) void prep_kernel(
        int* __restrict__ cntBlock,
        const float* __restrict__ instF, const float* __restrict__ phraF,
        ushort* __restrict__ instB, ushort* __restrict__ phraB,
        const float* __restrict__ psW, const float* __restrict__ poW,
        const float* __restrict__ opW, const float* __restrict__ spW,
        const float* __restrict__ psB, const float* __restrict__ poB,
        const float* __restrict__ opB, const float* __restrict__ spB,
        ushort* __restrict__ WiT, ushort* __restrict__ WpT,
        float* __restrict__ biascat,
        const float* __restrict__ W0, const float* __restrict__ W1,
        const float* __restrict__ W2, const float* __restrict__ W3,
        ushort* __restrict__ T0, ushort* __restrict__ T1,
        ushort* __restrict__ T2, ushort* __restrict__ T3) {
    __shared__ float tile[64][65];
    int b = blockIdx.x, t = threadIdx.x;
    if (b < NB_ZERO) {
        cntBlock[b * 256 + t] = 0;
        return;
    }
    b -= NB_ZERO;
    if (b < NB_F2B) {
        int i = b * 256 + t;
        constexpr int na4 = NN * DD / 4;
        if (i < na4) {
            float4 v = ((const float4*)instF)[i];
            ushort4 u; u.x = f2b(v.x); u.y = f2b(v.y); u.z = f2b(v.z); u.w = f2b(v.w);
            ((ushort4*)instB)[i] = u;
        } else {
            int j = i - na4;
            float4 v = ((const float4*)phraF)[j];
            ushort4 u; u.x = f2b(v.x); u.y = f2b(v.y); u.z = f2b(v.z); u.w = f2b(v.w);
            ((ushort4*)phraB)[j] = u;
        }
        return;
    }
    b -= NB_F2B;
    if (b < NB_PACK) {
        int idx = b * 256 + t;
        int n = idx >> 10, k = idx & 1023;
        int g = n >> 7, j = n & 127;
        float wi, wp;
        if (g == 0)      { wi = psW[(size_t)(DD + k) * OUTF + j]; wp = psW[(size_t)k * OUTF + j]; }
        else if (g == 1) { wi = poW[(size_t)(DD + k) * OUTF + j]; wp = poW[(size_t)k * OUTF + j]; }
        else if (g == 2) { wi = opW[(size_t)k * OUTF + j];        wp = opW[(size_t)(DD + k) * OUTF + j]; }
        else             { wi = spW[(size_t)k * OUTF + j];        wp = spW[(size_t)(DD + k) * OUTF + j]; }
        WiT[idx] = f2b(wi);
        WpT[idx] = f2b(wp);
        if (idx < G4) {
            int gg = idx >> 7, jj = idx & 127;
            biascat[idx] = (gg == 0) ? psB[jj] : (gg == 1) ? poB[jj]
                         : (gg == 2) ? opB[jj] : spB[jj];
        }
        return;
    }
    b -= NB_PACK;
    int z = b >> 8, rest = b & 255;
    const float* W = (z == 0) ? W0 : (z == 1) ? W1 : (z == 2) ? W2 : W3;
    ushort*      T = (z == 0) ? T0 : (z == 1) ? T1 : (z == 2) ? T2 : T3;
    int k0 = (rest & 15) * 64, n0 = (rest >> 4) * 64;
    int tx = t & 63, ty = t >> 6;
    #pragma unroll
    for (int i = 0; i < 64; i += 4)
        tile[ty + i][tx] = W[(size_t)(k0 + ty + i) * DD + n0 + tx];
    __syncthreads();
    #pragma unroll
    for (int i = 0; i < 64; i += 4)
        T[(size_t)(n0 + ty + i) * DD + k0 + tx] = f2b(tile[tx][ty + i]);
}

// ---------------------------------------------------------------------------
// MFMA GEMM building blocks. A-tile 128 rows; B-tile BROWS rows. BK=64,
// XOR-swizzled linear LDS (rule 21).
template<int BROWS>
__device__ __forceinline__ void stage_tiles(const ushort* __restrict__ A,
                                            const ushort* __restrict__ BT,
                                            int bm, int bn, int k0,
                                            ushort* Asl, ushort* Bsl, int t) {
    #pragma unroll
    for (int r = 0; r < 4; r++) {
        int ch = r * 256 + t;
        int row = ch >> 3;
        int sw = ((ch & 7) ^ (row & 7)) << 3;
        GLD16(A + (size_t)(bm + row) * DD + k0 + sw, &Asl[ch * 8]);
    }
    #pragma unroll
    for (int r = 0; r < BROWS / 32; r++) {
        int ch = r * 256 + t;
        int row = ch >> 3;
        int sw = ((ch & 7) ^ (row & 7)) << 3;
        GLD16(BT + (size_t)(bn + row) * DD + k0 + sw, &Bsl[ch * 8]);
    }
}

template<int NACC>
__device__ __forceinline__ void compute_tiles(const ushort* Asl, const ushort* Bsl,
                                              f32x4 (&acc)[4][NACC],
                                              int wr, int wc, int lr, int lk) {
    #pragma unroll
    for (int kk = 0; kk < 2; kk++) {
        int ch16 = kk * 4 + lk;
        short8v a[4], b[NACC];
        #pragma unroll
        for (int m = 0; m < 4; m++) {
            int ra = wr + m * 16 + lr;
            a[m] = *(const short8v*)&Asl[ra * 64 + ((ch16 ^ (ra & 7)) << 3)];
        }
        #pragma unroll
        for (int n = 0; n < NACC; n++) {
            int rb = wc + n * 16 + lr;
            b[n] = *(const short8v*)&Bsl[rb * 64 + ((ch16 ^ (rb & 7)) << 3)];
        }
        #pragma unroll
        for (int m = 0; m < 4; m++)
            #pragma unroll
            for (int n = 0; n < NACC; n++)
                acc[m][n] = __builtin_amdgcn_mfma_f32_16x16x32_bf16(a[m], b[n], acc[m][n], 0, 0, 0);
    }
}

// ---------------------------------------------------------------------------
// Gate tables, 128x64 tile. R11: 3-buffer, ONE barrier per step, counted
// vmcnt(6).  Order {vmcnt; barrier; compute(s); stage(s+2)} is race-free:
// stage(s+2) writes buf[(s+2)%3] = buf[(s-1)%3], and the barrier at the top
// of step s guarantees every wave finished compute(s-1).
__global__ __launch_bounds__(256) void mfma_tables_kernel(
        const ushort* __restrict__ instB, const ushort* __restrict__ WiT,
        const ushort* __restrict__ phraB, const ushort* __restrict__ WpT,
        const float* __restrict__ biascat,
        ushort* __restrict__ TiB, ushort* __restrict__ TpB) {
    __shared__ ushort Asl[3][128 * 64];
    __shared__ ushort Bsl[3][64 * 64];
    int bx = blockIdx.x;
    const ushort *A, *BT; ushort* C; const float* bias;
    if (bx < NN / 128) { A = instB; BT = WiT; C = TiB; bias = nullptr; }
    else { bx -= NN / 128; A = phraB; BT = WpT; C = TpB; bias = biascat; }
    int bm = bx * 128, bn = blockIdx.y * 64;
    int t = threadIdx.x;
    const int lane = t & 63, w = t >> 6;
    const int wr = (w >> 1) * 64, wc = (w & 1) * 32;
    const int lr = lane & 15, lk = lane >> 4;
    f32x4 acc[4][2] = {};

    stage_tiles<64>(A, BT, bm, bn, 0, Asl[0], Bsl[0], t);
    stage_tiles<64>(A, BT, bm, bn, 64, Asl[1], Bsl[1], t);
    for (int s = 0; s < 16; s++) {
        if (s == 15) { ASM_VMCNT(0); } else { ASM_VMCNT(6); }
        BARRIER();
        compute_tiles<2>(Asl[s % 3], Bsl[s % 3], acc, wr, wc, lr, lk);
        if (s + 2 < 16)
            stage_tiles<64>(A, BT, bm, bn, (s + 2) * 64, Asl[(s + 2) % 3], Bsl[(s + 2) % 3], t);
    }
    #pragma unroll
    for (int m = 0; m < 4; m++) {
        int row = bm + wr + m * 16 + lk * 4;
        #pragma unroll
        for (int n = 0; n < 2; n++) {
            int col = bn + wc + n * 16 + lr;
            float bv = bias ? bias[col] : 0.f;
            #pragma unroll
            for (int r = 0; r < 4; r++)
                C[(size_t)(row + r) * G4 + col] = f2b(acc[m][n][r] + bv);
        }
    }
}

// ---------------------------------------------------------------------------
// Fused refine: out = msg + relu(msg@W1+b1) + relu(feat@W2+b2).
// 128x64 tile (768 blocks), 32 virtual K-steps, 3-buffer single-barrier
// counted-vmcnt pipeline (same proof as tables).
__global__ __launch_bounds__(256) void mfma_refine_kernel(
        const ushort* __restrict__ imsgB, const ushort* __restrict__ instB,
        const ushort* __restrict__ iw1T, const ushort* __restrict__ iw2T,
        const float* __restrict__ ib1, const float* __restrict__ ib2,
        float* __restrict__ iout,
        const ushort* __restrict__ pmsgB, const ushort* __restrict__ phraB,
        const ushort* __restrict__ pw1T, const ushort* __restrict__ pw2T,
        const float* __restrict__ pb1, const float* __restrict__ pb2,
        float* __restrict__ pout) {
    __shared__ ushort Asl[3][128 * 64];
    __shared__ ushort Bsl[3][64 * 64];
    int bx = blockIdx.x;
    const ushort *Am, *Af, *W1, *W2; const float *b1, *b2; float* out;
    if (bx < NN / 128) {
        Am = imsgB; Af = instB; W1 = iw1T; W2 = iw2T; b1 = ib1; b2 = ib2; out = iout;
    } else {
        bx -= NN / 128;
        Am = pmsgB; Af = phraB; W1 = pw1T; W2 = pw2T; b1 = pb1; b2 = pb2; out = pout;
    }
    int bm = bx * 128, bn = blockIdx.y * 64;
    int t = threadIdx.x;
    const int lane = t & 63, w = t >> 6;
    const int wr = (w >> 1) * 64, wc = (w & 1) * 32;
    const int lr = lane & 15, lk = lane >> 4;
    f32x4 acc1[4][2] = {};
    f32x4 acc2[4][2] = {};

    auto stageStep = [&](int s) {
        if (s < 16)      stage_tiles<64>(Am, W1, bm, bn, s * 64,
                                         Asl[s % 3], Bsl[s % 3], t);
        else if (s < 32) stage_tiles<64>(Af, W2, bm, bn, (s - 16) * 64,
                                         Asl[s % 3], Bsl[s % 3], t);
    };
    stageStep(0);
    stageStep(1);
    for (int s = 0; s < 32; s++) {
        if (s == 31) { ASM_VMCNT(0); } else { ASM_VMCNT(6); }
        BARRIER();
        if (s < 16) compute_tiles<2>(Asl[s % 3], Bsl[s % 3], acc1, wr, wc, lr, lk);
        else        compute_tiles<2>(Asl[s % 3], Bsl[s % 3], acc2, wr, wc, lr, lk);
        stageStep(s + 2);
    }

    #pragma unroll
    for (int m = 0; m < 4; m++) {
        int row = bm + wr + m * 16 + lk * 4;
        #pragma unroll
        for (int n = 0; n < 2; n++) {
            int col = bn + wc + n * 16 + lr;
            float vb1 = b1[col], vb2 = b2[col];
            #pragma unroll
            for (int r = 0; r < 4; r++) {
                float v = b2f(Am[(size_t)(row + r) * DD + col])
                        + fmaxf(acc1[m][n][r] + vb1, 0.f)
                        + fmaxf(acc2[m][n][r] + vb2, 0.f);
                out[(size_t)(row + r) * DD + col] = v;
            }
        }
    }
}

// ---------------------------------------------------------------------------
// Counting sort: histogram + scan + scatter (positions for gate writes).
__global__ void hist_kernel(const int* __restrict__ s_idx, const int* __restrict__ o_idx,
                            const int* __restrict__ c_idx,
                            int* cntS, int* cntO, int* cntC) {
    int e = blockIdx.x * blockDim.x + threadIdx.x;
    if (e >= EE) return;
    atomicAdd(&cntS[s_idx[e]], 1);
    atomicAdd(&cntO[o_idx[e]], 1);
    atomicAdd(&cntC[c_idx[e]], 1);
}

__global__ __launch_bounds__(1024) void scan3_kernel(
        const int* __restrict__ cntS, const int* __restrict__ cntO,
        const int* __restrict__ cntC,
        int* __restrict__ startS, int* __restrict__ startO, int* __restrict__ startC) {
    const int* cnt; int* start; int n;
    if (blockIdx.x == 0)      { cnt = cntS; start = startS; n = NN; }
    else if (blockIdx.x == 1) { cnt = cntO; start = startO; n = NN; }
    else                      { cnt = cntC; start = startC; n = PP; }
    __shared__ int sh[1024];
    int t = threadIdx.x;
    int per = n >> 10;
    int base = t * per;
    int s = 0;
    for (int i = 0; i < per; i++) s += cnt[base + i];
    sh[t] = s;
    __syncthreads();
    for (int off = 1; off < 1024; off <<= 1) {
        int v = (t >= off) ? sh[t - off] : 0;
        __syncthreads();
        sh[t] += v;
        __syncthreads();
    }
    int ex = (t == 0) ? 0 : sh[t - 1];
    for (int i = 0; i < per; i++) { start[base + i] = ex; ex += cnt[base + i]; }
    if (t == 1023) start[n] = ex;
}

__global__ void scatter_kernel(const int* __restrict__ s_idx, const int* __restrict__ o_idx,
                               const int* __restrict__ c_idx,
                               const int* __restrict__ startS, const int* __restrict__ startO,
                               const int* __restrict__ startC,
                               int* curS, int* curO, int* curC,
                               int* posS, int* posO, int* posC) {
    int e = blockIdx.x * blockDim.x + threadIdx.x;
    if (e >= EE) return;
    posS[e] = startS[s_idx[e]] + atomicAdd(&curS[s_idx[e]], 1);
    posO[e] = startO[o_idx[e]] + atomicAdd(&curO[o_idx[e]], 1);
    posC[e] = startC[c_idx[e]] + atomicAdd(&curC[c_idx[e]], 1);
}

// ---------------------------------------------------------------------------
// Gates, XCD-quartered: one wave per (edge, gate).  bid&7 -> XCD, q = xcd>>1;
// quarter q reads only gate-q's 128 cols (Ti slice 1 MB + Tp slice 0.5 MB =
// L2-resident per XCD pair, same pinning that cut seg's FETCH 106->17.5 MB).
// q0: p_s (tpc,tis)->pkS; q1: p_o (tpc,tio)->pkO; q2: o_p (tpc,tio)->pkC.xyz;
// q3: s_p (tpc,tis)->pkC.w.
__global__ __launch_bounds__(256) void gate_kernel(
        const int* __restrict__ s_idx, const int* __restrict__ o_idx,
        const int* __restrict__ c_idx,
        const int* __restrict__ posS, const int* __restrict__ posO,
        const int* __restrict__ posC,
        const ushort* __restrict__ Ti, const ushort* __restrict__ Tp,
        int2* __restrict__ pkS, int2* __restrict__ pkO, int4* __restrict__ pkC) {
    int bid = blockIdx.x;
    int x = bid & 7;
    int q = x >> 1;
    int subB = ((bid >> 3) << 1) + (x & 1);      // 0..16383
    int w = threadIdx.x >> 6, lane = threadIdx.x & 63;
    int e = subB * 4 + w;
    int c = c_idx[e];
    int partner = (q == 0 || q == 3) ? s_idx[e] : o_idx[e];
    const unsigned int* tpc = (const unsigned int*)(Tp + (size_t)c * G4) + q * 64;
    const unsigned int* tix = (const unsigned int*)(Ti + (size_t)partner * G4) + q * 64;
    unsigned int a = tpc[lane], bb = tix[lane];
    float lo = __uint_as_float(a << 16) + __uint_as_float(bb << 16);
    float hi = __uint_as_float(a & 0xffff0000u) + __uint_as_float(bb & 0xffff0000u);
    float s = sigmoid_relu(lo) + sigmoid_relu(hi);
    #pragma unroll
    for (int off = 32; off; off >>= 1) s += __shfl_xor(s, off);
    if (lane == 0) {
        float g = s * (1.0f / 128.0f);
        if (q == 0) {
            pkS[posS[e]] = make_int2(c, __float_as_int(g));
        } else if (q == 1) {
            pkO[posO[e]] = make_int2(c, __float_as_int(g));
        } else if (q == 2) {
            int* p = (int*)&pkC[posC[e]];
            *(int2*)p = make_int2(o_idx[e], s_idx[e]);
            p[2] = __float_as_int(g);
        } else {
            ((int*)&pkC[posC[e]])[3] = __float_as_int(g);
        }
    }
}

// ---------------------------------------------------------------------------
// Segment means, D-quartered + XCD-pinned, shfl-broadcast pk, 2 edges per
// wave-step (unchanged from R10).
__device__ __forceinline__ void acc8(float* a, uint4 v, float g) {
    a[0] += g * lo16(v.x); a[1] += g * hi16(v.x);
    a[2] += g * lo16(v.y); a[3] += g * hi16(v.y);
    a[4] += g * lo16(v.z); a[5] += g * hi16(v.z);
    a[6] += g * lo16(v.w); a[7] += g * hi16(v.w);
}

__global__ __launch_bounds__(256) void seg_kernel(
        const ushort* __restrict__ phraB, const ushort* __restrict__ instB,
        const int2* __restrict__ pkS, const int* __restrict__ startS,
        const int2* __restrict__ pkO, const int* __restrict__ startO,
        const int4* __restrict__ pkC, const int* __restrict__ startC,
        ushort* __restrict__ imsgB, ushort* __restrict__ pmsgB) {
    __shared__ float lds[4][32 * 9];
    int bid = blockIdx.x;
    int x = bid & 7;
    int q = x >> 1;
    int sub = ((bid >> 3) << 1) + (x & 1);
    int qoff = q * 256;
    int w = threadIdx.x >> 6, lane = threadIdx.x & 63;
    int half = lane >> 5, l32 = lane & 31;
    float a[8];
    #pragma unroll
    for (int k = 0; k < 8; k++) a[k] = 0.f;
    bool instSide = sub < NN / 2;
    int lenScale;
    ushort* msgB;
    int base2;
    if (instSide) {
        int node = sub * 2 + (w >> 1);
        const int2* pk_list = (w & 1) ? pkO : pkS;
        const int*  start   = (w & 1) ? startO : startS;
        int b = start[node], e = start[node + 1];
        lenScale = e - b;
        for (int base = b; base < e; base += 64) {
            int n = min(64, e - base);
            int2 pkv = pk_list[base + min(lane, n - 1)];   // one coalesced load
            int   c0 = __shfl(pkv.x, 0);
            int   c1 = __shfl(pkv.x, 1 < n ? 1 : 0);
            float g0 = __int_as_float(__shfl(pkv.y, 0));
            float g1 = (1 < n) ? __int_as_float(__shfl(pkv.y, 1)) : 0.f;
            int   myc = half ? c1 : c0;
            float myg = half ? g1 : g0;
            uint4 v = *(const uint4*)(phraB + (size_t)myc * DD + qoff + l32 * 8);
            for (int j = 2; j < n; j += 2) {
                int   d0 = __shfl(pkv.x, j);
                int   d1 = __shfl(pkv.x, j + 1 < n ? j + 1 : j);
                float h0 = __int_as_float(__shfl(pkv.y, j));
                float h1 = (j + 1 < n) ? __int_as_float(__shfl(pkv.y, j + 1)) : 0.f;
                int   nc = half ? d1 : d0;
                float ng = half ? h1 : h0;
                uint4 vn = *(const uint4*)(phraB + (size_t)nc * DD + qoff + l32 * 8);
                acc8(a, v, myg);
                v = vn; myg = ng;
            }
            acc8(a, v, myg);
        }
        msgB = imsgB; base2 = sub * 2;
    } else {
        int pbx = sub - NN / 2;
        int p = pbx * 2 + (w >> 1);
        int cb = startC[p], ce = startC[p + 1];
        lenScale = ce - cb;
        int mid = cb + ((ce - cb) >> 1);
        int mb = (w & 1) ? mid : cb;       // contiguous halves (coalesced chunks)
        int me = (w & 1) ? ce : mid;
        for (int base = mb; base < me; base += 64) {
            int n = min(64, me - base);
            int4 pkv = pkC[base + min(lane, n - 1)];
            int   o0  = __shfl(pkv.x, 0);
            int   o1  = __shfl(pkv.x, 1 < n ? 1 : 0);
            int   si0 = __shfl(pkv.y, 0);
            int   si1 = __shfl(pkv.y, 1 < n ? 1 : 0);
            float go0 = __int_as_float(__shfl(pkv.z, 0));
            float go1 = (1 < n) ? __int_as_float(__shfl(pkv.z, 1)) : 0.f;
            float gs0 = __int_as_float(__shfl(pkv.w, 0));
            float gs1 = (1 < n) ? __int_as_float(__shfl(pkv.w, 1)) : 0.f;
            int   myo = half ? o1 : o0,  mys = half ? si1 : si0;
            float mygo = half ? go1 : go0, mygs = half ? gs1 : gs0;
            uint4 vo = *(const uint4*)(instB + (size_t)myo * DD + qoff + l32 * 8);
            uint4 vs = *(const uint4*)(instB + (size_t)mys * DD + qoff + l32 * 8);
            for (int j = 2; j < n; j += 2) {
                int   no0  = __shfl(pkv.x, j);
                int   no1  = __shfl(pkv.x, j + 1 < n ? j + 1 : j);
                int   ns0  = __shfl(pkv.y, j);
                int   ns1  = __shfl(pkv.y, j + 1 < n ? j + 1 : j);
                float ngo0 = __int_as_float(__shfl(pkv.z, j));
                float ngo1 = (j + 1 < n) ? __int_as_float(__shfl(pkv.z, j + 1)) : 0.f;
                float ngs0 = __int_as_float(__shfl(pkv.w, j));
                float ngs1 = (j + 1 < n) ? __int_as_float(__shfl(pkv.w, j + 1)) : 0.f;
                int   nno = half ? no1 : no0,  nns = half ? ns1 : ns0;
                float ngo = half ? ngo1 : ngo0, ngs = half ? ngs1 : ngs0;
                uint4 vno = *(const uint4*)(instB + (size_t)nno * DD + qoff + l32 * 8);
                uint4 vns = *(const uint4*)(instB + (size_t)nns * DD + qoff + l32 * 8);
                acc8(a, vo, mygo);
                acc8(a, vs, mygs);
                vo = vno; vs = vns; mygo = ngo; mygs = ngs;
            }
            acc8(a, vo, mygo);
            acc8(a, vs, mygs);
        }
        msgB = pmsgB; base2 = pbx * 2;
    }
    #pragma unroll
    for (int k = 0; k < 8; k++) a[k] += __shfl_xor(a[k], 32);
    float scale = 0.5f / (float)max(lenScale, 1);
    if (half == 0) {
        #pragma unroll
        for (int k = 0; k < 8; k++) lds[w][l32 * 9 + k] = a[k] * scale;
    }
    __syncthreads();
    if (threadIdx.x < 64) {
        int nodeSel = threadIdx.x >> 5;
        int l = threadIdx.x & 31;
        int w0 = nodeSel * 2;
        float s0 = lds[w0][l * 9 + 0] + lds[w0 + 1][l * 9 + 0];
        float s1 = lds[w0][l * 9 + 1] + lds[w0 + 1][l * 9 + 1];
        float s2 = lds[w0][l * 9 + 2] + lds[w0 + 1][l * 9 + 2];
        float s3 = lds[w0][l * 9 + 3] + lds[w0 + 1][l * 9 + 3];
        float s4 = lds[w0][l * 9 + 4] + lds[w0 + 1][l * 9 + 4];
        float s5 = lds[w0][l * 9 + 5] + lds[w0 + 1][l * 9 + 5];
        float s6 = lds[w0][l * 9 + 6] + lds[w0 + 1][l * 9 + 6];
        float s7 = lds[w0][l * 9 + 7] + lds[w0 + 1][l * 9 + 7];
        uint4 o;
        o.x = pack2(s0, s1);
        o.y = pack2(s2, s3);
        o.z = pack2(s4, s5);
        o.w = pack2(s6, s7);
        *(uint4*)&msgB[(size_t)(base2 + nodeSel) * DD + qoff + l * 8] = o;
    }
}

// ---------------------------------------------------------------------------
extern "C" void kernel_launch(void* const* d_in, const int* in_sizes, int n_in,
                              void* d_out, int out_size, void* d_ws, size_t ws_size,
                              hipStream_t stream) {
    (void)in_sizes; (void)n_in; (void)out_size; (void)ws_size;
    const float* inst_feat = (const float*)d_in[0];
    const float* phra_feat = (const float*)d_in[1];
    const int*   conn      = (const int*)d_in[2];
    const int*   clu       = (const int*)d_in[3];
    const float* psW = (const float*)d_in[4];  const float* psB = (const float*)d_in[5];
    const float* poW = (const float*)d_in[6];  const float* poB = (const float*)d_in[7];
    const float* opW = (const float*)d_in[8];  const float* opB = (const float*)d_in[9];
    const float* spW = (const float*)d_in[10]; const float* spB = (const float*)d_in[11];
    const float* iw1W = (const float*)d_in[12]; const float* iw1B = (const float*)d_in[13];
    const float* iw2W = (const float*)d_in[14]; const float* iw2B = (const float*)d_in[15];
    const float* pw1W = (const float*)d_in[16]; const float* pw1B = (const float*)d_in[17];
    const float* pw2W = (const float*)d_in[18]; const float* pw2B = (const float*)d_in[19];
    const int* s_idx = conn;
    const int* o_idx = conn + EE;

    char* ws = (char*)d_ws;
    size_t off = 0;
    auto alloc = [&](size_t bytes) {
        char* p = ws + off;
        off += (bytes + 255) & ~(size_t)255;
        return p;
    };
    ushort* instB = (ushort*)alloc((size_t)NN * DD * 2);
    ushort* phraB = (ushort*)alloc((size_t)PP * DD * 2);
    ushort* WiT   = (ushort*)alloc((size_t)G4 * DD * 2);
    ushort* WpT   = (ushort*)alloc((size_t)G4 * DD * 2);
    ushort* iw1T  = (ushort*)alloc((size_t)DD * DD * 2);
    ushort* iw2T  = (ushort*)alloc((size_t)DD * DD * 2);
    ushort* pw1T  = (ushort*)alloc((size_t)DD * DD * 2);
    ushort* pw2T  = (ushort*)alloc((size_t)DD * DD * 2);
    float* biascat = (float*)alloc(G4 * 4);
    ushort* TiB   = (ushort*)alloc((size_t)NN * G4 * 2);
    ushort* TpB   = (ushort*)alloc((size_t)PP * G4 * 2);
    int* cntBlock = (int*)alloc((size_t)NCNT * 4);
    int* cntS = cntBlock;      int* cntO = cntS + NN;  int* cntC = cntO + NN;
    int* curS = cntC + PP;     int* curO = curS + NN;  int* curC = curO + NN;
    int* startS = (int*)alloc((NN + 1) * 4);
    int* startO = (int*)alloc((NN + 1) * 4);
    int* startC = (int*)alloc((PP + 1) * 4);
    int* posS   = (int*)alloc((size_t)EE * 4);
    int* posO   = (int*)alloc((size_t)EE * 4);
    int* posC   = (int*)alloc((size_t)EE * 4);
    int2* pkS   = (int2*)alloc((size_t)EE * 8);
    int2* pkO   = (int2*)alloc((size_t)EE * 8);
    int4* pkC   = (int4*)alloc((size_t)EE * 16);
    ushort* imsgB = (ushort*)alloc((size_t)NN * DD * 2);
    ushort* pmsgB = (ushort*)alloc((size_t)PP * DD * 2);

    float* inst_out = (float*)d_out;
    float* phra_out = inst_out + (size_t)NN * DD;

    // Fused prep: counter zeroing + bf16 casts + weight pack/transpose
    prep_kernel<<<NB_ZERO + NB_F2B + NB_PACK + NB_WT, 256, 0, stream>>>(
        cntBlock, inst_feat, phra_feat, instB, phraB,
        psW, poW, opW, spW, psB, poB, opB, spB, WiT, WpT, biascat,
        iw1W, iw2W, pw1W, pw2W, iw1T, iw2T, pw1T, pw2T);

    // CSR build
    hist_kernel<<<EE / 256, 256, 0, stream>>>(s_idx, o_idx, clu, cntS, cntO, cntC);
    scan3_kernel<<<3, 1024, 0, stream>>>(cntS, cntO, cntC, startS, startO, startC);
    scatter_kernel<<<EE / 256, 256, 0, stream>>>(s_idx, o_idx, clu, startS, startO, startC,
                                                 curS, curO, curC, posS, posO, posC);

    // Gate tables (bf16 MFMA, bias folded into Tp; 3-buffer pipeline)
    mfma_tables_kernel<<<dim3((NN + PP) / 128, G4 / 64), 256, 0, stream>>>(
        instB, WiT, phraB, WpT, biascat, TiB, TpB);

    // Gates -> packed CSR entries (XCD-quartered: one wave per edge-gate)
    gate_kernel<<<EE, 256, 0, stream>>>(
        s_idx, o_idx, clu, posS, posO, posC, TiB, TpB, pkS, pkO, pkC);

    // Segment means (quartered, XCD-pinned, 2-edge-per-step uint4 pipeline)
    seg_kernel<<<(NN / 2 + PP / 2) * 4, 256, 0, stream>>>(
        phraB, instB, pkS, startS, pkO, startO, pkC, startC, imsgB, pmsgB);

    // Fused refine (128x64 tiles, 768 blocks, 3-buffer single-barrier pipeline)
    mfma_refine_kernel<<<dim3((NN + PP) / 128, DD / 64), 256, 0, stream>>>(
        imsgB, instB, iw1T, iw2T, iw1B, iw2B, inst_out,
        pmsgB, phraB, pw1T, pw2T, pw1B, pw2B, phra_out);
}

// Round 12
// 159.597 us; speedup vs baseline: 1.2425x; 1.2425x over previous
//
#include <hip/hip_runtime.h>
#include <math.h>

// Problem constants (fixed by the reference)
constexpr int NN  = 4096;   // instances
constexpr int PP  = 2048;   // phrases
constexpr int EE  = 65536;  // edges
constexpr int DD  = 1024;   // feature dim
constexpr int OUTF = 128;   // gate MLP out dim
constexpr int G4  = 512;    // 4 gates * 128

typedef __attribute__((ext_vector_type(8))) short short8v;
typedef __attribute__((ext_vector_type(4))) float f32x4;

__device__ __forceinline__ float sigmoid_relu(float z) {
    z = fmaxf(z, 0.0f);
    return 1.0f / (1.0f + __expf(-z));
}
__device__ __forceinline__ float b2f(ushort u) {
    return __uint_as_float(((unsigned int)u) << 16);
}
__device__ __forceinline__ ushort f2b(float f) {  // RNE
    unsigned int x = __float_as_uint(f);
    return (ushort)((x + 0x7fffu + ((x >> 16) & 1u)) >> 16);
}
__device__ __forceinline__ unsigned int pack2(float a, float b) {
    return (unsigned int)f2b(a) | ((unsigned int)f2b(b) << 16);
}
__device__ __forceinline__ float lo16(unsigned int u) { return __uint_as_float(u << 16); }
__device__ __forceinline__ float hi16(unsigned int u) { return __uint_as_float(u & 0xffff0000u); }
__device__ __forceinline__ float pairSig(unsigned int a, unsigned int b) {
    return sigmoid_relu(lo16(a) + lo16(b)) + sigmoid_relu(hi16(a) + hi16(b));
}

#define GLD16(gptr, lptr) \
    __builtin_amdgcn_global_load_lds((__attribute__((address_space(1))) const void*)(gptr), \
                                     (__attribute__((address_space(3))) void*)(lptr), 16, 0, 0)
// Counted-vmcnt pipeline primitives (T4): keep just-issued loads in flight.
#define ASM_VMCNT(n) asm volatile("s_waitcnt vmcnt(" #n ")" ::: "memory")
#define BARRIER() do { asm volatile("" ::: "memory"); \
                       __builtin_amdgcn_s_barrier();  \
                       asm volatile("" ::: "memory"); } while (0)

// ---------------------------------------------------------------------------
// Fused prep: counter zeroing, f32->bf16 features, gate-weight pack,
// refine-weight transpose.
constexpr int NCNT    = 2 * (NN + NN + PP);        // 20480 ints (cnt + cur)
constexpr int NB_ZERO = NCNT / 256;                // 80
constexpr int NB_F2B  = (NN + PP) * DD / 4 / 256;  // 6144
constexpr int NB_PACK = G4 * DD / 256;             // 2048
constexpr int NB_WT   = 4 * (DD / 64) * (DD / 64); // 1024

__global__ __launch_bounds__(256) void prep_kernel(
        int* __restrict__ cntBlock,
        const float* __restrict__ instF, const float* __restrict__ phraF,
        ushort* __restrict__ instB, ushort* __restrict__ phraB,
        const float* __restrict__ psW, const float* __restrict__ poW,
        const float* __restrict__ opW, const float* __restrict__ spW,
        const float* __restrict__ psB, const float* __restrict__ poB,
        const float* __restrict__ opB, const float* __restrict__ spB,
        ushort* __restrict__ WiT, ushort* __restrict__ WpT,
        float* __restrict__ biascat,
        const float* __restrict__ W0, const float* __restrict__ W1,
        const float* __restrict__ W2, const float* __restrict__ W3,
        ushort* __restrict__ T0, ushort* __restrict__ T1,
        ushort* __restrict__ T2, ushort* __restrict__ T3) {
    __shared__ float tile[64][65];
    int b = blockIdx.x, t = threadIdx.x;
    if (b < NB_ZERO) {
        cntBlock[b * 256 + t] = 0;
        return;
    }
    b -= NB_ZERO;
    if (b < NB_F2B) {
        int i = b * 256 + t;
        constexpr int na4 = NN * DD / 4;
        if (i < na4) {
            float4 v = ((const float4*)instF)[i];
            ushort4 u; u.x = f2b(v.x); u.y = f2b(v.y); u.z = f2b(v.z); u.w = f2b(v.w);
            ((ushort4*)instB)[i] = u;
        } else {
            int j = i - na4;
            float4 v = ((const float4*)phraF)[j];
            ushort4 u; u.x = f2b(v.x); u.y = f2b(v.y); u.z = f2b(v.z); u.w = f2b(v.w);
            ((ushort4*)phraB)[j] = u;
        }
        return;
    }
    b -= NB_F2B;
    if (b < NB_PACK) {
        int idx = b * 256 + t;
        int n = idx >> 10, k = idx & 1023;
        int g = n >> 7, j = n & 127;
        float wi, wp;
        if (g == 0)      { wi = psW[(size_t)(DD + k) * OUTF + j]; wp = psW[(size_t)k * OUTF + j]; }
        else if (g == 1) { wi = poW[(size_t)(DD + k) * OUTF + j]; wp = poW[(size_t)k * OUTF + j]; }
        else if (g == 2) { wi = opW[(size_t)k * OUTF + j];        wp = opW[(size_t)(DD + k) * OUTF + j]; }
        else             { wi = spW[(size_t)k * OUTF + j];        wp = spW[(size_t)(DD + k) * OUTF + j]; }
        WiT[idx] = f2b(wi);
        WpT[idx] = f2b(wp);
        if (idx < G4) {
            int gg = idx >> 7, jj = idx & 127;
            biascat[idx] = (gg == 0) ? psB[jj] : (gg == 1) ? poB[jj]
                         : (gg == 2) ? opB[jj] : spB[jj];
        }
        return;
    }
    b -= NB_PACK;
    int z = b >> 8, rest = b & 255;
    const float* W = (z == 0) ? W0 : (z == 1) ? W1 : (z == 2) ? W2 : W3;
    ushort*      T = (z == 0) ? T0 : (z == 1) ? T1 : (z == 2) ? T2 : T3;
    int k0 = (rest & 15) * 64, n0 = (rest >> 4) * 64;
    int tx = t & 63, ty = t >> 6;
    #pragma unroll
    for (int i = 0; i < 64; i += 4)
        tile[ty + i][tx] = W[(size_t)(k0 + ty + i) * DD + n0 + tx];
    __syncthreads();
    #pragma unroll
    for (int i = 0; i < 64; i += 4)
        T[(size_t)(n0 + ty + i) * DD + k0 + tx] = f2b(tile[tx][ty + i]);
}

// ---------------------------------------------------------------------------
// MFMA GEMM building blocks (R10 proven). A-tile 128 rows; B-tile BROWS rows.
// BK=64, XOR-swizzled linear LDS (rule 21).
template<int BROWS>
__device__ __forceinline__ void stage_tiles(const ushort* __restrict__ A,
                                            const ushort* __restrict__ BT,
                                            int bm, int bn, int k0,
                                            ushort* Asl, ushort* Bsl, int t) {
    #pragma unroll
    for (int r = 0; r < 4; r++) {
        int ch = r * 256 + t;
        int row = ch >> 3;
        int sw = ((ch & 7) ^ (row & 7)) << 3;
        GLD16(A + (size_t)(bm + row) * DD + k0 + sw, &Asl[ch * 8]);
    }
    #pragma unroll
    for (int r = 0; r < BROWS / 32; r++) {
        int ch = r * 256 + t;
        int row = ch >> 3;
        int sw = ((ch & 7) ^ (row & 7)) << 3;
        GLD16(BT + (size_t)(bn + row) * DD + k0 + sw, &Bsl[ch * 8]);
    }
}

template<int NACC>
__device__ __forceinline__ void compute_tiles(const ushort* Asl, const ushort* Bsl,
                                              f32x4 (&acc)[4][NACC],
                                              int wr, int wc, int lr, int lk) {
    #pragma unroll
    for (int kk = 0; kk < 2; kk++) {
        int ch16 = kk * 4 + lk;
        short8v a[4], b[NACC];
        #pragma unroll
        for (int m = 0; m < 4; m++) {
            int ra = wr + m * 16 + lr;
            a[m] = *(const short8v*)&Asl[ra * 64 + ((ch16 ^ (ra & 7)) << 3)];
        }
        #pragma unroll
        for (int n = 0; n < NACC; n++) {
            int rb = wc + n * 16 + lr;
            b[n] = *(const short8v*)&Bsl[rb * 64 + ((ch16 ^ (rb & 7)) << 3)];
        }
        #pragma unroll
        for (int m = 0; m < 4; m++)
            #pragma unroll
            for (int n = 0; n < NACC; n++)
                acc[m][n] = __builtin_amdgcn_mfma_f32_16x16x32_bf16(a[m], b[n], acc[m][n], 0, 0, 0);
    }
}

// ---------------------------------------------------------------------------
// Gate tables, 128x64 tile, counted-vmcnt 2-buffer pipeline (R10 proven:
// 48 KB LDS -> 3 blocks/CU; R11's 3-buffer at 72 KB dropped to 2 blocks/CU).
__global__ __launch_bounds__(256) void mfma_tables_kernel(
        const ushort* __restrict__ instB, const ushort* __restrict__ WiT,
        const ushort* __restrict__ phraB, const ushort* __restrict__ WpT,
        const float* __restrict__ biascat,
        ushort* __restrict__ TiB, ushort* __restrict__ TpB) {
    __shared__ ushort Asl[2][128 * 64];
    __shared__ ushort Bsl[2][64 * 64];
    int bx = blockIdx.x;
    const ushort *A, *BT; ushort* C; const float* bias;
    if (bx < NN / 128) { A = instB; BT = WiT; C = TiB; bias = nullptr; }
    else { bx -= NN / 128; A = phraB; BT = WpT; C = TpB; bias = biascat; }
    int bm = bx * 128, bn = blockIdx.y * 64;
    int t = threadIdx.x;
    const int lane = t & 63, w = t >> 6;
    const int wr = (w >> 1) * 64, wc = (w & 1) * 32;
    const int lr = lane & 15, lk = lane >> 4;
    f32x4 acc[4][2] = {};

    int cur = 0;
    stage_tiles<64>(A, BT, bm, bn, 0, Asl[0], Bsl[0], t);
    for (int k0 = 0; k0 < DD; k0 += 64) {
        int nxt = cur ^ 1;
        if (k0 + 64 < DD) {
            stage_tiles<64>(A, BT, bm, bn, k0 + 64, Asl[nxt], Bsl[nxt], t);
            ASM_VMCNT(6);
        } else {
            ASM_VMCNT(0);
        }
        BARRIER();
        compute_tiles<2>(Asl[cur], Bsl[cur], acc, wr, wc, lr, lk);
        BARRIER();
        cur = nxt;
    }
    #pragma unroll
    for (int m = 0; m < 4; m++) {
        int row = bm + wr + m * 16 + lk * 4;
        #pragma unroll
        for (int n = 0; n < 2; n++) {
            int col = bn + wc + n * 16 + lr;
            float bv = bias ? bias[col] : 0.f;
            #pragma unroll
            for (int r = 0; r < 4; r++)
                C[(size_t)(row + r) * G4 + col] = f2b(acc[m][n][r] + bv);
        }
    }
}

// ---------------------------------------------------------------------------
// Fused refine: out = msg + relu(msg@W1+b1) + relu(feat@W2+b2).
// 128x64 tile (768 blocks), continuous counted-vmcnt pipeline (R10 proven).
__global__ __launch_bounds__(256) void mfma_refine_kernel(
        const ushort* __restrict__ imsgB, const ushort* __restrict__ instB,
        const ushort* __restrict__ iw1T, const ushort* __restrict__ iw2T,
        const float* __restrict__ ib1, const float* __restrict__ ib2,
        float* __restrict__ iout,
        const ushort* __restrict__ pmsgB, const ushort* __restrict__ phraB,
        const ushort* __restrict__ pw1T, const ushort* __restrict__ pw2T,
        const float* __restrict__ pb1, const float* __restrict__ pb2,
        float* __restrict__ pout) {
    __shared__ ushort Asl[2][128 * 64];
    __shared__ ushort Bsl[2][64 * 64];
    int bx = blockIdx.x;
    const ushort *Am, *Af, *W1, *W2; const float *b1, *b2; float* out;
    if (bx < NN / 128) {
        Am = imsgB; Af = instB; W1 = iw1T; W2 = iw2T; b1 = ib1; b2 = ib2; out = iout;
    } else {
        bx -= NN / 128;
        Am = pmsgB; Af = phraB; W1 = pw1T; W2 = pw2T; b1 = pb1; b2 = pb2; out = pout;
    }
    int bm = bx * 128, bn = blockIdx.y * 64;
    int t = threadIdx.x;
    const int lane = t & 63, w = t >> 6;
    const int wr = (w >> 1) * 64, wc = (w & 1) * 32;
    const int lr = lane & 15, lk = lane >> 4;
    f32x4 acc1[4][2] = {};
    f32x4 acc2[4][2] = {};

    int cur = 0;
    stage_tiles<64>(Am, W1, bm, bn, 0, Asl[0], Bsl[0], t);
    auto run = [&](const ushort* A, const ushort* B, f32x4 (&acc)[4][2],
                   const ushort* An, const ushort* Bn) {
        for (int k0 = 0; k0 < DD; k0 += 64) {
            int nxt = cur ^ 1;
            if (k0 + 64 < DD) {
                stage_tiles<64>(A, B, bm, bn, k0 + 64, Asl[nxt], Bsl[nxt], t);
                ASM_VMCNT(6);
            } else if (An) {
                stage_tiles<64>(An, Bn, bm, bn, 0, Asl[nxt], Bsl[nxt], t);
                ASM_VMCNT(6);
            } else {
                ASM_VMCNT(0);
            }
            BARRIER();
            compute_tiles<2>(Asl[cur], Bsl[cur], acc, wr, wc, lr, lk);
            BARRIER();
            cur = nxt;
        }
    };
    run(Am, W1, acc1, Af, W2);
    run(Af, W2, acc2, nullptr, nullptr);

    #pragma unroll
    for (int m = 0; m < 4; m++) {
        int row = bm + wr + m * 16 + lk * 4;
        #pragma unroll
        for (int n = 0; n < 2; n++) {
            int col = bn + wc + n * 16 + lr;
            float vb1 = b1[col], vb2 = b2[col];
            #pragma unroll
            for (int r = 0; r < 4; r++) {
                float v = b2f(Am[(size_t)(row + r) * DD + col])
                        + fmaxf(acc1[m][n][r] + vb1, 0.f)
                        + fmaxf(acc2[m][n][r] + vb2, 0.f);
                out[(size_t)(row + r) * DD + col] = v;
            }
        }
    }
}

// ---------------------------------------------------------------------------
// Counting sort: histogram + scan (scatter fused into gate_kernel atomics).
__global__ void hist_kernel(const int* __restrict__ s_idx, const int* __restrict__ o_idx,
                            const int* __restrict__ c_idx,
                            int* cntS, int* cntO, int* cntC) {
    int e = blockIdx.x * blockDim.x + threadIdx.x;
    if (e >= EE) return;
    atomicAdd(&cntS[s_idx[e]], 1);
    atomicAdd(&cntO[o_idx[e]], 1);
    atomicAdd(&cntC[c_idx[e]], 1);
}

__global__ __launch_bounds__(1024) void scan3_kernel(
        const int* __restrict__ cntS, const int* __restrict__ cntO,
        const int* __restrict__ cntC,
        int* __restrict__ startS, int* __restrict__ startO, int* __restrict__ startC) {
    const int* cnt; int* start; int n;
    if (blockIdx.x == 0)      { cnt = cntS; start = startS; n = NN; }
    else if (blockIdx.x == 1) { cnt = cntO; start = startO; n = NN; }
    else                      { cnt = cntC; start = startC; n = PP; }
    __shared__ int sh[1024];
    int t = threadIdx.x;
    int per = n >> 10;
    int base = t * per;
    int s = 0;
    for (int i = 0; i < per; i++) s += cnt[base + i];
    sh[t] = s;
    __syncthreads();
    for (int off = 1; off < 1024; off <<= 1) {
        int v = (t >= off) ? sh[t - off] : 0;
        __syncthreads();
        sh[t] += v;
        __syncthreads();
    }
    int ex = (t == 0) ? 0 : sh[t - 1];
    for (int i = 0; i < per; i++) { start[base + i] = ex; ex += cnt[base + i]; }
    if (t == 1023) start[n] = ex;
}

// ---------------------------------------------------------------------------
// Gates, table-HALVED + XCD-pinned (same L2-residency mechanism as seg's
// R8 win).  bid&7 -> XCD; h = xcd>>2 selects gate pair.  Half h's table
// slices: Tp-half 1 MB + two Ti-quarters 2 MB = 3 MB < 4 MB L2.
// h0: gates p_s,p_o -> pkS,pkO (atomics curS/curO).
// h1: gates o_p,s_p -> pkC whole int4 (atomics curC).  No partial writes.
__global__ __launch_bounds__(256) void gate_kernel(
        const int* __restrict__ s_idx, const int* __restrict__ o_idx,
        const int* __restrict__ c_idx,
        const int* __restrict__ startS, const int* __restrict__ startO,
        const int* __restrict__ startC,
        int* __restrict__ curS, int* __restrict__ curO, int* __restrict__ curC,
        const ushort* __restrict__ Ti, const ushort* __restrict__ Tp,
        int2* __restrict__ pkS, int2* __restrict__ pkO, int4* __restrict__ pkC) {
    int bid = blockIdx.x;
    int x = bid & 7;
    int h = x >> 2;                          // gate pair: 0 -> {p_s,p_o}, 1 -> {o_p,s_p}
    int sub = ((bid >> 3) << 2) + (x & 3);   // 0..16383 edge-groups per half
    int w = threadIdx.x >> 6, lane = threadIdx.x & 63;
    int e = sub * 4 + w;
    int c = c_idx[e], s = s_idx[e], o = o_idx[e];
    const unsigned int* tpc = (const unsigned int*)(Tp + (size_t)c * G4);
    const unsigned int* tis = (const unsigned int*)(Ti + (size_t)s * G4);
    const unsigned int* tio = (const unsigned int*)(Ti + (size_t)o * G4);
    float sA, sB;
    if (h == 0) {
        sA = pairSig(tpc[lane],       tis[lane]);        // p_s
        sB = pairSig(tpc[64 + lane],  tio[64 + lane]);   // p_o
    } else {
        sA = pairSig(tpc[128 + lane], tio[128 + lane]);  // o_p
        sB = pairSig(tpc[192 + lane], tis[192 + lane]);  // s_p
    }
    #pragma unroll
    for (int off = 32; off; off >>= 1) {
        sA += __shfl_xor(sA, off);
        sB += __shfl_xor(sB, off);
    }
    if (lane == 0) {
        const float inv = 1.0f / 128.0f;
        if (h == 0) {
            int ps = startS[s] + atomicAdd(&curS[s], 1);
            int po = startO[o] + atomicAdd(&curO[o], 1);
            pkS[ps] = make_int2(c, __float_as_int(sA * inv));
            pkO[po] = make_int2(c, __float_as_int(sB * inv));
        } else {
            int pc = startC[c] + atomicAdd(&curC[c], 1);
            pkC[pc] = make_int4(o, s, __float_as_int(sA * inv), __float_as_int(sB * inv));
        }
    }
}

// ---------------------------------------------------------------------------
// Segment means, D-quartered + XCD-pinned, shfl-broadcast pk, 2 edges per
// wave-step (unchanged from R10, proven 40.3 us).
__device__ __forceinline__ void acc8(float* a, uint4 v, float g) {
    a[0] += g * lo16(v.x); a[1] += g * hi16(v.x);
    a[2] += g * lo16(v.y); a[3] += g * hi16(v.y);
    a[4] += g * lo16(v.z); a[5] += g * hi16(v.z);
    a[6] += g * lo16(v.w); a[7] += g * hi16(v.w);
}

__global__ __launch_bounds__(256) void seg_kernel(
        const ushort* __restrict__ phraB, const ushort* __restrict__ instB,
        const int2* __restrict__ pkS, const int* __restrict__ startS,
        const int2* __restrict__ pkO, const int* __restrict__ startO,
        const int4* __restrict__ pkC, const int* __restrict__ startC,
        ushort* __restrict__ imsgB, ushort* __restrict__ pmsgB) {
    __shared__ float lds[4][32 * 9];
    int bid = blockIdx.x;
    int x = bid & 7;
    int q = x >> 1;
    int sub = ((bid >> 3) << 1) + (x & 1);
    int qoff = q * 256;
    int w = threadIdx.x >> 6, lane = threadIdx.x & 63;
    int half = lane >> 5, l32 = lane & 31;
    float a[8];
    #pragma unroll
    for (int k = 0; k < 8; k++) a[k] = 0.f;
    bool instSide = sub < NN / 2;
    int lenScale;
    ushort* msgB;
    int base2;
    if (instSide) {
        int node = sub * 2 + (w >> 1);
        const int2* pk_list = (w & 1) ? pkO : pkS;
        const int*  start   = (w & 1) ? startO : startS;
        int b = start[node], e = start[node + 1];
        lenScale = e - b;
        for (int base = b; base < e; base += 64) {
            int n = min(64, e - base);
            int2 pkv = pk_list[base + min(lane, n - 1)];   // one coalesced load
            int   c0 = __shfl(pkv.x, 0);
            int   c1 = __shfl(pkv.x, 1 < n ? 1 : 0);
            float g0 = __int_as_float(__shfl(pkv.y, 0));
            float g1 = (1 < n) ? __int_as_float(__shfl(pkv.y, 1)) : 0.f;
            int   myc = half ? c1 : c0;
            float myg = half ? g1 : g0;
            uint4 v = *(const uint4*)(phraB + (size_t)myc * DD + qoff + l32 * 8);
            for (int j = 2; j < n; j += 2) {
                int   d0 = __shfl(pkv.x, j);
                int   d1 = __shfl(pkv.x, j + 1 < n ? j + 1 : j);
                float h0 = __int_as_float(__shfl(pkv.y, j));
                float h1 = (j + 1 < n) ? __int_as_float(__shfl(pkv.y, j + 1)) : 0.f;
                int   nc = half ? d1 : d0;
                float ng = half ? h1 : h0;
                uint4 vn = *(const uint4*)(phraB + (size_t)nc * DD + qoff + l32 * 8);
                acc8(a, v, myg);
                v = vn; myg = ng;
            }
            acc8(a, v, myg);
        }
        msgB = imsgB; base2 = sub * 2;
    } else {
        int pbx = sub - NN / 2;
        int p = pbx * 2 + (w >> 1);
        int cb = startC[p], ce = startC[p + 1];
        lenScale = ce - cb;
        int mid = cb + ((ce - cb) >> 1);
        int mb = (w & 1) ? mid : cb;       // contiguous halves (coalesced chunks)
        int me = (w & 1) ? ce : mid;
        for (int base = mb; base < me; base += 64) {
            int n = min(64, me - base);
            int4 pkv = pkC[base + min(lane, n - 1)];
            int   o0  = __shfl(pkv.x, 0);
            int   o1  = __shfl(pkv.x, 1 < n ? 1 : 0);
            int   si0 = __shfl(pkv.y, 0);
            int   si1 = __shfl(pkv.y, 1 < n ? 1 : 0);
            float go0 = __int_as_float(__shfl(pkv.z, 0));
            float go1 = (1 < n) ? __int_as_float(__shfl(pkv.z, 1)) : 0.f;
            float gs0 = __int_as_float(__shfl(pkv.w, 0));
            float gs1 = (1 < n) ? __int_as_float(__shfl(pkv.w, 1)) : 0.f;
            int   myo = half ? o1 : o0,  mys = half ? si1 : si0;
            float mygo = half ? go1 : go0, mygs = half ? gs1 : gs0;
            uint4 vo = *(const uint4*)(instB + (size_t)myo * DD + qoff + l32 * 8);
            uint4 vs = *(const uint4*)(instB + (size_t)mys * DD + qoff + l32 * 8);
            for (int j = 2; j < n; j += 2) {
                int   no0  = __shfl(pkv.x, j);
                int   no1  = __shfl(pkv.x, j + 1 < n ? j + 1 : j);
                int   ns0  = __shfl(pkv.y, j);
                int   ns1  = __shfl(pkv.y, j + 1 < n ? j + 1 : j);
                float ngo0 = __int_as_float(__shfl(pkv.z, j));
                float ngo1 = (j + 1 < n) ? __int_as_float(__shfl(pkv.z, j + 1)) : 0.f;
                float ngs0 = __int_as_float(__shfl(pkv.w, j));
                float ngs1 = (j + 1 < n) ? __int_as_float(__shfl(pkv.w, j + 1)) : 0.f;
                int   nno = half ? no1 : no0,  nns = half ? ns1 : ns0;
                float ngo = half ? ngo1 : ngo0, ngs = half ? ngs1 : ngs0;
                uint4 vno = *(const uint4*)(instB + (size_t)nno * DD + qoff + l32 * 8);
                uint4 vns = *(const uint4*)(instB + (size_t)nns * DD + qoff + l32 * 8);
                acc8(a, vo, mygo);
                acc8(a, vs, mygs);
                vo = vno; vs = vns; mygo = ngo; mygs = ngs;
            }
            acc8(a, vo, mygo);
            acc8(a, vs, mygs);
        }
        msgB = pmsgB; base2 = pbx * 2;
    }
    #pragma unroll
    for (int k = 0; k < 8; k++) a[k] += __shfl_xor(a[k], 32);
    float scale = 0.5f / (float)max(lenScale, 1);
    if (half == 0) {
        #pragma unroll
        for (int k = 0; k < 8; k++) lds[w][l32 * 9 + k] = a[k] * scale;
    }
    __syncthreads();
    if (threadIdx.x < 64) {
        int nodeSel = threadIdx.x >> 5;
        int l = threadIdx.x & 31;
        int w0 = nodeSel * 2;
        float s0 = lds[w0][l * 9 + 0] + lds[w0 + 1][l * 9 + 0];
        float s1 = lds[w0][l * 9 + 1] + lds[w0 + 1][l * 9 + 1];
        float s2 = lds[w0][l * 9 + 2] + lds[w0 + 1][l * 9 + 2];
        float s3 = lds[w0][l * 9 + 3] + lds[w0 + 1][l * 9 + 3];
        float s4 = lds[w0][l * 9 + 4] + lds[w0 + 1][l * 9 + 4];
        float s5 = lds[w0][l * 9 + 5] + lds[w0 + 1][l * 9 + 5];
        float s6 = lds[w0][l * 9 + 6] + lds[w0 + 1][l * 9 + 6];
        float s7 = lds[w0][l * 9 + 7] + lds[w0 + 1][l * 9 + 7];
        uint4 o;
        o.x = pack2(s0, s1);
        o.y = pack2(s2, s3);
        o.z = pack2(s4, s5);
        o.w = pack2(s6, s7);
        *(uint4*)&msgB[(size_t)(base2 + nodeSel) * DD + qoff + l * 8] = o;
    }
}

// ---------------------------------------------------------------------------
extern "C" void kernel_launch(void* const* d_in, const int* in_sizes, int n_in,
                              void* d_out, int out_size, void* d_ws, size_t ws_size,
                              hipStream_t stream) {
    (void)in_sizes; (void)n_in; (void)out_size; (void)ws_size;
    const float* inst_feat = (const float*)d_in[0];
    const float* phra_feat = (const float*)d_in[1];
    const int*   conn      = (const int*)d_in[2];
    const int*   clu       = (const int*)d_in[3];
    const float* psW = (const float*)d_in[4];  const float* psB = (const float*)d_in[5];
    const float* poW = (const float*)d_in[6];  const float* poB = (const float*)d_in[7];
    const float* opW = (const float*)d_in[8];  const float* opB = (const float*)d_in[9];
    const float* spW = (const float*)d_in[10]; const float* spB = (const float*)d_in[11];
    const float* iw1W = (const float*)d_in[12]; const float* iw1B = (const float*)d_in[13];
    const float* iw2W = (const float*)d_in[14]; const float* iw2B = (const float*)d_in[15];
    const float* pw1W = (const float*)d_in[16]; const float* pw1B = (const float*)d_in[17];
    const float* pw2W = (const float*)d_in[18]; const float* pw2B = (const float*)d_in[19];
    const int* s_idx = conn;
    const int* o_idx = conn + EE;

    char* ws = (char*)d_ws;
    size_t off = 0;
    auto alloc = [&](size_t bytes) {
        char* p = ws + off;
        off += (bytes + 255) & ~(size_t)255;
        return p;
    };
    ushort* instB = (ushort*)alloc((size_t)NN * DD * 2);
    ushort* phraB = (ushort*)alloc((size_t)PP * DD * 2);
    ushort* WiT   = (ushort*)alloc((size_t)G4 * DD * 2);
    ushort* WpT   = (ushort*)alloc((size_t)G4 * DD * 2);
    ushort* iw1T  = (ushort*)alloc((size_t)DD * DD * 2);
    ushort* iw2T  = (ushort*)alloc((size_t)DD * DD * 2);
    ushort* pw1T  = (ushort*)alloc((size_t)DD * DD * 2);
    ushort* pw2T  = (ushort*)alloc((size_t)DD * DD * 2);
    float* biascat = (float*)alloc(G4 * 4);
    ushort* TiB   = (ushort*)alloc((size_t)NN * G4 * 2);
    ushort* TpB   = (ushort*)alloc((size_t)PP * G4 * 2);
    int* cntBlock = (int*)alloc((size_t)NCNT * 4);
    int* cntS = cntBlock;      int* cntO = cntS + NN;  int* cntC = cntO + NN;
    int* curS = cntC + PP;     int* curO = curS + NN;  int* curC = curO + NN;
    int* startS = (int*)alloc((NN + 1) * 4);
    int* startO = (int*)alloc((NN + 1) * 4);
    int* startC = (int*)alloc((PP + 1) * 4);
    int2* pkS   = (int2*)alloc((size_t)EE * 8);
    int2* pkO   = (int2*)alloc((size_t)EE * 8);
    int4* pkC   = (int4*)alloc((size_t)EE * 16);
    ushort* imsgB = (ushort*)alloc((size_t)NN * DD * 2);
    ushort* pmsgB = (ushort*)alloc((size_t)PP * DD * 2);

    float* inst_out = (float*)d_out;
    float* phra_out = inst_out + (size_t)NN * DD;

    // Fused prep: counter zeroing + bf16 casts + weight pack/transpose
    prep_kernel<<<NB_ZERO + NB_F2B + NB_PACK + NB_WT, 256, 0, stream>>>(
        cntBlock, inst_feat, phra_feat, instB, phraB,
        psW, poW, opW, spW, psB, poB, opB, spB, WiT, WpT, biascat,
        iw1W, iw2W, pw1W, pw2W, iw1T, iw2T, pw1T, pw2T);

    // CSR build (scatter fused into gate_kernel atomics)
    hist_kernel<<<EE / 256, 256, 0, stream>>>(s_idx, o_idx, clu, cntS, cntO, cntC);
    scan3_kernel<<<3, 1024, 0, stream>>>(cntS, cntO, cntC, startS, startO, startC);

    // Gate tables (bf16 MFMA, bias folded into Tp; 2-buffer pipeline)
    mfma_tables_kernel<<<dim3((NN + PP) / 128, G4 / 64), 256, 0, stream>>>(
        instB, WiT, phraB, WpT, biascat, TiB, TpB);

    // Gates -> packed CSR entries (table-halved, XCD-pinned, scatter fused)
    gate_kernel<<<2 * EE / 4, 256, 0, stream>>>(
        s_idx, o_idx, clu, startS, startO, startC, curS, curO, curC,
        TiB, TpB, pkS, pkO, pkC);

    // Segment means (quartered, XCD-pinned, 2-edge-per-step uint4 pipeline)
    seg_kernel<<<(NN / 2 + PP / 2) * 4, 256, 0, stream>>>(
        phraB, instB, pkS, startS, pkO, startO, pkC, startC, imsgB, pmsgB);

    // Fused refine (128x64 tiles, 768 blocks, 2-buffer counted-vmcnt pipeline)
    mfma_refine_kernel<<<dim3((NN + PP) / 128, DD / 64), 256, 0, stream>>>(
        imsgB, instB, iw1T, iw2T, iw1B, iw2B, inst_out,
        pmsgB, phraB, pw1T, pw2T, pw1B, pw2B, phra_out);
}

// Round 13
// 145.597 us; speedup vs baseline: 1.3619x; 1.0962x over previous
//
#include <hip/hip_runtime.h>
#include <math.h>

// Problem constants (fixed by the reference)
constexpr int NN  = 4096;   // instances
constexpr int PP  = 2048;   // phrases
constexpr int EE  = 65536;  // edges
constexpr int DD  = 1024;   // feature dim
constexpr int OUTF = 128;   // gate MLP out dim
constexpr int G4  = 512;    // 4 gates * 128

typedef __attribute__((ext_vector_type(8))) short short8v;
typedef __attribute__((ext_vector_type(4))) float f32x4;

// sigmoid(relu(z)) with fast rcp (v_rcp_f32, ~1 ulp; bf16 rounding dominates).
// Plain 1.0f/x compiles to the precise div sequence (~12 VALU) without
// fast-math -- that was ~2/3 of gate_kernel's runtime (R12 post-mortem).
__device__ __forceinline__ float sigmoid_relu(float z) {
    z = fmaxf(z, 0.0f);
    return __builtin_amdgcn_rcpf(1.0f + __expf(-z));
}
__device__ __forceinline__ float b2f(ushort u) {
    return __uint_as_float(((unsigned int)u) << 16);
}
__device__ __forceinline__ ushort f2b(float f) {  // RNE
    unsigned int x = __float_as_uint(f);
    return (ushort)((x + 0x7fffu + ((x >> 16) & 1u)) >> 16);
}
__device__ __forceinline__ unsigned int pack2(float a, float b) {
    return (unsigned int)f2b(a) | ((unsigned int)f2b(b) << 16);
}
__device__ __forceinline__ float lo16(unsigned int u) { return __uint_as_float(u << 16); }
__device__ __forceinline__ float hi16(unsigned int u) { return __uint_as_float(u & 0xffff0000u); }
__device__ __forceinline__ float pairSig(unsigned int a, unsigned int b) {
    return sigmoid_relu(lo16(a) + lo16(b)) + sigmoid_relu(hi16(a) + hi16(b));
}

#define GLD16(gptr, lptr) \
    __builtin_amdgcn_global_load_lds((__attribute__((address_space(1))) const void*)(gptr), \
                                     (__attribute__((address_space(3))) void*)(lptr), 16, 0, 0)
// Counted-vmcnt pipeline primitives (T4): keep just-issued loads in flight.
#define ASM_VMCNT(n) asm volatile("s_waitcnt vmcnt(" #n ")" ::: "memory")
#define BARRIER() do { asm volatile("" ::: "memory"); \
                       __builtin_amdgcn_s_barrier();  \
                       asm volatile("" ::: "memory"); } while (0)

// ---------------------------------------------------------------------------
// Fused prep: counter zeroing, f32->bf16 features, gate-weight pack,
// refine-weight transpose.
constexpr int NCNT    = 2 * (NN + NN + PP);        // 20480 ints (cnt + cur)
constexpr int NB_ZERO = NCNT / 256;                // 80
constexpr int NB_F2B  = (NN + PP) * DD / 4 / 256;  // 6144
constexpr int NB_PACK = G4 * DD / 256;             // 2048
constexpr int NB_WT   = 4 * (DD / 64) * (DD / 64); // 1024

__global__ __launch_bounds__(256) void prep_kernel(
        int* __restrict__ cntBlock,
        const float* __restrict__ instF, const float* __restrict__ phraF,
        ushort* __restrict__ instB, ushort* __restrict__ phraB,
        const float* __restrict__ psW, const float* __restrict__ poW,
        const float* __restrict__ opW, const float* __restrict__ spW,
        const float* __restrict__ psB, const float* __restrict__ poB,
        const float* __restrict__ opB, const float* __restrict__ spB,
        ushort* __restrict__ WiT, ushort* __restrict__ WpT,
        float* __restrict__ biascat,
        const float* __restrict__ W0, const float* __restrict__ W1,
        const float* __restrict__ W2, const float* __restrict__ W3,
        ushort* __restrict__ T0, ushort* __restrict__ T1,
        ushort* __restrict__ T2, ushort* __restrict__ T3) {
    __shared__ float tile[64][65];
    int b = blockIdx.x, t = threadIdx.x;
    if (b < NB_ZERO) {
        cntBlock[b * 256 + t] = 0;
        return;
    }
    b -= NB_ZERO;
    if (b < NB_F2B) {
        int i = b * 256 + t;
        constexpr int na4 = NN * DD / 4;
        if (i < na4) {
            float4 v = ((const float4*)instF)[i];
            ushort4 u; u.x = f2b(v.x); u.y = f2b(v.y); u.z = f2b(v.z); u.w = f2b(v.w);
            ((ushort4*)instB)[i] = u;
        } else {
            int j = i - na4;
            float4 v = ((const float4*)phraF)[j];
            ushort4 u; u.x = f2b(v.x); u.y = f2b(v.y); u.z = f2b(v.z); u.w = f2b(v.w);
            ((ushort4*)phraB)[j] = u;
        }
        return;
    }
    b -= NB_F2B;
    if (b < NB_PACK) {
        int idx = b * 256 + t;
        int n = idx >> 10, k = idx & 1023;
        int g = n >> 7, j = n & 127;
        float wi, wp;
        if (g == 0)      { wi = psW[(size_t)(DD + k) * OUTF + j]; wp = psW[(size_t)k * OUTF + j]; }
        else if (g == 1) { wi = poW[(size_t)(DD + k) * OUTF + j]; wp = poW[(size_t)k * OUTF + j]; }
        else if (g == 2) { wi = opW[(size_t)k * OUTF + j];        wp = opW[(size_t)(DD + k) * OUTF + j]; }
        else             { wi = spW[(size_t)k * OUTF + j];        wp = spW[(size_t)(DD + k) * OUTF + j]; }
        WiT[idx] = f2b(wi);
        WpT[idx] = f2b(wp);
        if (idx < G4) {
            int gg = idx >> 7, jj = idx & 127;
            biascat[idx] = (gg == 0) ? psB[jj] : (gg == 1) ? poB[jj]
                         : (gg == 2) ? opB[jj] : spB[jj];
        }
        return;
    }
    b -= NB_PACK;
    int z = b >> 8, rest = b & 255;
    const float* W = (z == 0) ? W0 : (z == 1) ? W1 : (z == 2) ? W2 : W3;
    ushort*      T = (z == 0) ? T0 : (z == 1) ? T1 : (z == 2) ? T2 : T3;
    int k0 = (rest & 15) * 64, n0 = (rest >> 4) * 64;
    int tx = t & 63, ty = t >> 6;
    #pragma unroll
    for (int i = 0; i < 64; i += 4)
        tile[ty + i][tx] = W[(size_t)(k0 + ty + i) * DD + n0 + tx];
    __syncthreads();
    #pragma unroll
    for (int i = 0; i < 64; i += 4)
        T[(size_t)(n0 + ty + i) * DD + k0 + tx] = f2b(tile[tx][ty + i]);
}

// ---------------------------------------------------------------------------
// MFMA GEMM building blocks (R10 proven). A-tile 128 rows; B-tile BROWS rows.
// BK=64, XOR-swizzled linear LDS (rule 21).
template<int BROWS>
__device__ __forceinline__ void stage_tiles(const ushort* __restrict__ A,
                                            const ushort* __restrict__ BT,
                                            int bm, int bn, int k0,
                                            ushort* Asl, ushort* Bsl, int t) {
    #pragma unroll
    for (int r = 0; r < 4; r++) {
        int ch = r * 256 + t;
        int row = ch >> 3;
        int sw = ((ch & 7) ^ (row & 7)) << 3;
        GLD16(A + (size_t)(bm + row) * DD + k0 + sw, &Asl[ch * 8]);
    }
    #pragma unroll
    for (int r = 0; r < BROWS / 32; r++) {
        int ch = r * 256 + t;
        int row = ch >> 3;
        int sw = ((ch & 7) ^ (row & 7)) << 3;
        GLD16(BT + (size_t)(bn + row) * DD + k0 + sw, &Bsl[ch * 8]);
    }
}

template<int NACC>
__device__ __forceinline__ void compute_tiles(const ushort* Asl, const ushort* Bsl,
                                              f32x4 (&acc)[4][NACC],
                                              int wr, int wc, int lr, int lk) {
    #pragma unroll
    for (int kk = 0; kk < 2; kk++) {
        int ch16 = kk * 4 + lk;
        short8v a[4], b[NACC];
        #pragma unroll
        for (int m = 0; m < 4; m++) {
            int ra = wr + m * 16 + lr;
            a[m] = *(const short8v*)&Asl[ra * 64 + ((ch16 ^ (ra & 7)) << 3)];
        }
        #pragma unroll
        for (int n = 0; n < NACC; n++) {
            int rb = wc + n * 16 + lr;
            b[n] = *(const short8v*)&Bsl[rb * 64 + ((ch16 ^ (rb & 7)) << 3)];
        }
        #pragma unroll
        for (int m = 0; m < 4; m++)
            #pragma unroll
            for (int n = 0; n < NACC; n++)
                acc[m][n] = __builtin_amdgcn_mfma_f32_16x16x32_bf16(a[m], b[n], acc[m][n], 0, 0, 0);
    }
}

// ---------------------------------------------------------------------------
// Gate tables, 128x64 tile, counted-vmcnt 2-buffer pipeline (R10 proven).
__global__ __launch_bounds__(256) void mfma_tables_kernel(
        const ushort* __restrict__ instB, const ushort* __restrict__ WiT,
        const ushort* __restrict__ phraB, const ushort* __restrict__ WpT,
        const float* __restrict__ biascat,
        ushort* __restrict__ TiB, ushort* __restrict__ TpB) {
    __shared__ ushort Asl[2][128 * 64];
    __shared__ ushort Bsl[2][64 * 64];
    int bx = blockIdx.x;
    const ushort *A, *BT; ushort* C; const float* bias;
    if (bx < NN / 128) { A = instB; BT = WiT; C = TiB; bias = nullptr; }
    else { bx -= NN / 128; A = phraB; BT = WpT; C = TpB; bias = biascat; }
    int bm = bx * 128, bn = blockIdx.y * 64;
    int t = threadIdx.x;
    const int lane = t & 63, w = t >> 6;
    const int wr = (w >> 1) * 64, wc = (w & 1) * 32;
    const int lr = lane & 15, lk = lane >> 4;
    f32x4 acc[4][2] = {};

    int cur = 0;
    stage_tiles<64>(A, BT, bm, bn, 0, Asl[0], Bsl[0], t);
    for (int k0 = 0; k0 < DD; k0 += 64) {
        int nxt = cur ^ 1;
        if (k0 + 64 < DD) {
            stage_tiles<64>(A, BT, bm, bn, k0 + 64, Asl[nxt], Bsl[nxt], t);
            ASM_VMCNT(6);
        } else {
            ASM_VMCNT(0);
        }
        BARRIER();
        compute_tiles<2>(Asl[cur], Bsl[cur], acc, wr, wc, lr, lk);
        BARRIER();
        cur = nxt;
    }
    #pragma unroll
    for (int m = 0; m < 4; m++) {
        int row = bm + wr + m * 16 + lk * 4;
        #pragma unroll
        for (int n = 0; n < 2; n++) {
            int col = bn + wc + n * 16 + lr;
            float bv = bias ? bias[col] : 0.f;
            #pragma unroll
            for (int r = 0; r < 4; r++)
                C[(size_t)(row + r) * G4 + col] = f2b(acc[m][n][r] + bv);
        }
    }
}

// ---------------------------------------------------------------------------
// Fused refine: out = msg + relu(msg@W1+b1) + relu(feat@W2+b2).
// 128x64 tile (768 blocks), continuous counted-vmcnt pipeline (R10 proven).
__global__ __launch_bounds__(256) void mfma_refine_kernel(
        const ushort* __restrict__ imsgB, const ushort* __restrict__ instB,
        const ushort* __restrict__ iw1T, const ushort* __restrict__ iw2T,
        const float* __restrict__ ib1, const float* __restrict__ ib2,
        float* __restrict__ iout,
        const ushort* __restrict__ pmsgB, const ushort* __restrict__ phraB,
        const ushort* __restrict__ pw1T, const ushort* __restrict__ pw2T,
        const float* __restrict__ pb1, const float* __restrict__ pb2,
        float* __restrict__ pout) {
    __shared__ ushort Asl[2][128 * 64];
    __shared__ ushort Bsl[2][64 * 64];
    int bx = blockIdx.x;
    const ushort *Am, *Af, *W1, *W2; const float *b1, *b2; float* out;
    if (bx < NN / 128) {
        Am = imsgB; Af = instB; W1 = iw1T; W2 = iw2T; b1 = ib1; b2 = ib2; out = iout;
    } else {
        bx -= NN / 128;
        Am = pmsgB; Af = phraB; W1 = pw1T; W2 = pw2T; b1 = pb1; b2 = pb2; out = pout;
    }
    int bm = bx * 128, bn = blockIdx.y * 64;
    int t = threadIdx.x;
    const int lane = t & 63, w = t >> 6;
    const int wr = (w >> 1) * 64, wc = (w & 1) * 32;
    const int lr = lane & 15, lk = lane >> 4;
    f32x4 acc1[4][2] = {};
    f32x4 acc2[4][2] = {};

    int cur = 0;
    stage_tiles<64>(Am, W1, bm, bn, 0, Asl[0], Bsl[0], t);
    auto run = [&](const ushort* A, const ushort* B, f32x4 (&acc)[4][2],
                   const ushort* An, const ushort* Bn) {
        for (int k0 = 0; k0 < DD; k0 += 64) {
            int nxt = cur ^ 1;
            if (k0 + 64 < DD) {
                stage_tiles<64>(A, B, bm, bn, k0 + 64, Asl[nxt], Bsl[nxt], t);
                ASM_VMCNT(6);
            } else if (An) {
                stage_tiles<64>(An, Bn, bm, bn, 0, Asl[nxt], Bsl[nxt], t);
                ASM_VMCNT(6);
            } else {
                ASM_VMCNT(0);
            }
            BARRIER();
            compute_tiles<2>(Asl[cur], Bsl[cur], acc, wr, wc, lr, lk);
            BARRIER();
            cur = nxt;
        }
    };
    run(Am, W1, acc1, Af, W2);
    run(Af, W2, acc2, nullptr, nullptr);

    #pragma unroll
    for (int m = 0; m < 4; m++) {
        int row = bm + wr + m * 16 + lk * 4;
        #pragma unroll
        for (int n = 0; n < 2; n++) {
            int col = bn + wc + n * 16 + lr;
            float vb1 = b1[col], vb2 = b2[col];
            #pragma unroll
            for (int r = 0; r < 4; r++) {
                float v = b2f(Am[(size_t)(row + r) * DD + col])
                        + fmaxf(acc1[m][n][r] + vb1, 0.f)
                        + fmaxf(acc2[m][n][r] + vb2, 0.f);
                out[(size_t)(row + r) * DD + col] = v;
            }
        }
    }
}

// ---------------------------------------------------------------------------
// Counting sort: histogram + scan (scatter fused into gate_kernel atomics).
__global__ void hist_kernel(const int* __restrict__ s_idx, const int* __restrict__ o_idx,
                            const int* __restrict__ c_idx,
                            int* cntS, int* cntO, int* cntC) {
    int e = blockIdx.x * blockDim.x + threadIdx.x;
    if (e >= EE) return;
    atomicAdd(&cntS[s_idx[e]], 1);
    atomicAdd(&cntO[o_idx[e]], 1);
    atomicAdd(&cntC[c_idx[e]], 1);
}

__global__ __launch_bounds__(1024) void scan3_kernel(
        const int* __restrict__ cntS, const int* __restrict__ cntO,
        const int* __restrict__ cntC,
        int* __restrict__ startS, int* __restrict__ startO, int* __restrict__ startC) {
    const int* cnt; int* start; int n;
    if (blockIdx.x == 0)      { cnt = cntS; start = startS; n = NN; }
    else if (blockIdx.x == 1) { cnt = cntO; start = startO; n = NN; }
    else                      { cnt = cntC; start = startC; n = PP; }
    __shared__ int sh[1024];
    int t = threadIdx.x;
    int per = n >> 10;
    int base = t * per;
    int s = 0;
    for (int i = 0; i < per; i++) s += cnt[base + i];
    sh[t] = s;
    __syncthreads();
    for (int off = 1; off < 1024; off <<= 1) {
        int v = (t >= off) ? sh[t - off] : 0;
        __syncthreads();
        sh[t] += v;
        __syncthreads();
    }
    int ex = (t == 0) ? 0 : sh[t - 1];
    for (int i = 0; i < per; i++) { start[base + i] = ex; ex += cnt[base + i]; }
    if (t == 1023) start[n] = ex;
}

// ---------------------------------------------------------------------------
// Per-edge gates (R10 proven structure: one wave per edge, all 4 gates,
// scatter fused via atomics).  R13: fast-rcp sigmoid (see sigmoid_relu).
__global__ __launch_bounds__(256) void gate_kernel(
        const int* __restrict__ s_idx, const int* __restrict__ o_idx,
        const int* __restrict__ c_idx,
        const int* __restrict__ startS, const int* __restrict__ startO,
        const int* __restrict__ startC,
        int* __restrict__ curS, int* __restrict__ curO, int* __restrict__ curC,
        const ushort* __restrict__ Ti, const ushort* __restrict__ Tp,
        int2* __restrict__ pkS, int2* __restrict__ pkO, int4* __restrict__ pkC) {
    int gid = blockIdx.x * 256 + threadIdx.x;
    int e = gid >> 6, lane = gid & 63;
    if (e >= EE) return;
    int s = s_idx[e], o = o_idx[e], c = c_idx[e];
    const unsigned int* tpc = (const unsigned int*)(Tp + (size_t)c * G4);
    const unsigned int* tis = (const unsigned int*)(Ti + (size_t)s * G4);
    const unsigned int* tio = (const unsigned int*)(Ti + (size_t)o * G4);
    float s0 = pairSig(tpc[lane],       tis[lane]);
    float s1 = pairSig(tpc[64 + lane],  tio[64 + lane]);
    float s2 = pairSig(tpc[128 + lane], tio[128 + lane]);
    float s3 = pairSig(tpc[192 + lane], tis[192 + lane]);
    #pragma unroll
    for (int off = 32; off; off >>= 1) {
        s0 += __shfl_xor(s0, off);
        s1 += __shfl_xor(s1, off);
        s2 += __shfl_xor(s2, off);
        s3 += __shfl_xor(s3, off);
    }
    if (lane == 0) {
        const float inv = 1.0f / 128.0f;
        int ps = startS[s] + atomicAdd(&curS[s], 1);
        int po = startO[o] + atomicAdd(&curO[o], 1);
        int pc = startC[c] + atomicAdd(&curC[c], 1);
        pkS[ps] = make_int2(c, __float_as_int(s0 * inv));
        pkO[po] = make_int2(c, __float_as_int(s1 * inv));
        pkC[pc] = make_int4(o, s, __float_as_int(s2 * inv), __float_as_int(s3 * inv));
    }
}

// ---------------------------------------------------------------------------
// Segment means, D-quartered + XCD-pinned, shfl-broadcast pk, 2 edges per
// wave-step (unchanged from R10, proven 40.3 us).
__device__ __forceinline__ void acc8(float* a, uint4 v, float g) {
    a[0] += g * lo16(v.x); a[1] += g * hi16(v.x);
    a[2] += g * lo16(v.y); a[3] += g * hi16(v.y);
    a[4] += g * lo16(v.z); a[5] += g * hi16(v.z);
    a[6] += g * lo16(v.w); a[7] += g * hi16(v.w);
}

__global__ __launch_bounds__(256) void seg_kernel(
        const ushort* __restrict__ phraB, const ushort* __restrict__ instB,
        const int2* __restrict__ pkS, const int* __restrict__ startS,
        const int2* __restrict__ pkO, const int* __restrict__ startO,
        const int4* __restrict__ pkC, const int* __restrict__ startC,
        ushort* __restrict__ imsgB, ushort* __restrict__ pmsgB) {
    __shared__ float lds[4][32 * 9];
    int bid = blockIdx.x;
    int x = bid & 7;
    int q = x >> 1;
    int sub = ((bid >> 3) << 1) + (x & 1);
    int qoff = q * 256;
    int w = threadIdx.x >> 6, lane = threadIdx.x & 63;
    int half = lane >> 5, l32 = lane & 31;
    float a[8];
    #pragma unroll
    for (int k = 0; k < 8; k++) a[k] = 0.f;
    bool instSide = sub < NN / 2;
    int lenScale;
    ushort* msgB;
    int base2;
    if (instSide) {
        int node = sub * 2 + (w >> 1);
        const int2* pk_list = (w & 1) ? pkO : pkS;
        const int*  start   = (w & 1) ? startO : startS;
        int b = start[node], e = start[node + 1];
        lenScale = e - b;
        for (int base = b; base < e; base += 64) {
            int n = min(64, e - base);
            int2 pkv = pk_list[base + min(lane, n - 1)];   // one coalesced load
            int   c0 = __shfl(pkv.x, 0);
            int   c1 = __shfl(pkv.x, 1 < n ? 1 : 0);
            float g0 = __int_as_float(__shfl(pkv.y, 0));
            float g1 = (1 < n) ? __int_as_float(__shfl(pkv.y, 1)) : 0.f;
            int   myc = half ? c1 : c0;
            float myg = half ? g1 : g0;
            uint4 v = *(const uint4*)(phraB + (size_t)myc * DD + qoff + l32 * 8);
            for (int j = 2; j < n; j += 2) {
                int   d0 = __shfl(pkv.x, j);
                int   d1 = __shfl(pkv.x, j + 1 < n ? j + 1 : j);
                float h0 = __int_as_float(__shfl(pkv.y, j));
                float h1 = (j + 1 < n) ? __int_as_float(__shfl(pkv.y, j + 1)) : 0.f;
                int   nc = half ? d1 : d0;
                float ng = half ? h1 : h0;
                uint4 vn = *(const uint4*)(phraB + (size_t)nc * DD + qoff + l32 * 8);
                acc8(a, v, myg);
                v = vn; myg = ng;
            }
            acc8(a, v, myg);
        }
        msgB = imsgB; base2 = sub * 2;
    } else {
        int pbx = sub - NN / 2;
        int p = pbx * 2 + (w >> 1);
        int cb = startC[p], ce = startC[p + 1];
        lenScale = ce - cb;
        int mid = cb + ((ce - cb) >> 1);
        int mb = (w & 1) ? mid : cb;       // contiguous halves (coalesced chunks)
        int me = (w & 1) ? ce : mid;
        for (int base = mb; base < me; base += 64) {
            int n = min(64, me - base);
            int4 pkv = pkC[base + min(lane, n - 1)];
            int   o0  = __shfl(pkv.x, 0);
            int   o1  = __shfl(pkv.x, 1 < n ? 1 : 0);
            int   si0 = __shfl(pkv.y, 0);
            int   si1 = __shfl(pkv.y, 1 < n ? 1 : 0);
            float go0 = __int_as_float(__shfl(pkv.z, 0));
            float go1 = (1 < n) ? __int_as_float(__shfl(pkv.z, 1)) : 0.f;
            float gs0 = __int_as_float(__shfl(pkv.w, 0));
            float gs1 = (1 < n) ? __int_as_float(__shfl(pkv.w, 1)) : 0.f;
            int   myo = half ? o1 : o0,  mys = half ? si1 : si0;
            float mygo = half ? go1 : go0, mygs = half ? gs1 : gs0;
            uint4 vo = *(const uint4*)(instB + (size_t)myo * DD + qoff + l32 * 8);
            uint4 vs = *(const uint4*)(instB + (size_t)mys * DD + qoff + l32 * 8);
            for (int j = 2; j < n; j += 2) {
                int   no0  = __shfl(pkv.x, j);
                int   no1  = __shfl(pkv.x, j + 1 < n ? j + 1 : j);
                int   ns0  = __shfl(pkv.y, j);
                int   ns1  = __shfl(pkv.y, j + 1 < n ? j + 1 : j);
                float ngo0 = __int_as_float(__shfl(pkv.z, j));
                float ngo1 = (j + 1 < n) ? __int_as_float(__shfl(pkv.z, j + 1)) : 0.f;
                float ngs0 = __int_as_float(__shfl(pkv.w, j));
                float ngs1 = (j + 1 < n) ? __int_as_float(__shfl(pkv.w, j + 1)) : 0.f;
                int   nno = half ? no1 : no0,  nns = half ? ns1 : ns0;
                float ngo = half ? ngo1 : ngo0, ngs = half ? ngs1 : ngs0;
                uint4 vno = *(const uint4*)(instB + (size_t)nno * DD + qoff + l32 * 8);
                uint4 vns = *(const uint4*)(instB + (size_t)nns * DD + qoff + l32 * 8);
                acc8(a, vo, mygo);
                acc8(a, vs, mygs);
                vo = vno; vs = vns; mygo = ngo; mygs = ngs;
            }
            acc8(a, vo, mygo);
            acc8(a, vs, mygs);
        }
        msgB = pmsgB; base2 = pbx * 2;
    }
    #pragma unroll
    for (int k = 0; k < 8; k++) a[k] += __shfl_xor(a[k], 32);
    float scale = 0.5f / (float)max(lenScale, 1);
    if (half == 0) {
        #pragma unroll
        for (int k = 0; k < 8; k++) lds[w][l32 * 9 + k] = a[k] * scale;
    }
    __syncthreads();
    if (threadIdx.x < 64) {
        int nodeSel = threadIdx.x >> 5;
        int l = threadIdx.x & 31;
        int w0 = nodeSel * 2;
        float s0 = lds[w0][l * 9 + 0] + lds[w0 + 1][l * 9 + 0];
        float s1 = lds[w0][l * 9 + 1] + lds[w0 + 1][l * 9 + 1];
        float s2 = lds[w0][l * 9 + 2] + lds[w0 + 1][l * 9 + 2];
        float s3 = lds[w0][l * 9 + 3] + lds[w0 + 1][l * 9 + 3];
        float s4 = lds[w0][l * 9 + 4] + lds[w0 + 1][l * 9 + 4];
        float s5 = lds[w0][l * 9 + 5] + lds[w0 + 1][l * 9 + 5];
        float s6 = lds[w0][l * 9 + 6] + lds[w0 + 1][l * 9 + 6];
        float s7 = lds[w0][l * 9 + 7] + lds[w0 + 1][l * 9 + 7];
        uint4 o;
        o.x = pack2(s0, s1);
        o.y = pack2(s2, s3);
        o.z = pack2(s4, s5);
        o.w = pack2(s6, s7);
        *(uint4*)&msgB[(size_t)(base2 + nodeSel) * DD + qoff + l * 8] = o;
    }
}

// ---------------------------------------------------------------------------
extern "C" void kernel_launch(void* const* d_in, const int* in_sizes, int n_in,
                              void* d_out, int out_size, void* d_ws, size_t ws_size,
                              hipStream_t stream) {
    (void)in_sizes; (void)n_in; (void)out_size; (void)ws_size;
    const float* inst_feat = (const float*)d_in[0];
    const float* phra_feat = (const float*)d_in[1];
    const int*   conn      = (const int*)d_in[2];
    const int*   clu       = (const int*)d_in[3];
    const float* psW = (const float*)d_in[4];  const float* psB = (const float*)d_in[5];
    const float* poW = (const float*)d_in[6];  const float* poB = (const float*)d_in[7];
    const float* opW = (const float*)d_in[8];  const float* opB = (const float*)d_in[9];
    const float* spW = (const float*)d_in[10]; const float* spB = (const float*)d_in[11];
    const float* iw1W = (const float*)d_in[12]; const float* iw1B = (const float*)d_in[13];
    const float* iw2W = (const float*)d_in[14]; const float* iw2B = (const float*)d_in[15];
    const float* pw1W = (const float*)d_in[16]; const float* pw1B = (const float*)d_in[17];
    const float* pw2W = (const float*)d_in[18]; const float* pw2B = (const float*)d_in[19];
    const int* s_idx = conn;
    const int* o_idx = conn + EE;

    char* ws = (char*)d_ws;
    size_t off = 0;
    auto alloc = [&](size_t bytes) {
        char* p = ws + off;
        off += (bytes + 255) & ~(size_t)255;
        return p;
    };
    ushort* instB = (ushort*)alloc((size_t)NN * DD * 2);
    ushort* phraB = (ushort*)alloc((size_t)PP * DD * 2);
    ushort* WiT   = (ushort*)alloc((size_t)G4 * DD * 2);
    ushort* WpT   = (ushort*)alloc((size_t)G4 * DD * 2);
    ushort* iw1T  = (ushort*)alloc((size_t)DD * DD * 2);
    ushort* iw2T  = (ushort*)alloc((size_t)DD * DD * 2);
    ushort* pw1T  = (ushort*)alloc((size_t)DD * DD * 2);
    ushort* pw2T  = (ushort*)alloc((size_t)DD * DD * 2);
    float* biascat = (float*)alloc(G4 * 4);
    ushort* TiB   = (ushort*)alloc((size_t)NN * G4 * 2);
    ushort* TpB   = (ushort*)alloc((size_t)PP * G4 * 2);
    int* cntBlock = (int*)alloc((size_t)NCNT * 4);
    int* cntS = cntBlock;      int* cntO = cntS + NN;  int* cntC = cntO + NN;
    int* curS = cntC + PP;     int* curO = curS + NN;  int* curC = curO + NN;
    int* startS = (int*)alloc((NN + 1) * 4);
    int* startO = (int*)alloc((NN + 1) * 4);
    int* startC = (int*)alloc((PP + 1) * 4);
    int2* pkS   = (int2*)alloc((size_t)EE * 8);
    int2* pkO   = (int2*)alloc((size_t)EE * 8);
    int4* pkC   = (int4*)alloc((size_t)EE * 16);
    ushort* imsgB = (ushort*)alloc((size_t)NN * DD * 2);
    ushort* pmsgB = (ushort*)alloc((size_t)PP * DD * 2);

    float* inst_out = (float*)d_out;
    float* phra_out = inst_out + (size_t)NN * DD;

    // Fused prep: counter zeroing + bf16 casts + weight pack/transpose
    prep_kernel<<<NB_ZERO + NB_F2B + NB_PACK + NB_WT, 256, 0, stream>>>(
        cntBlock, inst_feat, phra_feat, instB, phraB,
        psW, poW, opW, spW, psB, poB, opB, spB, WiT, WpT, biascat,
        iw1W, iw2W, pw1W, pw2W, iw1T, iw2T, pw1T, pw2T);

    // CSR build (scatter fused into gate_kernel atomics)
    hist_kernel<<<EE / 256, 256, 0, stream>>>(s_idx, o_idx, clu, cntS, cntO, cntC);
    scan3_kernel<<<3, 1024, 0, stream>>>(cntS, cntO, cntC, startS, startO, startC);

    // Gate tables (bf16 MFMA, bias folded into Tp; 2-buffer pipeline)
    mfma_tables_kernel<<<dim3((NN + PP) / 128, G4 / 64), 256, 0, stream>>>(
        instB, WiT, phraB, WpT, biascat, TiB, TpB);

    // Gates -> packed CSR entries (one wave/edge, fast-rcp sigmoid)
    gate_kernel<<<(EE * 64) / 256, 256, 0, stream>>>(
        s_idx, o_idx, clu, startS, startO, startC, curS, curO, curC,
        TiB, TpB, pkS, pkO, pkC);

    // Segment means (quartered, XCD-pinned, 2-edge-per-step uint4 pipeline)
    seg_kernel<<<(NN / 2 + PP / 2) * 4, 256, 0, stream>>>(
        phraB, instB, pkS, startS, pkO, startO, pkC, startC, imsgB, pmsgB);

    // Fused refine (128x64 tiles, 768 blocks, 2-buffer counted-vmcnt pipeline)
    mfma_refine_kernel<<<dim3((NN + PP) / 128, DD / 64), 256, 0, stream>>>(
        imsgB, instB, iw1T, iw2T, iw1B, iw2B, inst_out,
        pmsgB, phraB, pw1T, pw2T, pw1B, pw2B, phra_out);
}

// Round 15
// 142.230 us; speedup vs baseline: 1.3942x; 1.0237x over previous
//
#include <hip/hip_runtime.h>
#include <math.h>

// Problem constants (fixed by the reference)
constexpr int NN  = 4096;   // instances
constexpr int PP  = 2048;   // phrases
constexpr int EE  = 65536;  // edges
constexpr int DD  = 1024;   // feature dim
constexpr int OUTF = 128;   // gate MLP out dim
constexpr int G4  = 512;    // 4 gates * 128

typedef __attribute__((ext_vector_type(8))) short short8v;
typedef __attribute__((ext_vector_type(4))) float f32x4;

// sigmoid(relu(z)) with fast rcp (v_rcp_f32, ~1 ulp; bf16 rounding dominates).
__device__ __forceinline__ float sigmoid_relu(float z) {
    z = fmaxf(z, 0.0f);
    return __builtin_amdgcn_rcpf(1.0f + __expf(-z));
}
__device__ __forceinline__ float b2f(ushort u) {
    return __uint_as_float(((unsigned int)u) << 16);
}
__device__ __forceinline__ ushort f2b(float f) {  // RNE
    unsigned int x = __float_as_uint(f);
    return (ushort)((x + 0x7fffu + ((x >> 16) & 1u)) >> 16);
}
__device__ __forceinline__ unsigned int pack2(float a, float b) {
    return (unsigned int)f2b(a) | ((unsigned int)f2b(b) << 16);
}
__device__ __forceinline__ float lo16(unsigned int u) { return __uint_as_float(u << 16); }
__device__ __forceinline__ float hi16(unsigned int u) { return __uint_as_float(u & 0xffff0000u); }
__device__ __forceinline__ float pairSig(unsigned int a, unsigned int b) {
    return sigmoid_relu(lo16(a) + lo16(b)) + sigmoid_relu(hi16(a) + hi16(b));
}

#define GLD16(gptr, lptr) \
    __builtin_amdgcn_global_load_lds((__attribute__((address_space(1))) const void*)(gptr), \
                                     (__attribute__((address_space(3))) void*)(lptr), 16, 0, 0)
// Counted-vmcnt pipeline primitives (T4): keep just-issued loads in flight.
#define ASM_VMCNT(n) asm volatile("s_waitcnt vmcnt(" #n ")" ::: "memory")
#define BARRIER() do { asm volatile("" ::: "memory"); \
                       __builtin_amdgcn_s_barrier();  \
                       asm volatile("" ::: "memory"); } while (0)

// ---------------------------------------------------------------------------
// Fused prep: counter zeroing, f32->bf16 features, gate-weight pack,
// refine-weight transpose.
constexpr int NCNT    = 2 * (NN + NN + PP);        // 20480 ints (cnt + cur)
constexpr int NB_ZERO = NCNT / 256;                // 80
constexpr int NB_F2B  = (NN + PP) * DD / 4 / 256;  // 6144
constexpr int NB_PACK = G4 * DD / 256;             // 2048
constexpr int NB_WT   = 4 * (DD / 64) * (DD / 64); // 1024

__global__ __launch_bounds__(256) void prep_kernel(
        int* __restrict__ cntBlock,
        const float* __restrict__ instF, const float* __restrict__ phraF,
        ushort* __restrict__ instB, ushort* __restrict__ phraB,
        const float* __restrict__ psW, const float* __restrict__ poW,
        const float* __restrict__ opW, const float* __restrict__ spW,
        const float* __restrict__ psB, const float* __restrict__ poB,
        const float* __restrict__ opB, const float* __restrict__ spB,
        ushort* __restrict__ WiT, ushort* __restrict__ WpT,
        float* __restrict__ biascat,
        const float* __restrict__ W0, const float* __restrict__ W1,
        const float* __restrict__ W2, const float* __restrict__ W3,
        ushort* __restrict__ T0, ushort* __restrict__ T1,
        ushort* __restrict__ T2, ushort* __restrict__ T3) {
    __shared__ float tile[64][65];
    int b = blockIdx.x, t = threadIdx.x;
    if (b < NB_ZERO) {
        cntBlock[b * 256 + t] = 0;
        return;
    }
    b -= NB_ZERO;
    if (b < NB_F2B) {
        int i = b * 256 + t;
        constexpr int na4 = NN * DD / 4;
        if (i < na4) {
            float4 v = ((const float4*)instF)[i];
            ushort4 u; u.x = f2b(v.x); u.y = f2b(v.y); u.z = f2b(v.z); u.w = f2b(v.w);
            ((ushort4*)instB)[i] = u;
        } else {
            int j = i - na4;
            float4 v = ((const float4*)phraF)[j];
            ushort4 u; u.x = f2b(v.x); u.y = f2b(v.y); u.z = f2b(v.z); u.w = f2b(v.w);
            ((ushort4*)phraB)[j] = u;
        }
        return;
    }
    b -= NB_F2B;
    if (b < NB_PACK) {
        int idx = b * 256 + t;
        int n = idx >> 10, k = idx & 1023;
        int g = n >> 7, j = n & 127;
        float wi, wp;
        if (g == 0)      { wi = psW[(size_t)(DD + k) * OUTF + j]; wp = psW[(size_t)k * OUTF + j]; }
        else if (g == 1) { wi = poW[(size_t)(DD + k) * OUTF + j]; wp = poW[(size_t)k * OUTF + j]; }
        else if (g == 2) { wi = opW[(size_t)k * OUTF + j];        wp = opW[(size_t)(DD + k) * OUTF + j]; }
        else             { wi = spW[(size_t)k * OUTF + j];        wp = spW[(size_t)(DD + k) * OUTF + j]; }
        WiT[idx] = f2b(wi);
        WpT[idx] = f2b(wp);
        if (idx < G4) {
            int gg = idx >> 7, jj = idx & 127;
            biascat[idx] = (gg == 0) ? psB[jj] : (gg == 1) ? poB[jj]
                         : (gg == 2) ? opB[jj] : spB[jj];
        }
        return;
    }
    b -= NB_PACK;
    int z = b >> 8, rest = b & 255;
    const float* W = (z == 0) ? W0 : (z == 1) ? W1 : (z == 2) ? W2 : W3;
    ushort*      T = (z == 0) ? T0 : (z == 1) ? T1 : (z == 2) ? T2 : T3;
    int k0 = (rest & 15) * 64, n0 = (rest >> 4) * 64;
    int tx = t & 63, ty = t >> 6;
    #pragma unroll
    for (int i = 0; i < 64; i += 4)
        tile[ty + i][tx] = W[(size_t)(k0 + ty + i) * DD + n0 + tx];
    __syncthreads();
    #pragma unroll
    for (int i = 0; i < 64; i += 4)
        T[(size_t)(n0 + ty + i) * DD + k0 + tx] = f2b(tile[tx][ty + i]);
}

// ---------------------------------------------------------------------------
// MFMA GEMM building blocks (R10 proven). A-tile 128 rows; B-tile BROWS rows.
// BK=64, XOR-swizzled linear LDS (rule 21).
template<int BROWS>
__device__ __forceinline__ void stage_tiles(const ushort* __restrict__ A,
                                            const ushort* __restrict__ BT,
                                            int bm, int bn, int k0,
                                            ushort* Asl, ushort* Bsl, int t) {
    #pragma unroll
    for (int r = 0; r < 4; r++) {
        int ch = r * 256 + t;
        int row = ch >> 3;
        int sw = ((ch & 7) ^ (row & 7)) << 3;
        GLD16(A + (size_t)(bm + row) * DD + k0 + sw, &Asl[ch * 8]);
    }
    #pragma unroll
    for (int r = 0; r < BROWS / 32; r++) {
        int ch = r * 256 + t;
        int row = ch >> 3;
        int sw = ((ch & 7) ^ (row & 7)) << 3;
        GLD16(BT + (size_t)(bn + row) * DD + k0 + sw, &Bsl[ch * 8]);
    }
}

template<int NACC>
__device__ __forceinline__ void compute_tiles(const ushort* Asl, const ushort* Bsl,
                                              f32x4 (&acc)[4][NACC],
                                              int wr, int wc, int lr, int lk) {
    #pragma unroll
    for (int kk = 0; kk < 2; kk++) {
        int ch16 = kk * 4 + lk;
        short8v a[4], b[NACC];
        #pragma unroll
        for (int m = 0; m < 4; m++) {
            int ra = wr + m * 16 + lr;
            a[m] = *(const short8v*)&Asl[ra * 64 + ((ch16 ^ (ra & 7)) << 3)];
        }
        #pragma unroll
        for (int n = 0; n < NACC; n++) {
            int rb = wc + n * 16 + lr;
            b[n] = *(const short8v*)&Bsl[rb * 64 + ((ch16 ^ (rb & 7)) << 3)];
        }
        #pragma unroll
        for (int m = 0; m < 4; m++)
            #pragma unroll
            for (int n = 0; n < NACC; n++)
                acc[m][n] = __builtin_amdgcn_mfma_f32_16x16x32_bf16(a[m], b[n], acc[m][n], 0, 0, 0);
    }
}

// ---------------------------------------------------------------------------
// Gate tables, 128x64 tile, counted-vmcnt 2-buffer pipeline (R10 proven).
__global__ __launch_bounds__(256) void mfma_tables_kernel(
        const ushort* __restrict__ instB, const ushort* __restrict__ WiT,
        const ushort* __restrict__ phraB, const ushort* __restrict__ WpT,
        const float* __restrict__ biascat,
        ushort* __restrict__ TiB, ushort* __restrict__ TpB) {
    __shared__ ushort Asl[2][128 * 64];
    __shared__ ushort Bsl[2][64 * 64];
    int bx = blockIdx.x;
    const ushort *A, *BT; ushort* C; const float* bias;
    if (bx < NN / 128) { A = instB; BT = WiT; C = TiB; bias = nullptr; }
    else { bx -= NN / 128; A = phraB; BT = WpT; C = TpB; bias = biascat; }
    int bm = bx * 128, bn = blockIdx.y * 64;
    int t = threadIdx.x;
    const int lane = t & 63, w = t >> 6;
    const int wr = (w >> 1) * 64, wc = (w & 1) * 32;
    const int lr = lane & 15, lk = lane >> 4;
    f32x4 acc[4][2] = {};

    int cur = 0;
    stage_tiles<64>(A, BT, bm, bn, 0, Asl[0], Bsl[0], t);
    for (int k0 = 0; k0 < DD; k0 += 64) {
        int nxt = cur ^ 1;
        if (k0 + 64 < DD) {
            stage_tiles<64>(A, BT, bm, bn, k0 + 64, Asl[nxt], Bsl[nxt], t);
            ASM_VMCNT(6);
        } else {
            ASM_VMCNT(0);
        }
        BARRIER();
        compute_tiles<2>(Asl[cur], Bsl[cur], acc, wr, wc, lr, lk);
        BARRIER();
        cur = nxt;
    }
    #pragma unroll
    for (int m = 0; m < 4; m++) {
        int row = bm + wr + m * 16 + lk * 4;
        #pragma unroll
        for (int n = 0; n < 2; n++) {
            int col = bn + wc + n * 16 + lr;
            float bv = bias ? bias[col] : 0.f;
            #pragma unroll
            for (int r = 0; r < 4; r++)
                C[(size_t)(row + r) * G4 + col] = f2b(acc[m][n][r] + bv);
        }
    }
}

// ---------------------------------------------------------------------------
// Fused refine: out = msg + relu(msg@W1+b1) + relu(feat@W2+b2).
// 128x64 tile (768 blocks), continuous counted-vmcnt pipeline (R10 proven).
__global__ __launch_bounds__(256) void mfma_refine_kernel(
        const ushort* __restrict__ imsgB, const ushort* __restrict__ instB,
        const ushort* __restrict__ iw1T, const ushort* __restrict__ iw2T,
        const float* __restrict__ ib1, const float* __restrict__ ib2,
        float* __restrict__ iout,
        const ushort* __restrict__ pmsgB, const ushort* __restrict__ phraB,
        const ushort* __restrict__ pw1T, const ushort* __restrict__ pw2T,
        const float* __restrict__ pb1, const float* __restrict__ pb2,
        float* __restrict__ pout) {
    __shared__ ushort Asl[2][128 * 64];
    __shared__ ushort Bsl[2][64 * 64];
    int bx = blockIdx.x;
    const ushort *Am, *Af, *W1, *W2; const float *b1, *b2; float* out;
    if (bx < NN / 128) {
        Am = imsgB; Af = instB; W1 = iw1T; W2 = iw2T; b1 = ib1; b2 = ib2; out = iout;
    } else {
        bx -= NN / 128;
        Am = pmsgB; Af = phraB; W1 = pw1T; W2 = pw2T; b1 = pb1; b2 = pb2; out = pout;
    }
    int bm = bx * 128, bn = blockIdx.y * 64;
    int t = threadIdx.x;
    const int lane = t & 63, w = t >> 6;
    const int wr = (w >> 1) * 64, wc = (w & 1) * 32;
    const int lr = lane & 15, lk = lane >> 4;
    f32x4 acc1[4][2] = {};
    f32x4 acc2[4][2] = {};

    int cur = 0;
    stage_tiles<64>(Am, W1, bm, bn, 0, Asl[0], Bsl[0], t);
    auto run = [&](const ushort* A, const ushort* B, f32x4 (&acc)[4][2],
                   const ushort* An, const ushort* Bn) {
        for (int k0 = 0; k0 < DD; k0 += 64) {
            int nxt = cur ^ 1;
            if (k0 + 64 < DD) {
                stage_tiles<64>(A, B, bm, bn, k0 + 64, Asl[nxt], Bsl[nxt], t);
                ASM_VMCNT(6);
            } else if (An) {
                stage_tiles<64>(An, Bn, bm, bn, 0, Asl[nxt], Bsl[nxt], t);
                ASM_VMCNT(6);
            } else {
                ASM_VMCNT(0);
            }
            BARRIER();
            compute_tiles<2>(Asl[cur], Bsl[cur], acc, wr, wc, lr, lk);
            BARRIER();
            cur = nxt;
        }
    };
    run(Am, W1, acc1, Af, W2);
    run(Af, W2, acc2, nullptr, nullptr);

    #pragma unroll
    for (int m = 0; m < 4; m++) {
        int row = bm + wr + m * 16 + lk * 4;
        #pragma unroll
        for (int n = 0; n < 2; n++) {
            int col = bn + wc + n * 16 + lr;
            float vb1 = b1[col], vb2 = b2[col];
            #pragma unroll
            for (int r = 0; r < 4; r++) {
                float v = b2f(Am[(size_t)(row + r) * DD + col])
                        + fmaxf(acc1[m][n][r] + vb1, 0.f)
                        + fmaxf(acc2[m][n][r] + vb2, 0.f);
                out[(size_t)(row + r) * DD + col] = v;
            }
        }
    }
}

// ---------------------------------------------------------------------------
// Counting sort: histogram + scan (scatter fused into gate_kernel atomics).
__global__ void hist_kernel(const int* __restrict__ s_idx, const int* __restrict__ o_idx,
                            const int* __restrict__ c_idx,
                            int* cntS, int* cntO, int* cntC) {
    int e = blockIdx.x * blockDim.x + threadIdx.x;
    if (e >= EE) return;
    atomicAdd(&cntS[s_idx[e]], 1);
    atomicAdd(&cntO[o_idx[e]], 1);
    atomicAdd(&cntC[c_idx[e]], 1);
}

__global__ __launch_bounds__(1024) void scan3_kernel(
        const int* __restrict__ cntS, const int* __restrict__ cntO,
        const int* __restrict__ cntC,
        int* __restrict__ startS, int* __restrict__ startO, int* __restrict__ startC) {
    const int* cnt; int* start; int n;
    if (blockIdx.x == 0)      { cnt = cntS; start = startS; n = NN; }
    else if (blockIdx.x == 1) { cnt = cntO; start = startO; n = NN; }
    else                      { cnt = cntC; start = startC; n = PP; }
    __shared__ int sh[1024];
    int t = threadIdx.x;
    int per = n >> 10;
    int base = t * per;
    int s = 0;
    for (int i = 0; i < per; i++) s += cnt[base + i];
    sh[t] = s;
    __syncthreads();
    for (int off = 1; off < 1024; off <<= 1) {
        int v = (t >= off) ? sh[t - off] : 0;
        __syncthreads();
        sh[t] += v;
        __syncthreads();
    }
    int ex = (t == 0) ? 0 : sh[t - 1];
    for (int i = 0; i < per; i++) { start[base + i] = ex; ex += cnt[base + i]; }
    if (t == 1023) start[n] = ex;
}

// ---------------------------------------------------------------------------
// Per-edge gates (R10 structure + R13 fast-rcp sigmoid, both proven).
__global__ __launch_bounds__(256) void gate_kernel(
        const int* __restrict__ s_idx, const int* __restrict__ o_idx,
        const int* __restrict__ c_idx,
        const int* __restrict__ startS, const int* __restrict__ startO,
        const int* __restrict__ startC,
        int* __restrict__ curS, int* __restrict__ curO, int* __restrict__ curC,
        const ushort* __restrict__ Ti, const ushort* __restrict__ Tp,
        int2* __restrict__ pkS, int2* __restrict__ pkO, int4* __restrict__ pkC) {
    int gid = blockIdx.x * 256 + threadIdx.x;
    int e = gid >> 6, lane = gid & 63;
    if (e >= EE) return;
    int s = s_idx[e], o = o_idx[e], c = c_idx[e];
    const unsigned int* tpc = (const unsigned int*)(Tp + (size_t)c * G4);
    const unsigned int* tis = (const unsigned int*)(Ti + (size_t)s * G4);
    const unsigned int* tio = (const unsigned int*)(Ti + (size_t)o * G4);
    float s0 = pairSig(tpc[lane],       tis[lane]);
    float s1 = pairSig(tpc[64 + lane],  tio[64 + lane]);
    float s2 = pairSig(tpc[128 + lane], tio[128 + lane]);
    float s3 = pairSig(tpc[192 + lane], tis[192 + lane]);
    #pragma unroll
    for (int off = 32; off; off >>= 1) {
        s0 += __shfl_xor(s0, off);
        s1 += __shfl_xor(s1, off);
        s2 += __shfl_xor(s2, off);
        s3 += __shfl_xor(s3, off);
    }
    if (lane == 0) {
        const float inv = 1.0f / 128.0f;
        int ps = startS[s] + atomicAdd(&curS[s], 1);
        int po = startO[o] + atomicAdd(&curO[o], 1);
        int pc = startC[c] + atomicAdd(&curC[c], 1);
        pkS[ps] = make_int2(c, __float_as_int(s0 * inv));
        pkO[po] = make_int2(c, __float_as_int(s1 * inv));
        pkC[pc] = make_int4(o, s, __float_as_int(s2 * inv), __float_as_int(s3 * inv));
    }
}

// ---------------------------------------------------------------------------
// Segment means, D-quartered + XCD-pinned (R8 traffic win), 2 edges per
// wave-step (R10).  R14/R15: pk entries staged in LDS with ZERO-GATE PADDING
// (kills shfl broadcasts and per-j guard ternaries).  R15 fix: phra side's
// two waves split the edge list into CONTIGUOUS HALVES again (R14 had both
// waves over the full list -> pmsg doubled, Output-1 absmax 0.39).
__device__ __forceinline__ void acc8(float* a, uint4 v, float g) {
    a[0] += g * lo16(v.x); a[1] += g * hi16(v.x);
    a[2] += g * lo16(v.y); a[3] += g * hi16(v.y);
    a[4] += g * lo16(v.z); a[5] += g * hi16(v.z);
    a[6] += g * lo16(v.w); a[7] += g * hi16(v.w);
}

__global__ __launch_bounds__(256) void seg_kernel(
        const ushort* __restrict__ phraB, const ushort* __restrict__ instB,
        const int2* __restrict__ pkS, const int* __restrict__ startS,
        const int2* __restrict__ pkO, const int* __restrict__ startO,
        const int4* __restrict__ pkC, const int* __restrict__ startC,
        ushort* __restrict__ imsgB, ushort* __restrict__ pmsgB) {
    __shared__ float lds[4][32 * 9];
    __shared__ int4 pkLds[4][64];          // 1 KB per wave
    int bid = blockIdx.x;
    int x = bid & 7;
    int q = x >> 1;
    int sub = ((bid >> 3) << 1) + (x & 1);
    int qoff = q * 256;
    int w = threadIdx.x >> 6, lane = threadIdx.x & 63;
    int half = lane >> 5, l32 = lane & 31;
    float a[8];
    #pragma unroll
    for (int k = 0; k < 8; k++) a[k] = 0.f;
    bool instSide = sub < NN / 2;
    int lenScale;
    ushort* msgB;
    int base2;
    if (instSide) {
        int node = sub * 2 + (w >> 1);
        const int2* pk_list = (w & 1) ? pkO : pkS;
        const int*  start   = (w & 1) ? startO : startS;
        int b = start[node], e = start[node + 1];
        lenScale = e - b;
        int2* myPk = (int2*)&pkLds[w][0];
        for (int base = b; base < e; base += 64) {
            int n = min(64, e - base);
            int2 pkv = (lane < n) ? pk_list[base + lane] : make_int2(0, 0);
            myPk[lane] = pkv;
            int nst = (n + 1) & ~1;
            int2 pe = myPk[half];
            uint4 v = *(const uint4*)(phraB + (size_t)pe.x * DD + qoff + l32 * 8);
            for (int j = 2; j < nst; j += 2) {
                int2 pen = myPk[j + half];
                uint4 vn = *(const uint4*)(phraB + (size_t)pen.x * DD + qoff + l32 * 8);
                acc8(a, v, __int_as_float(pe.y));
                pe = pen; v = vn;
            }
            acc8(a, v, __int_as_float(pe.y));
        }
        msgB = imsgB; base2 = sub * 2;
    } else {
        int pbx = sub - NN / 2;
        int p = pbx * 2 + (w >> 1);
        int cb = startC[p], ce = startC[p + 1];
        lenScale = ce - cb;
        int mid = cb + ((ce - cb) >> 1);
        int mb = (w & 1) ? mid : cb;       // contiguous halves per wave (R15 fix)
        int me = (w & 1) ? ce : mid;
        int4* myPk = &pkLds[w][0];
        for (int base = mb; base < me; base += 64) {
            int n = min(64, me - base);
            int4 pkv = (lane < n) ? pkC[base + lane] : make_int4(0, 0, 0, 0);
            myPk[lane] = pkv;
            int nst = (n + 1) & ~1;
            int4 pe = myPk[half];
            uint4 vo = *(const uint4*)(instB + (size_t)pe.x * DD + qoff + l32 * 8);
            uint4 vs = *(const uint4*)(instB + (size_t)pe.y * DD + qoff + l32 * 8);
            for (int j = 2; j < nst; j += 2) {
                int4 pen = myPk[j + half];
                uint4 vno = *(const uint4*)(instB + (size_t)pen.x * DD + qoff + l32 * 8);
                uint4 vns = *(const uint4*)(instB + (size_t)pen.y * DD + qoff + l32 * 8);
                acc8(a, vo, __int_as_float(pe.z));
                acc8(a, vs, __int_as_float(pe.w));
                pe = pen; vo = vno; vs = vns;
            }
            acc8(a, vo, __int_as_float(pe.z));
            acc8(a, vs, __int_as_float(pe.w));
        }
        msgB = pmsgB; base2 = pbx * 2;
    }
    // combine lane halves (entries j and j+1 partial sums share dims)
    #pragma unroll
    for (int k = 0; k < 8; k++) a[k] += __shfl_xor(a[k], 32);
    float scale = 0.5f / (float)max(lenScale, 1);
    if (half == 0) {
        #pragma unroll
        for (int k = 0; k < 8; k++) lds[w][l32 * 9 + k] = a[k] * scale;
    }
    __syncthreads();
    if (threadIdx.x < 64) {
        int nodeSel = threadIdx.x >> 5;
        int l = threadIdx.x & 31;
        int w0 = nodeSel * 2;
        float s0 = lds[w0][l * 9 + 0] + lds[w0 + 1][l * 9 + 0];
        float s1 = lds[w0][l * 9 + 1] + lds[w0 + 1][l * 9 + 1];
        float s2 = lds[w0][l * 9 + 2] + lds[w0 + 1][l * 9 + 2];
        float s3 = lds[w0][l * 9 + 3] + lds[w0 + 1][l * 9 + 3];
        float s4 = lds[w0][l * 9 + 4] + lds[w0 + 1][l * 9 + 4];
        float s5 = lds[w0][l * 9 + 5] + lds[w0 + 1][l * 9 + 5];
        float s6 = lds[w0][l * 9 + 6] + lds[w0 + 1][l * 9 + 6];
        float s7 = lds[w0][l * 9 + 7] + lds[w0 + 1][l * 9 + 7];
        uint4 o;
        o.x = pack2(s0, s1);
        o.y = pack2(s2, s3);
        o.z = pack2(s4, s5);
        o.w = pack2(s6, s7);
        *(uint4*)&msgB[(size_t)(base2 + nodeSel) * DD + qoff + l * 8] = o;
    }
}

// ---------------------------------------------------------------------------
extern "C" void kernel_launch(void* const* d_in, const int* in_sizes, int n_in,
                              void* d_out, int out_size, void* d_ws, size_t ws_size,
                              hipStream_t stream) {
    (void)in_sizes; (void)n_in; (void)out_size; (void)ws_size;
    const float* inst_feat = (const float*)d_in[0];
    const float* phra_feat = (const float*)d_in[1];
    const int*   conn      = (const int*)d_in[2];
    const int*   clu       = (const int*)d_in[3];
    const float* psW = (const float*)d_in[4];  const float* psB = (const float*)d_in[5];
    const float* poW = (const float*)d_in[6];  const float* poB = (const float*)d_in[7];
    const float* opW = (const float*)d_in[8];  const float* opB = (const float*)d_in[9];
    const float* spW = (const float*)d_in[10]; const float* spB = (const float*)d_in[11];
    const float* iw1W = (const float*)d_in[12]; const float* iw1B = (const float*)d_in[13];
    const float* iw2W = (const float*)d_in[14]; const float* iw2B = (const float*)d_in[15];
    const float* pw1W = (const float*)d_in[16]; const float* pw1B = (const float*)d_in[17];
    const float* pw2W = (const float*)d_in[18]; const float* pw2B = (const float*)d_in[19];
    const int* s_idx = conn;
    const int* o_idx = conn + EE;

    char* ws = (char*)d_ws;
    size_t off = 0;
    auto alloc = [&](size_t bytes) {
        char* p = ws + off;
        off += (bytes + 255) & ~(size_t)255;
        return p;
    };
    ushort* instB = (ushort*)alloc((size_t)NN * DD * 2);
    ushort* phraB = (ushort*)alloc((size_t)PP * DD * 2);
    ushort* WiT   = (ushort*)alloc((size_t)G4 * DD * 2);
    ushort* WpT   = (ushort*)alloc((size_t)G4 * DD * 2);
    ushort* iw1T  = (ushort*)alloc((size_t)DD * DD * 2);
    ushort* iw2T  = (ushort*)alloc((size_t)DD * DD * 2);
    ushort* pw1T  = (ushort*)alloc((size_t)DD * DD * 2);
    ushort* pw2T  = (ushort*)alloc((size_t)DD * DD * 2);
    float* biascat = (float*)alloc(G4 * 4);
    ushort* TiB   = (ushort*)alloc((size_t)NN * G4 * 2);
    ushort* TpB   = (ushort*)alloc((size_t)PP * G4 * 2);
    int* cntBlock = (int*)alloc((size_t)NCNT * 4);
    int* cntS = cntBlock;      int* cntO = cntS + NN;  int* cntC = cntO + NN;
    int* curS = cntC + PP;     int* curO = curS + NN;  int* curC = curO + NN;
    int* startS = (int*)alloc((NN + 1) * 4);
    int* startO = (int*)alloc((NN + 1) * 4);
    int* startC = (int*)alloc((PP + 1) * 4);
    int2* pkS   = (int2*)alloc((size_t)EE * 8);
    int2* pkO   = (int2*)alloc((size_t)EE * 8);
    int4* pkC   = (int4*)alloc((size_t)EE * 16);
    ushort* imsgB = (ushort*)alloc((size_t)NN * DD * 2);
    ushort* pmsgB = (ushort*)alloc((size_t)PP * DD * 2);

    float* inst_out = (float*)d_out;
    float* phra_out = inst_out + (size_t)NN * DD;

    // Fused prep: counter zeroing + bf16 casts + weight pack/transpose
    prep_kernel<<<NB_ZERO + NB_F2B + NB_PACK + NB_WT, 256, 0, stream>>>(
        cntBlock, inst_feat, phra_feat, instB, phraB,
        psW, poW, opW, spW, psB, poB, opB, spB, WiT, WpT, biascat,
        iw1W, iw2W, pw1W, pw2W, iw1T, iw2T, pw1T, pw2T);

    // CSR build (scatter fused into gate_kernel atomics)
    hist_kernel<<<EE / 256, 256, 0, stream>>>(s_idx, o_idx, clu, cntS, cntO, cntC);
    scan3_kernel<<<3, 1024, 0, stream>>>(cntS, cntO, cntC, startS, startO, startC);

    // Gate tables (bf16 MFMA, bias folded into Tp; 2-buffer pipeline)
    mfma_tables_kernel<<<dim3((NN + PP) / 128, G4 / 64), 256, 0, stream>>>(
        instB, WiT, phraB, WpT, biascat, TiB, TpB);

    // Gates -> packed CSR entries (one wave/edge, fast-rcp sigmoid)
    gate_kernel<<<(EE * 64) / 256, 256, 0, stream>>>(
        s_idx, o_idx, clu, startS, startO, startC, curS, curO, curC,
        TiB, TpB, pkS, pkO, pkC);

    // Segment means (quartered, XCD-pinned, LDS-staged zero-pad pk pipeline)
    seg_kernel<<<(NN / 2 + PP / 2) * 4, 256, 0, stream>>>(
        phraB, instB, pkS, startS, pkO, startO, pkC, startC, imsgB, pmsgB);

    // Fused refine (128x64 tiles, 768 blocks, 2-buffer counted-vmcnt pipeline)
    mfma_refine_kernel<<<dim3((NN + PP) / 128, DD / 64), 256, 0, stream>>>(
        imsgB, instB, iw1T, iw2T, iw1B, iw2B, inst_out,
        pmsgB, phraB, pw1T, pw2T, pw1B, pw2B, phra_out);
}

// Round 16
// 139.798 us; speedup vs baseline: 1.4184x; 1.0174x over previous
//
#include <hip/hip_runtime.h>
#include <math.h>

// Problem constants (fixed by the reference)
constexpr int NN  = 4096;   // instances
constexpr int PP  = 2048;   // phrases
constexpr int EE  = 65536;  // edges
constexpr int DD  = 1024;   // feature dim
constexpr int OUTF = 128;   // gate MLP out dim
constexpr int G4  = 512;    // 4 gates * 128

typedef __attribute__((ext_vector_type(8))) short short8v;
typedef __attribute__((ext_vector_type(4))) float f32x4;

// sigmoid(relu(z)) with fast rcp (v_rcp_f32, ~1 ulp; bf16 rounding dominates).
__device__ __forceinline__ float sigmoid_relu(float z) {
    z = fmaxf(z, 0.0f);
    return __builtin_amdgcn_rcpf(1.0f + __expf(-z));
}
__device__ __forceinline__ float b2f(ushort u) {
    return __uint_as_float(((unsigned int)u) << 16);
}
__device__ __forceinline__ ushort f2b(float f) {  // RNE
    unsigned int x = __float_as_uint(f);
    return (ushort)((x + 0x7fffu + ((x >> 16) & 1u)) >> 16);
}
__device__ __forceinline__ unsigned int pack2(float a, float b) {
    return (unsigned int)f2b(a) | ((unsigned int)f2b(b) << 16);
}
__device__ __forceinline__ float lo16(unsigned int u) { return __uint_as_float(u << 16); }
__device__ __forceinline__ float hi16(unsigned int u) { return __uint_as_float(u & 0xffff0000u); }
__device__ __forceinline__ float pairSig(unsigned int a, unsigned int b) {
    return sigmoid_relu(lo16(a) + lo16(b)) + sigmoid_relu(hi16(a) + hi16(b));
}

#define GLD16(gptr, lptr) \
    __builtin_amdgcn_global_load_lds((__attribute__((address_space(1))) const void*)(gptr), \
                                     (__attribute__((address_space(3))) void*)(lptr), 16, 0, 0)
// Counted-vmcnt pipeline primitives (T4): keep just-issued loads in flight.
#define ASM_VMCNT(n) asm volatile("s_waitcnt vmcnt(" #n ")" ::: "memory")
#define BARRIER() do { asm volatile("" ::: "memory"); \
                       __builtin_amdgcn_s_barrier();  \
                       asm volatile("" ::: "memory"); } while (0)

// ---------------------------------------------------------------------------
// Fused prep: counter zeroing, f32->bf16 features, gate-weight pack
// (R16: 64x64 LDS tile-transpose -- the old per-element gather read W at
// stride 512 B = 16x overfetch, ~67 MB for 4.2 MB of data), bias, refine-
// weight transpose.
constexpr int NCNT    = 2 * (NN + NN + PP);        // 20480 ints (cnt + cur)
constexpr int NB_ZERO = NCNT / 256;                // 80
constexpr int NB_F2B  = (NN + PP) * DD / 4 / 256;  // 6144
constexpr int NB_GW   = 4 * 32 * 2;                // 256: 4 mats x 32 ktiles x 2 jtiles
constexpr int NB_BIAS = 2;
constexpr int NB_WT   = 4 * (DD / 64) * (DD / 64); // 1024

__global__ __launch_bounds__(256) void prep_kernel(
        int* __restrict__ cntBlock,
        const float* __restrict__ instF, const float* __restrict__ phraF,
        ushort* __restrict__ instB, ushort* __restrict__ phraB,
        const float* __restrict__ psW, const float* __restrict__ poW,
        const float* __restrict__ opW, const float* __restrict__ spW,
        const float* __restrict__ psB, const float* __restrict__ poB,
        const float* __restrict__ opB, const float* __restrict__ spB,
        ushort* __restrict__ WiT, ushort* __restrict__ WpT,
        float* __restrict__ biascat,
        const float* __restrict__ W0, const float* __restrict__ W1,
        const float* __restrict__ W2, const float* __restrict__ W3,
        ushort* __restrict__ T0, ushort* __restrict__ T1,
        ushort* __restrict__ T2, ushort* __restrict__ T3) {
    __shared__ float tile[64][65];
    int b = blockIdx.x, t = threadIdx.x;
    if (b < NB_ZERO) {
        cntBlock[b * 256 + t] = 0;
        return;
    }
    b -= NB_ZERO;
    if (b < NB_F2B) {
        int i = b * 256 + t;
        constexpr int na4 = NN * DD / 4;
        if (i < na4) {
            float4 v = ((const float4*)instF)[i];
            ushort4 u; u.x = f2b(v.x); u.y = f2b(v.y); u.z = f2b(v.z); u.w = f2b(v.w);
            ((ushort4*)instB)[i] = u;
        } else {
            int j = i - na4;
            float4 v = ((const float4*)phraF)[j];
            ushort4 u; u.x = f2b(v.x); u.y = f2b(v.y); u.z = f2b(v.z); u.w = f2b(v.w);
            ((ushort4*)phraB)[j] = u;
        }
        return;
    }
    b -= NB_F2B;
    if (b < NB_GW) {
        // Gate-weight pack via coalesced 64x64 tile transpose.
        int m  = b >> 6;            // source matrix 0..3 (ps,po,op,sp)
        int rest = b & 63;
        int kt = rest >> 1;         // source row-tile 0..31 (rows r0..r0+63 of 2048)
        int jt = rest & 1;          // col-tile 0..1 (cols j0..j0+63 of 128)
        const float* W = (m == 0) ? psW : (m == 1) ? poW : (m == 2) ? opW : spW;
        int r0 = kt * 64, j0 = jt * 64;
        int tx = t & 63, ty = t >> 6;  // 64 cols x 4 rows per pass
        #pragma unroll
        for (int i = 0; i < 64; i += 4)
            tile[ty + i][tx] = W[(size_t)(r0 + ty + i) * OUTF + j0 + tx];
        __syncthreads();
        bool top = (r0 < DD);
        int kbase = top ? r0 : r0 - DD;
        // top half (k=r): ps/po -> Wp, op/sp -> Wi; bottom half: swapped.
        ushort* T = top ? ((m < 2) ? WpT : WiT) : ((m < 2) ? WiT : WpT);
        #pragma unroll
        for (int i = 0; i < 64; i += 4)
            T[(size_t)(m * OUTF + j0 + ty + i) * DD + kbase + tx] = f2b(tile[tx][ty + i]);
        return;
    }
    b -= NB_GW;
    if (b < NB_BIAS) {
        int idx = b * 256 + t;      // 0..511
        int gg = idx >> 7, jj = idx & 127;
        biascat[idx] = (gg == 0) ? psB[jj] : (gg == 1) ? poB[jj]
                     : (gg == 2) ? opB[jj] : spB[jj];
        return;
    }
    b -= NB_BIAS;
    int z = b >> 8, rest = b & 255;
    const float* W = (z == 0) ? W0 : (z == 1) ? W1 : (z == 2) ? W2 : W3;
    ushort*      T = (z == 0) ? T0 : (z == 1) ? T1 : (z == 2) ? T2 : T3;
    int k0 = (rest & 15) * 64, n0 = (rest >> 4) * 64;
    int tx = t & 63, ty = t >> 6;
    #pragma unroll
    for (int i = 0; i < 64; i += 4)
        tile[ty + i][tx] = W[(size_t)(k0 + ty + i) * DD + n0 + tx];
    __syncthreads();
    #pragma unroll
    for (int i = 0; i < 64; i += 4)
        T[(size_t)(n0 + ty + i) * DD + k0 + tx] = f2b(tile[tx][ty + i]);
}

// ---------------------------------------------------------------------------
// MFMA GEMM building blocks (R10 proven). A-tile 128 rows; B-tile BROWS rows.
// BK=64, XOR-swizzled linear LDS (rule 21).
template<int BROWS>
__device__ __forceinline__ void stage_tiles(const ushort* __restrict__ A,
                                            const ushort* __restrict__ BT,
                                            int bm, int bn, int k0,
                                            ushort* Asl, ushort* Bsl, int t) {
    #pragma unroll
    for (int r = 0; r < 4; r++) {
        int ch = r * 256 + t;
        int row = ch >> 3;
        int sw = ((ch & 7) ^ (row & 7)) << 3;
        GLD16(A + (size_t)(bm + row) * DD + k0 + sw, &Asl[ch * 8]);
    }
    #pragma unroll
    for (int r = 0; r < BROWS / 32; r++) {
        int ch = r * 256 + t;
        int row = ch >> 3;
        int sw = ((ch & 7) ^ (row & 7)) << 3;
        GLD16(BT + (size_t)(bn + row) * DD + k0 + sw, &Bsl[ch * 8]);
    }
}

template<int NACC>
__device__ __forceinline__ void compute_tiles(const ushort* Asl, const ushort* Bsl,
                                              f32x4 (&acc)[4][NACC],
                                              int wr, int wc, int lr, int lk) {
    #pragma unroll
    for (int kk = 0; kk < 2; kk++) {
        int ch16 = kk * 4 + lk;
        short8v a[4], b[NACC];
        #pragma unroll
        for (int m = 0; m < 4; m++) {
            int ra = wr + m * 16 + lr;
            a[m] = *(const short8v*)&Asl[ra * 64 + ((ch16 ^ (ra & 7)) << 3)];
        }
        #pragma unroll
        for (int n = 0; n < NACC; n++) {
            int rb = wc + n * 16 + lr;
            b[n] = *(const short8v*)&Bsl[rb * 64 + ((ch16 ^ (rb & 7)) << 3)];
        }
        #pragma unroll
        for (int m = 0; m < 4; m++)
            #pragma unroll
            for (int n = 0; n < NACC; n++)
                acc[m][n] = __builtin_amdgcn_mfma_f32_16x16x32_bf16(a[m], b[n], acc[m][n], 0, 0, 0);
    }
}

// ---------------------------------------------------------------------------
// Gate tables, 128x64 tile, counted-vmcnt 2-buffer pipeline (R10 proven).
__global__ __launch_bounds__(256) void mfma_tables_kernel(
        const ushort* __restrict__ instB, const ushort* __restrict__ WiT,
        const ushort* __restrict__ phraB, const ushort* __restrict__ WpT,
        const float* __restrict__ biascat,
        ushort* __restrict__ TiB, ushort* __restrict__ TpB) {
    __shared__ ushort Asl[2][128 * 64];
    __shared__ ushort Bsl[2][64 * 64];
    int bx = blockIdx.x;
    const ushort *A, *BT; ushort* C; const float* bias;
    if (bx < NN / 128) { A = instB; BT = WiT; C = TiB; bias = nullptr; }
    else { bx -= NN / 128; A = phraB; BT = WpT; C = TpB; bias = biascat; }
    int bm = bx * 128, bn = blockIdx.y * 64;
    int t = threadIdx.x;
    const int lane = t & 63, w = t >> 6;
    const int wr = (w >> 1) * 64, wc = (w & 1) * 32;
    const int lr = lane & 15, lk = lane >> 4;
    f32x4 acc[4][2] = {};

    int cur = 0;
    stage_tiles<64>(A, BT, bm, bn, 0, Asl[0], Bsl[0], t);
    for (int k0 = 0; k0 < DD; k0 += 64) {
        int nxt = cur ^ 1;
        if (k0 + 64 < DD) {
            stage_tiles<64>(A, BT, bm, bn, k0 + 64, Asl[nxt], Bsl[nxt], t);
            ASM_VMCNT(6);
        } else {
            ASM_VMCNT(0);
        }
        BARRIER();
        compute_tiles<2>(Asl[cur], Bsl[cur], acc, wr, wc, lr, lk);
        BARRIER();
        cur = nxt;
    }
    #pragma unroll
    for (int m = 0; m < 4; m++) {
        int row = bm + wr + m * 16 + lk * 4;
        #pragma unroll
        for (int n = 0; n < 2; n++) {
            int col = bn + wc + n * 16 + lr;
            float bv = bias ? bias[col] : 0.f;
            #pragma unroll
            for (int r = 0; r < 4; r++)
                C[(size_t)(row + r) * G4 + col] = f2b(acc[m][n][r] + bv);
        }
    }
}

// ---------------------------------------------------------------------------
// Fused refine: out = msg + relu(msg@W1+b1) + relu(feat@W2+b2).
// 128x64 tile (768 blocks), continuous counted-vmcnt pipeline (R10 proven).
__global__ __launch_bounds__(256) void mfma_refine_kernel(
        const ushort* __restrict__ imsgB, const ushort* __restrict__ instB,
        const ushort* __restrict__ iw1T, const ushort* __restrict__ iw2T,
        const float* __restrict__ ib1, const float* __restrict__ ib2,
        float* __restrict__ iout,
        const ushort* __restrict__ pmsgB, const ushort* __restrict__ phraB,
        const ushort* __restrict__ pw1T, const ushort* __restrict__ pw2T,
        const float* __restrict__ pb1, const float* __restrict__ pb2,
        float* __restrict__ pout) {
    __shared__ ushort Asl[2][128 * 64];
    __shared__ ushort Bsl[2][64 * 64];
    int bx = blockIdx.x;
    const ushort *Am, *Af, *W1, *W2; const float *b1, *b2; float* out;
    if (bx < NN / 128) {
        Am = imsgB; Af = instB; W1 = iw1T; W2 = iw2T; b1 = ib1; b2 = ib2; out = iout;
    } else {
        bx -= NN / 128;
        Am = pmsgB; Af = phraB; W1 = pw1T; W2 = pw2T; b1 = pb1; b2 = pb2; out = pout;
    }
    int bm = bx * 128, bn = blockIdx.y * 64;
    int t = threadIdx.x;
    const int lane = t & 63, w = t >> 6;
    const int wr = (w >> 1) * 64, wc = (w & 1) * 32;
    const int lr = lane & 15, lk = lane >> 4;
    f32x4 acc1[4][2] = {};
    f32x4 acc2[4][2] = {};

    int cur = 0;
    stage_tiles<64>(Am, W1, bm, bn, 0, Asl[0], Bsl[0], t);
    auto run = [&](const ushort* A, const ushort* B, f32x4 (&acc)[4][2],
                   const ushort* An, const ushort* Bn) {
        for (int k0 = 0; k0 < DD; k0 += 64) {
            int nxt = cur ^ 1;
            if (k0 + 64 < DD) {
                stage_tiles<64>(A, B, bm, bn, k0 + 64, Asl[nxt], Bsl[nxt], t);
                ASM_VMCNT(6);
            } else if (An) {
                stage_tiles<64>(An, Bn, bm, bn, 0, Asl[nxt], Bsl[nxt], t);
                ASM_VMCNT(6);
            } else {
                ASM_VMCNT(0);
            }
            BARRIER();
            compute_tiles<2>(Asl[cur], Bsl[cur], acc, wr, wc, lr, lk);
            BARRIER();
            cur = nxt;
        }
    };
    run(Am, W1, acc1, Af, W2);
    run(Af, W2, acc2, nullptr, nullptr);

    #pragma unroll
    for (int m = 0; m < 4; m++) {
        int row = bm + wr + m * 16 + lk * 4;
        #pragma unroll
        for (int n = 0; n < 2; n++) {
            int col = bn + wc + n * 16 + lr;
            float vb1 = b1[col], vb2 = b2[col];
            #pragma unroll
            for (int r = 0; r < 4; r++) {
                float v = b2f(Am[(size_t)(row + r) * DD + col])
                        + fmaxf(acc1[m][n][r] + vb1, 0.f)
                        + fmaxf(acc2[m][n][r] + vb2, 0.f);
                out[(size_t)(row + r) * DD + col] = v;
            }
        }
    }
}

// ---------------------------------------------------------------------------
// Counting sort: histogram + scan (scatter fused into gate_kernel atomics).
__global__ void hist_kernel(const int* __restrict__ s_idx, const int* __restrict__ o_idx,
                            const int* __restrict__ c_idx,
                            int* cntS, int* cntO, int* cntC) {
    int e = blockIdx.x * blockDim.x + threadIdx.x;
    if (e >= EE) return;
    atomicAdd(&cntS[s_idx[e]], 1);
    atomicAdd(&cntO[o_idx[e]], 1);
    atomicAdd(&cntC[c_idx[e]], 1);
}

__global__ __launch_bounds__(1024) void scan3_kernel(
        const int* __restrict__ cntS, const int* __restrict__ cntO,
        const int* __restrict__ cntC,
        int* __restrict__ startS, int* __restrict__ startO, int* __restrict__ startC) {
    const int* cnt; int* start; int n;
    if (blockIdx.x == 0)      { cnt = cntS; start = startS; n = NN; }
    else if (blockIdx.x == 1) { cnt = cntO; start = startO; n = NN; }
    else                      { cnt = cntC; start = startC; n = PP; }
    __shared__ int sh[1024];
    int t = threadIdx.x;
    int per = n >> 10;
    int base = t * per;
    int s = 0;
    for (int i = 0; i < per; i++) s += cnt[base + i];
    sh[t] = s;
    __syncthreads();
    for (int off = 1; off < 1024; off <<= 1) {
        int v = (t >= off) ? sh[t - off] : 0;
        __syncthreads();
        sh[t] += v;
        __syncthreads();
    }
    int ex = (t == 0) ? 0 : sh[t - 1];
    for (int i = 0; i < per; i++) { start[base + i] = ex; ex += cnt[base + i]; }
    if (t == 1023) start[n] = ex;
}

// ---------------------------------------------------------------------------
// Per-edge gates (R10 structure + R13 fast-rcp sigmoid, both proven).
__global__ __launch_bounds__(256) void gate_kernel(
        const int* __restrict__ s_idx, const int* __restrict__ o_idx,
        const int* __restrict__ c_idx,
        const int* __restrict__ startS, const int* __restrict__ startO,
        const int* __restrict__ startC,
        int* __restrict__ curS, int* __restrict__ curO, int* __restrict__ curC,
        const ushort* __restrict__ Ti, const ushort* __restrict__ Tp,
        int2* __restrict__ pkS, int2* __restrict__ pkO, int4* __restrict__ pkC) {
    int gid = blockIdx.x * 256 + threadIdx.x;
    int e = gid >> 6, lane = gid & 63;
    if (e >= EE) return;
    int s = s_idx[e], o = o_idx[e], c = c_idx[e];
    const unsigned int* tpc = (const unsigned int*)(Tp + (size_t)c * G4);
    const unsigned int* tis = (const unsigned int*)(Ti + (size_t)s * G4);
    const unsigned int* tio = (const unsigned int*)(Ti + (size_t)o * G4);
    float s0 = pairSig(tpc[lane],       tis[lane]);
    float s1 = pairSig(tpc[64 + lane],  tio[64 + lane]);
    float s2 = pairSig(tpc[128 + lane], tio[128 + lane]);
    float s3 = pairSig(tpc[192 + lane], tis[192 + lane]);
    #pragma unroll
    for (int off = 32; off; off >>= 1) {
        s0 += __shfl_xor(s0, off);
        s1 += __shfl_xor(s1, off);
        s2 += __shfl_xor(s2, off);
        s3 += __shfl_xor(s3, off);
    }
    if (lane == 0) {
        const float inv = 1.0f / 128.0f;
        int ps = startS[s] + atomicAdd(&curS[s], 1);
        int po = startO[o] + atomicAdd(&curO[o], 1);
        int pc = startC[c] + atomicAdd(&curC[c], 1);
        pkS[ps] = make_int2(c, __float_as_int(s0 * inv));
        pkO[po] = make_int2(c, __float_as_int(s1 * inv));
        pkC[pc] = make_int4(o, s, __float_as_int(s2 * inv), __float_as_int(s3 * inv));
    }
}

// ---------------------------------------------------------------------------
// Segment means, D-quartered + XCD-pinned (R8), LDS-staged zero-pad pk (R15),
// phra side split into contiguous halves per wave (R15 fix).
__device__ __forceinline__ void acc8(float* a, uint4 v, float g) {
    a[0] += g * lo16(v.x); a[1] += g * hi16(v.x);
    a[2] += g * lo16(v.y); a[3] += g * hi16(v.y);
    a[4] += g * lo16(v.z); a[5] += g * hi16(v.z);
    a[6] += g * lo16(v.w); a[7] += g * hi16(v.w);
}

__global__ __launch_bounds__(256) void seg_kernel(
        const ushort* __restrict__ phraB, const ushort* __restrict__ instB,
        const int2* __restrict__ pkS, const int* __restrict__ startS,
        const int2* __restrict__ pkO, const int* __restrict__ startO,
        const int4* __restrict__ pkC, const int* __restrict__ startC,
        ushort* __restrict__ imsgB, ushort* __restrict__ pmsgB) {
    __shared__ float lds[4][32 * 9];
    __shared__ int4 pkLds[4][64];          // 1 KB per wave
    int bid = blockIdx.x;
    int x = bid & 7;
    int q = x >> 1;
    int sub = ((bid >> 3) << 1) + (x & 1);
    int qoff = q * 256;
    int w = threadIdx.x >> 6, lane = threadIdx.x & 63;
    int half = lane >> 5, l32 = lane & 31;
    float a[8];
    #pragma unroll
    for (int k = 0; k < 8; k++) a[k] = 0.f;
    bool instSide = sub < NN / 2;
    int lenScale;
    ushort* msgB;
    int base2;
    if (instSide) {
        int node = sub * 2 + (w >> 1);
        const int2* pk_list = (w & 1) ? pkO : pkS;
        const int*  start   = (w & 1) ? startO : startS;
        int b = start[node], e = start[node + 1];
        lenScale = e - b;
        int2* myPk = (int2*)&pkLds[w][0];
        for (int base = b; base < e; base += 64) {
            int n = min(64, e - base);
            int2 pkv = (lane < n) ? pk_list[base + lane] : make_int2(0, 0);
            myPk[lane] = pkv;
            int nst = (n + 1) & ~1;
            int2 pe = myPk[half];
            uint4 v = *(const uint4*)(phraB + (size_t)pe.x * DD + qoff + l32 * 8);
            for (int j = 2; j < nst; j += 2) {
                int2 pen = myPk[j + half];
                uint4 vn = *(const uint4*)(phraB + (size_t)pen.x * DD + qoff + l32 * 8);
                acc8(a, v, __int_as_float(pe.y));
                pe = pen; v = vn;
            }
            acc8(a, v, __int_as_float(pe.y));
        }
        msgB = imsgB; base2 = sub * 2;
    } else {
        int pbx = sub - NN / 2;
        int p = pbx * 2 + (w >> 1);
        int cb = startC[p], ce = startC[p + 1];
        lenScale = ce - cb;
        int mid = cb + ((ce - cb) >> 1);
        int mb = (w & 1) ? mid : cb;       // contiguous halves per wave
        int me = (w & 1) ? ce : mid;
        int4* myPk = &pkLds[w][0];
        for (int base = mb; base < me; base += 64) {
            int n = min(64, me - base);
            int4 pkv = (lane < n) ? pkC[base + lane] : make_int4(0, 0, 0, 0);
            myPk[lane] = pkv;
            int nst = (n + 1) & ~1;
            int4 pe = myPk[half];
            uint4 vo = *(const uint4*)(instB + (size_t)pe.x * DD + qoff + l32 * 8);
            uint4 vs = *(const uint4*)(instB + (size_t)pe.y * DD + qoff + l32 * 8);
            for (int j = 2; j < nst; j += 2) {
                int4 pen = myPk[j + half];
                uint4 vno = *(const uint4*)(instB + (size_t)pen.x * DD + qoff + l32 * 8);
                uint4 vns = *(const uint4*)(instB + (size_t)pen.y * DD + qoff + l32 * 8);
                acc8(a, vo, __int_as_float(pe.z));
                acc8(a, vs, __int_as_float(pe.w));
                pe = pen; vo = vno; vs = vns;
            }
            acc8(a, vo, __int_as_float(pe.z));
            acc8(a, vs, __int_as_float(pe.w));
        }
        msgB = pmsgB; base2 = pbx * 2;
    }
    // combine lane halves (entries j and j+1 partial sums share dims)
    #pragma unroll
    for (int k = 0; k < 8; k++) a[k] += __shfl_xor(a[k], 32);
    float scale = 0.5f / (float)max(lenScale, 1);
    if (half == 0) {
        #pragma unroll
        for (int k = 0; k < 8; k++) lds[w][l32 * 9 + k] = a[k] * scale;
    }
    __syncthreads();
    if (threadIdx.x < 64) {
        int nodeSel = threadIdx.x >> 5;
        int l = threadIdx.x & 31;
        int w0 = nodeSel * 2;
        float s0 = lds[w0][l * 9 + 0] + lds[w0 + 1][l * 9 + 0];
        float s1 = lds[w0][l * 9 + 1] + lds[w0 + 1][l * 9 + 1];
        float s2 = lds[w0][l * 9 + 2] + lds[w0 + 1][l * 9 + 2];
        float s3 = lds[w0][l * 9 + 3] + lds[w0 + 1][l * 9 + 3];
        float s4 = lds[w0][l * 9 + 4] + lds[w0 + 1][l * 9 + 4];
        float s5 = lds[w0][l * 9 + 5] + lds[w0 + 1][l * 9 + 5];
        float s6 = lds[w0][l * 9 + 6] + lds[w0 + 1][l * 9 + 6];
        float s7 = lds[w0][l * 9 + 7] + lds[w0 + 1][l * 9 + 7];
        uint4 o;
        o.x = pack2(s0, s1);
        o.y = pack2(s2, s3);
        o.z = pack2(s4, s5);
        o.w = pack2(s6, s7);
        *(uint4*)&msgB[(size_t)(base2 + nodeSel) * DD + qoff + l * 8] = o;
    }
}

// ---------------------------------------------------------------------------
extern "C" void kernel_launch(void* const* d_in, const int* in_sizes, int n_in,
                              void* d_out, int out_size, void* d_ws, size_t ws_size,
                              hipStream_t stream) {
    (void)in_sizes; (void)n_in; (void)out_size; (void)ws_size;
    const float* inst_feat = (const float*)d_in[0];
    const float* phra_feat = (const float*)d_in[1];
    const int*   conn      = (const int*)d_in[2];
    const int*   clu       = (const int*)d_in[3];
    const float* psW = (const float*)d_in[4];  const float* psB = (const float*)d_in[5];
    const float* poW = (const float*)d_in[6];  const float* poB = (const float*)d_in[7];
    const float* opW = (const float*)d_in[8];  const float* opB = (const float*)d_in[9];
    const float* spW = (const float*)d_in[10]; const float* spB = (const float*)d_in[11];
    const float* iw1W = (const float*)d_in[12]; const float* iw1B = (const float*)d_in[13];
    const float* iw2W = (const float*)d_in[14]; const float* iw2B = (const float*)d_in[15];
    const float* pw1W = (const float*)d_in[16]; const float* pw1B = (const float*)d_in[17];
    const float* pw2W = (const float*)d_in[18]; const float* pw2B = (const float*)d_in[19];
    const int* s_idx = conn;
    const int* o_idx = conn + EE;

    char* ws = (char*)d_ws;
    size_t off = 0;
    auto alloc = [&](size_t bytes) {
        char* p = ws + off;
        off += (bytes + 255) & ~(size_t)255;
        return p;
    };
    ushort* instB = (ushort*)alloc((size_t)NN * DD * 2);
    ushort* phraB = (ushort*)alloc((size_t)PP * DD * 2);
    ushort* WiT   = (ushort*)alloc((size_t)G4 * DD * 2);
    ushort* WpT   = (ushort*)alloc((size_t)G4 * DD * 2);
    ushort* iw1T  = (ushort*)alloc((size_t)DD * DD * 2);
    ushort* iw2T  = (ushort*)alloc((size_t)DD * DD * 2);
    ushort* pw1T  = (ushort*)alloc((size_t)DD * DD * 2);
    ushort* pw2T  = (ushort*)alloc((size_t)DD * DD * 2);
    float* biascat = (float*)alloc(G4 * 4);
    ushort* TiB   = (ushort*)alloc((size_t)NN * G4 * 2);
    ushort* TpB   = (ushort*)alloc((size_t)PP * G4 * 2);
    int* cntBlock = (int*)alloc((size_t)NCNT * 4);
    int* cntS = cntBlock;      int* cntO = cntS + NN;  int* cntC = cntO + NN;
    int* curS = cntC + PP;     int* curO = curS + NN;  int* curC = curO + NN;
    int* startS = (int*)alloc((NN + 1) * 4);
    int* startO = (int*)alloc((NN + 1) * 4);
    int* startC = (int*)alloc((PP + 1) * 4);
    int2* pkS   = (int2*)alloc((size_t)EE * 8);
    int2* pkO   = (int2*)alloc((size_t)EE * 8);
    int4* pkC   = (int4*)alloc((size_t)EE * 16);
    ushort* imsgB = (ushort*)alloc((size_t)NN * DD * 2);
    ushort* pmsgB = (ushort*)alloc((size_t)PP * DD * 2);

    float* inst_out = (float*)d_out;
    float* phra_out = inst_out + (size_t)NN * DD;

    // Fused prep: counter zeroing + bf16 casts + weight pack/transpose
    prep_kernel<<<NB_ZERO + NB_F2B + NB_GW + NB_BIAS + NB_WT, 256, 0, stream>>>(
        cntBlock, inst_feat, phra_feat, instB, phraB,
        psW, poW, opW, spW, psB, poB, opB, spB, WiT, WpT, biascat,
        iw1W, iw2W, pw1W, pw2W, iw1T, iw2T, pw1T, pw2T);

    // CSR build (scatter fused into gate_kernel atomics)
    hist_kernel<<<EE / 256, 256, 0, stream>>>(s_idx, o_idx, clu, cntS, cntO, cntC);
    scan3_kernel<<<3, 1024, 0, stream>>>(cntS, cntO, cntC, startS, startO, startC);

    // Gate tables (bf16 MFMA, bias folded into Tp; 2-buffer pipeline)
    mfma_tables_kernel<<<dim3((NN + PP) / 128, G4 / 64), 256, 0, stream>>>(
        instB, WiT, phraB, WpT, biascat, TiB, TpB);

    // Gates -> packed CSR entries (one wave/edge, fast-rcp sigmoid)
    gate_kernel<<<(EE * 64) / 256, 256, 0, stream>>>(
        s_idx, o_idx, clu, startS, startO, startC, curS, curO, curC,
        TiB, TpB, pkS, pkO, pkC);

    // Segment means (quartered, XCD-pinned, LDS-staged zero-pad pk pipeline)
    seg_kernel<<<(NN / 2 + PP / 2) * 4, 256, 0, stream>>>(
        phraB, instB, pkS, startS, pkO, startO, pkC, startC, imsgB, pmsgB);

    // Fused refine (128x64 tiles, 768 blocks, 2-buffer counted-vmcnt pipeline)
    mfma_refine_kernel<<<dim3((NN + PP) / 128, DD / 64), 256, 0, stream>>>(
        imsgB, instB, iw1T, iw2T, iw1B, iw2B, inst_out,
        pmsgB, phraB, pw1T, pw2T, pw1B, pw2B, phra_out);
}

// Round 17
// 138.542 us; speedup vs baseline: 1.4313x; 1.0091x over previous
//
#include <hip/hip_runtime.h>
#include <math.h>

// Problem constants (fixed by the reference)
constexpr int NN  = 4096;   // instances
constexpr int PP  = 2048;   // phrases
constexpr int EE  = 65536;  // edges
constexpr int DD  = 1024;   // feature dim
constexpr int OUTF = 128;   // gate MLP out dim
constexpr int G4  = 512;    // 4 gates * 128

typedef __attribute__((ext_vector_type(8))) short short8v;
typedef __attribute__((ext_vector_type(4))) float f32x4;

// sigmoid(relu(z)) with fast rcp (v_rcp_f32, ~1 ulp; bf16 rounding dominates).
__device__ __forceinline__ float sigmoid_relu(float z) {
    z = fmaxf(z, 0.0f);
    return __builtin_amdgcn_rcpf(1.0f + __expf(-z));
}
__device__ __forceinline__ float b2f(ushort u) {
    return __uint_as_float(((unsigned int)u) << 16);
}
__device__ __forceinline__ ushort f2b(float f) {  // RNE
    unsigned int x = __float_as_uint(f);
    return (ushort)((x + 0x7fffu + ((x >> 16) & 1u)) >> 16);
}
__device__ __forceinline__ unsigned int pack2(float a, float b) {
    return (unsigned int)f2b(a) | ((unsigned int)f2b(b) << 16);
}
__device__ __forceinline__ float lo16(unsigned int u) { return __uint_as_float(u << 16); }
__device__ __forceinline__ float hi16(unsigned int u) { return __uint_as_float(u & 0xffff0000u); }
__device__ __forceinline__ float pairSig(unsigned int a, unsigned int b) {
    return sigmoid_relu(lo16(a) + lo16(b)) + sigmoid_relu(hi16(a) + hi16(b));
}

#define GLD16(gptr, lptr) \
    __builtin_amdgcn_global_load_lds((__attribute__((address_space(1))) const void*)(gptr), \
                                     (__attribute__((address_space(3))) void*)(lptr), 16, 0, 0)
// Counted-vmcnt pipeline primitives (T4): keep just-issued loads in flight.
#define ASM_VMCNT(n) asm volatile("s_waitcnt vmcnt(" #n ")" ::: "memory")
#define BARRIER() do { asm volatile("" ::: "memory"); \
                       __builtin_amdgcn_s_barrier();  \
                       asm volatile("" ::: "memory"); } while (0)

// ---------------------------------------------------------------------------
// Fused prep: counter zeroing, f32->bf16 features, gate-weight pack
// (R16 coalesced 64x64 tile transpose), bias, refine-weight transpose.
constexpr int NCNT    = 2 * (NN + NN + PP);        // 20480 ints (cnt + cur)
constexpr int NB_ZERO = NCNT / 256;                // 80
constexpr int NB_F2B  = (NN + PP) * DD / 4 / 256;  // 6144
constexpr int NB_GW   = 4 * 32 * 2;                // 256: 4 mats x 32 ktiles x 2 jtiles
constexpr int NB_BIAS = 2;
constexpr int NB_WT   = 4 * (DD / 64) * (DD / 64); // 1024

__global__ __launch_bounds__(256) void prep_kernel(
        int* __restrict__ cntBlock,
        const float* __restrict__ instF, const float* __restrict__ phraF,
        ushort* __restrict__ instB, ushort* __restrict__ phraB,
        const float* __restrict__ psW, const float* __restrict__ poW,
        const float* __restrict__ opW, const float* __restrict__ spW,
        const float* __restrict__ psB, const float* __restrict__ poB,
        const float* __restrict__ opB, const float* __restrict__ spB,
        ushort* __restrict__ WiT, ushort* __restrict__ WpT,
        float* __restrict__ biascat,
        const float* __restrict__ W0, const float* __restrict__ W1,
        const float* __restrict__ W2, const float* __restrict__ W3,
        ushort* __restrict__ T0, ushort* __restrict__ T1,
        ushort* __restrict__ T2, ushort* __restrict__ T3) {
    __shared__ float tile[64][65];
    int b = blockIdx.x, t = threadIdx.x;
    if (b < NB_ZERO) {
        cntBlock[b * 256 + t] = 0;
        return;
    }
    b -= NB_ZERO;
    if (b < NB_F2B) {
        int i = b * 256 + t;
        constexpr int na4 = NN * DD / 4;
        if (i < na4) {
            float4 v = ((const float4*)instF)[i];
            ushort4 u; u.x = f2b(v.x); u.y = f2b(v.y); u.z = f2b(v.z); u.w = f2b(v.w);
            ((ushort4*)instB)[i] = u;
        } else {
            int j = i - na4;
            float4 v = ((const float4*)phraF)[j];
            ushort4 u; u.x = f2b(v.x); u.y = f2b(v.y); u.z = f2b(v.z); u.w = f2b(v.w);
            ((ushort4*)phraB)[j] = u;
        }
        return;
    }
    b -= NB_F2B;
    if (b < NB_GW) {
        int m  = b >> 6;            // source matrix 0..3 (ps,po,op,sp)
        int rest = b & 63;
        int kt = rest >> 1;         // source row-tile 0..31
        int jt = rest & 1;          // col-tile 0..1
        const float* W = (m == 0) ? psW : (m == 1) ? poW : (m == 2) ? opW : spW;
        int r0 = kt * 64, j0 = jt * 64;
        int tx = t & 63, ty = t >> 6;
        #pragma unroll
        for (int i = 0; i < 64; i += 4)
            tile[ty + i][tx] = W[(size_t)(r0 + ty + i) * OUTF + j0 + tx];
        __syncthreads();
        bool top = (r0 < DD);
        int kbase = top ? r0 : r0 - DD;
        ushort* T = top ? ((m < 2) ? WpT : WiT) : ((m < 2) ? WiT : WpT);
        #pragma unroll
        for (int i = 0; i < 64; i += 4)
            T[(size_t)(m * OUTF + j0 + ty + i) * DD + kbase + tx] = f2b(tile[tx][ty + i]);
        return;
    }
    b -= NB_GW;
    if (b < NB_BIAS) {
        int idx = b * 256 + t;      // 0..511
        int gg = idx >> 7, jj = idx & 127;
        biascat[idx] = (gg == 0) ? psB[jj] : (gg == 1) ? poB[jj]
                     : (gg == 2) ? opB[jj] : spB[jj];
        return;
    }
    b -= NB_BIAS;
    int z = b >> 8, rest = b & 255;
    const float* W = (z == 0) ? W0 : (z == 1) ? W1 : (z == 2) ? W2 : W3;
    ushort*      T = (z == 0) ? T0 : (z == 1) ? T1 : (z == 2) ? T2 : T3;
    int k0 = (rest & 15) * 64, n0 = (rest >> 4) * 64;
    int tx = t & 63, ty = t >> 6;
    #pragma unroll
    for (int i = 0; i < 64; i += 4)
        tile[ty + i][tx] = W[(size_t)(k0 + ty + i) * DD + n0 + tx];
    __syncthreads();
    #pragma unroll
    for (int i = 0; i < 64; i += 4)
        T[(size_t)(n0 + ty + i) * DD + k0 + tx] = f2b(tile[tx][ty + i]);
}

// ---------------------------------------------------------------------------
// MFMA GEMM building blocks (R10 proven). A-tile 128 rows; B-tile BROWS rows.
// BK=64, XOR-swizzled linear LDS (rule 21).
template<int BROWS>
__device__ __forceinline__ void stage_tiles(const ushort* __restrict__ A,
                                            const ushort* __restrict__ BT,
                                            int bm, int bn, int k0,
                                            ushort* Asl, ushort* Bsl, int t) {
    #pragma unroll
    for (int r = 0; r < 4; r++) {
        int ch = r * 256 + t;
        int row = ch >> 3;
        int sw = ((ch & 7) ^ (row & 7)) << 3;
        GLD16(A + (size_t)(bm + row) * DD + k0 + sw, &Asl[ch * 8]);
    }
    #pragma unroll
    for (int r = 0; r < BROWS / 32; r++) {
        int ch = r * 256 + t;
        int row = ch >> 3;
        int sw = ((ch & 7) ^ (row & 7)) << 3;
        GLD16(BT + (size_t)(bn + row) * DD + k0 + sw, &Bsl[ch * 8]);
    }
}

template<int NACC>
__device__ __forceinline__ void compute_tiles(const ushort* Asl, const ushort* Bsl,
                                              f32x4 (&acc)[4][NACC],
                                              int wr, int wc, int lr, int lk) {
    #pragma unroll
    for (int kk = 0; kk < 2; kk++) {
        int ch16 = kk * 4 + lk;
        short8v a[4], b[NACC];
        #pragma unroll
        for (int m = 0; m < 4; m++) {
            int ra = wr + m * 16 + lr;
            a[m] = *(const short8v*)&Asl[ra * 64 + ((ch16 ^ (ra & 7)) << 3)];
        }
        #pragma unroll
        for (int n = 0; n < NACC; n++) {
            int rb = wc + n * 16 + lr;
            b[n] = *(const short8v*)&Bsl[rb * 64 + ((ch16 ^ (rb & 7)) << 3)];
        }
        #pragma unroll
        for (int m = 0; m < 4; m++)
            #pragma unroll
            for (int n = 0; n < NACC; n++)
                acc[m][n] = __builtin_amdgcn_mfma_f32_16x16x32_bf16(a[m], b[n], acc[m][n], 0, 0, 0);
    }
}

// ---------------------------------------------------------------------------
// Gate tables, 128x64 tile, counted-vmcnt 2-buffer pipeline (R10 proven).
__global__ __launch_bounds__(256) void mfma_tables_kernel(
        const ushort* __restrict__ instB, const ushort* __restrict__ WiT,
        const ushort* __restrict__ phraB, const ushort* __restrict__ WpT,
        const float* __restrict__ biascat,
        ushort* __restrict__ TiB, ushort* __restrict__ TpB) {
    __shared__ ushort Asl[2][128 * 64];
    __shared__ ushort Bsl[2][64 * 64];
    int bx = blockIdx.x;
    const ushort *A, *BT; ushort* C; const float* bias;
    if (bx < NN / 128) { A = instB; BT = WiT; C = TiB; bias = nullptr; }
    else { bx -= NN / 128; A = phraB; BT = WpT; C = TpB; bias = biascat; }
    int bm = bx * 128, bn = blockIdx.y * 64;
    int t = threadIdx.x;
    const int lane = t & 63, w = t >> 6;
    const int wr = (w >> 1) * 64, wc = (w & 1) * 32;
    const int lr = lane & 15, lk = lane >> 4;
    f32x4 acc[4][2] = {};

    int cur = 0;
    stage_tiles<64>(A, BT, bm, bn, 0, Asl[0], Bsl[0], t);
    for (int k0 = 0; k0 < DD; k0 += 64) {
        int nxt = cur ^ 1;
        if (k0 + 64 < DD) {
            stage_tiles<64>(A, BT, bm, bn, k0 + 64, Asl[nxt], Bsl[nxt], t);
            ASM_VMCNT(6);
        } else {
            ASM_VMCNT(0);
        }
        BARRIER();
        compute_tiles<2>(Asl[cur], Bsl[cur], acc, wr, wc, lr, lk);
        BARRIER();
        cur = nxt;
    }
    #pragma unroll
    for (int m = 0; m < 4; m++) {
        int row = bm + wr + m * 16 + lk * 4;
        #pragma unroll
        for (int n = 0; n < 2; n++) {
            int col = bn + wc + n * 16 + lr;
            float bv = bias ? bias[col] : 0.f;
            #pragma unroll
            for (int r = 0; r < 4; r++)
                C[(size_t)(row + r) * G4 + col] = f2b(acc[m][n][r] + bv);
        }
    }
}

// ---------------------------------------------------------------------------
// Fused refine: out = msg + relu(msg@W1+b1) + relu(feat@W2+b2).
// 128x64 tile (768 blocks), continuous counted-vmcnt pipeline (R10 proven).
__global__ __launch_bounds__(256) void mfma_refine_kernel(
        const ushort* __restrict__ imsgB, const ushort* __restrict__ instB,
        const ushort* __restrict__ iw1T, const ushort* __restrict__ iw2T,
        const float* __restrict__ ib1, const float* __restrict__ ib2,
        float* __restrict__ iout,
        const ushort* __restrict__ pmsgB, const ushort* __restrict__ phraB,
        const ushort* __restrict__ pw1T, const ushort* __restrict__ pw2T,
        const float* __restrict__ pb1, const float* __restrict__ pb2,
        float* __restrict__ pout) {
    __shared__ ushort Asl[2][128 * 64];
    __shared__ ushort Bsl[2][64 * 64];
    int bx = blockIdx.x;
    const ushort *Am, *Af, *W1, *W2; const float *b1, *b2; float* out;
    if (bx < NN / 128) {
        Am = imsgB; Af = instB; W1 = iw1T; W2 = iw2T; b1 = ib1; b2 = ib2; out = iout;
    } else {
        bx -= NN / 128;
        Am = pmsgB; Af = phraB; W1 = pw1T; W2 = pw2T; b1 = pb1; b2 = pb2; out = pout;
    }
    int bm = bx * 128, bn = blockIdx.y * 64;
    int t = threadIdx.x;
    const int lane = t & 63, w = t >> 6;
    const int wr = (w >> 1) * 64, wc = (w & 1) * 32;
    const int lr = lane & 15, lk = lane >> 4;
    f32x4 acc1[4][2] = {};
    f32x4 acc2[4][2] = {};

    int cur = 0;
    stage_tiles<64>(Am, W1, bm, bn, 0, Asl[0], Bsl[0], t);
    auto run = [&](const ushort* A, const ushort* B, f32x4 (&acc)[4][2],
                   const ushort* An, const ushort* Bn) {
        for (int k0 = 0; k0 < DD; k0 += 64) {
            int nxt = cur ^ 1;
            if (k0 + 64 < DD) {
                stage_tiles<64>(A, B, bm, bn, k0 + 64, Asl[nxt], Bsl[nxt], t);
                ASM_VMCNT(6);
            } else if (An) {
                stage_tiles<64>(An, Bn, bm, bn, 0, Asl[nxt], Bsl[nxt], t);
                ASM_VMCNT(6);
            } else {
                ASM_VMCNT(0);
            }
            BARRIER();
            compute_tiles<2>(Asl[cur], Bsl[cur], acc, wr, wc, lr, lk);
            BARRIER();
            cur = nxt;
        }
    };
    run(Am, W1, acc1, Af, W2);
    run(Af, W2, acc2, nullptr, nullptr);

    #pragma unroll
    for (int m = 0; m < 4; m++) {
        int row = bm + wr + m * 16 + lk * 4;
        #pragma unroll
        for (int n = 0; n < 2; n++) {
            int col = bn + wc + n * 16 + lr;
            float vb1 = b1[col], vb2 = b2[col];
            #pragma unroll
            for (int r = 0; r < 4; r++) {
                float v = b2f(Am[(size_t)(row + r) * DD + col])
                        + fmaxf(acc1[m][n][r] + vb1, 0.f)
                        + fmaxf(acc2[m][n][r] + vb2, 0.f);
                out[(size_t)(row + r) * DD + col] = v;
            }
        }
    }
}

// ---------------------------------------------------------------------------
// Counting sort: histogram + scan (scatter fused into gate_kernel atomics).
__global__ void hist_kernel(const int* __restrict__ s_idx, const int* __restrict__ o_idx,
                            const int* __restrict__ c_idx,
                            int* cntS, int* cntO, int* cntC) {
    int e = blockIdx.x * blockDim.x + threadIdx.x;
    if (e >= EE) return;
    atomicAdd(&cntS[s_idx[e]], 1);
    atomicAdd(&cntO[o_idx[e]], 1);
    atomicAdd(&cntC[c_idx[e]], 1);
}

__global__ __launch_bounds__(1024) void scan3_kernel(
        const int* __restrict__ cntS, const int* __restrict__ cntO,
        const int* __restrict__ cntC,
        int* __restrict__ startS, int* __restrict__ startO, int* __restrict__ startC) {
    const int* cnt; int* start; int n;
    if (blockIdx.x == 0)      { cnt = cntS; start = startS; n = NN; }
    else if (blockIdx.x == 1) { cnt = cntO; start = startO; n = NN; }
    else                      { cnt = cntC; start = startC; n = PP; }
    __shared__ int sh[1024];
    int t = threadIdx.x;
    int per = n >> 10;
    int base = t * per;
    int s = 0;
    for (int i = 0; i < per; i++) s += cnt[base + i];
    sh[t] = s;
    __syncthreads();
    for (int off = 1; off < 1024; off <<= 1) {
        int v = (t >= off) ? sh[t - off] : 0;
        __syncthreads();
        sh[t] += v;
        __syncthreads();
    }
    int ex = (t == 0) ? 0 : sh[t - 1];
    for (int i = 0; i < per; i++) { start[base + i] = ex; ex += cnt[base + i]; }
    if (t == 1023) start[n] = ex;
}

// ---------------------------------------------------------------------------
// Per-edge gates (R10 structure + R13 fast-rcp sigmoid, both proven).
__global__ __launch_bounds__(256) void gate_kernel(
        const int* __restrict__ s_idx, const int* __restrict__ o_idx,
        const int* __restrict__ c_idx,
        const int* __restrict__ startS, const int* __restrict__ startO,
        const int* __restrict__ startC,
        int* __restrict__ curS, int* __restrict__ curO, int* __restrict__ curC,
        const ushort* __restrict__ Ti, const ushort* __restrict__ Tp,
        int2* __restrict__ pkS, int2* __restrict__ pkO, int4* __restrict__ pkC) {
    int gid = blockIdx.x * 256 + threadIdx.x;
    int e = gid >> 6, lane = gid & 63;
    if (e >= EE) return;
    int s = s_idx[e], o = o_idx[e], c = c_idx[e];
    const unsigned int* tpc = (const unsigned int*)(Tp + (size_t)c * G4);
    const unsigned int* tis = (const unsigned int*)(Ti + (size_t)s * G4);
    const unsigned int* tio = (const unsigned int*)(Ti + (size_t)o * G4);
    float s0 = pairSig(tpc[lane],       tis[lane]);
    float s1 = pairSig(tpc[64 + lane],  tio[64 + lane]);
    float s2 = pairSig(tpc[128 + lane], tio[128 + lane]);
    float s3 = pairSig(tpc[192 + lane], tis[192 + lane]);
    #pragma unroll
    for (int off = 32; off; off >>= 1) {
        s0 += __shfl_xor(s0, off);
        s1 += __shfl_xor(s1, off);
        s2 += __shfl_xor(s2, off);
        s3 += __shfl_xor(s3, off);
    }
    if (lane == 0) {
        const float inv = 1.0f / 128.0f;
        int ps = startS[s] + atomicAdd(&curS[s], 1);
        int po = startO[o] + atomicAdd(&curO[o], 1);
        int pc = startC[c] + atomicAdd(&curC[c], 1);
        pkS[ps] = make_int2(c, __float_as_int(s0 * inv));
        pkO[po] = make_int2(c, __float_as_int(s1 * inv));
        pkC[pc] = make_int4(o, s, __float_as_int(s2 * inv), __float_as_int(s3 * inv));
    }
}

// ---------------------------------------------------------------------------
// Segment means, D-quartered + XCD-pinned (R8), LDS-staged zero-pad pk (R15),
// phra halves split per wave (R15).  R17: 2-DEEP row prefetch -- entries j
// and j+2 both in flight (inst: 2 loads, phra: 4).  Zero-gate padding makes
// the preamble/tail guard-free (pad rows load row 0 with gate 0).
__device__ __forceinline__ void acc8(float* a, uint4 v, float g) {
    a[0] += g * lo16(v.x); a[1] += g * hi16(v.x);
    a[2] += g * lo16(v.y); a[3] += g * hi16(v.y);
    a[4] += g * lo16(v.z); a[5] += g * hi16(v.z);
    a[6] += g * lo16(v.w); a[7] += g * hi16(v.w);
}

__global__ __launch_bounds__(256) void seg_kernel(
        const ushort* __restrict__ phraB, const ushort* __restrict__ instB,
        const int2* __restrict__ pkS, const int* __restrict__ startS,
        const int2* __restrict__ pkO, const int* __restrict__ startO,
        const int4* __restrict__ pkC, const int* __restrict__ startC,
        ushort* __restrict__ imsgB, ushort* __restrict__ pmsgB) {
    __shared__ float lds[4][32 * 9];
    __shared__ int4 pkLds[4][64];          // 1 KB per wave
    int bid = blockIdx.x;
    int x = bid & 7;
    int q = x >> 1;
    int sub = ((bid >> 3) << 1) + (x & 1);
    int qoff = q * 256;
    int w = threadIdx.x >> 6, lane = threadIdx.x & 63;
    int half = lane >> 5, l32 = lane & 31;
    float a[8];
    #pragma unroll
    for (int k = 0; k < 8; k++) a[k] = 0.f;
    bool instSide = sub < NN / 2;
    int lenScale;
    ushort* msgB;
    int base2;
    if (instSide) {
        int node = sub * 2 + (w >> 1);
        const int2* pk_list = (w & 1) ? pkO : pkS;
        const int*  start   = (w & 1) ? startO : startS;
        int b = start[node], e = start[node + 1];
        lenScale = e - b;
        int2* myPk = (int2*)&pkLds[w][0];
        for (int base = b; base < e; base += 64) {
            int n = min(64, e - base);
            int2 pkv = (lane < n) ? pk_list[base + lane] : make_int2(0, 0);
            myPk[lane] = pkv;
            int nst = (n + 1) & ~1;
            // 2-deep pipeline: entries (0,2)+half in flight; pads are no-ops.
            int2 pe0 = myPk[half];
            int2 pe1 = myPk[2 + half];
            uint4 v0 = *(const uint4*)(phraB + (size_t)pe0.x * DD + qoff + l32 * 8);
            uint4 v1 = *(const uint4*)(phraB + (size_t)pe1.x * DD + qoff + l32 * 8);
            for (int j = 4; j < nst; j += 2) {
                int2 pen = myPk[j + half];
                uint4 vn = *(const uint4*)(phraB + (size_t)pen.x * DD + qoff + l32 * 8);
                acc8(a, v0, __int_as_float(pe0.y));
                pe0 = pe1; v0 = v1;
                pe1 = pen; v1 = vn;
            }
            acc8(a, v0, __int_as_float(pe0.y));
            acc8(a, v1, __int_as_float(pe1.y));   // pad-safe (gate 0 if nst<=2)
        }
        msgB = imsgB; base2 = sub * 2;
    } else {
        int pbx = sub - NN / 2;
        int p = pbx * 2 + (w >> 1);
        int cb = startC[p], ce = startC[p + 1];
        lenScale = ce - cb;
        int mid = cb + ((ce - cb) >> 1);
        int mb = (w & 1) ? mid : cb;       // contiguous halves per wave
        int me = (w & 1) ? ce : mid;
        int4* myPk = &pkLds[w][0];
        for (int base = mb; base < me; base += 64) {
            int n = min(64, me - base);
            int4 pkv = (lane < n) ? pkC[base + lane] : make_int4(0, 0, 0, 0);
            myPk[lane] = pkv;
            int nst = (n + 1) & ~1;
            int4 pe0 = myPk[half];
            int4 pe1 = myPk[2 + half];
            uint4 vo0 = *(const uint4*)(instB + (size_t)pe0.x * DD + qoff + l32 * 8);
            uint4 vs0 = *(const uint4*)(instB + (size_t)pe0.y * DD + qoff + l32 * 8);
            uint4 vo1 = *(const uint4*)(instB + (size_t)pe1.x * DD + qoff + l32 * 8);
            uint4 vs1 = *(const uint4*)(instB + (size_t)pe1.y * DD + qoff + l32 * 8);
            for (int j = 4; j < nst; j += 2) {
                int4 pen = myPk[j + half];
                uint4 vno = *(const uint4*)(instB + (size_t)pen.x * DD + qoff + l32 * 8);
                uint4 vns = *(const uint4*)(instB + (size_t)pen.y * DD + qoff + l32 * 8);
                acc8(a, vo0, __int_as_float(pe0.z));
                acc8(a, vs0, __int_as_float(pe0.w));
                pe0 = pe1; vo0 = vo1; vs0 = vs1;
                pe1 = pen; vo1 = vno; vs1 = vns;
            }
            acc8(a, vo0, __int_as_float(pe0.z));
            acc8(a, vs0, __int_as_float(pe0.w));
            acc8(a, vo1, __int_as_float(pe1.z));  // pad-safe
            acc8(a, vs1, __int_as_float(pe1.w));
        }
        msgB = pmsgB; base2 = pbx * 2;
    }
    // combine lane halves (entries j and j+1 partial sums share dims)
    #pragma unroll
    for (int k = 0; k < 8; k++) a[k] += __shfl_xor(a[k], 32);
    float scale = 0.5f / (float)max(lenScale, 1);
    if (half == 0) {
        #pragma unroll
        for (int k = 0; k < 8; k++) lds[w][l32 * 9 + k] = a[k] * scale;
    }
    __syncthreads();
    if (threadIdx.x < 64) {
        int nodeSel = threadIdx.x >> 5;
        int l = threadIdx.x & 31;
        int w0 = nodeSel * 2;
        float s0 = lds[w0][l * 9 + 0] + lds[w0 + 1][l * 9 + 0];
        float s1 = lds[w0][l * 9 + 1] + lds[w0 + 1][l * 9 + 1];
        float s2 = lds[w0][l * 9 + 2] + lds[w0 + 1][l * 9 + 2];
        float s3 = lds[w0][l * 9 + 3] + lds[w0 + 1][l * 9 + 3];
        float s4 = lds[w0][l * 9 + 4] + lds[w0 + 1][l * 9 + 4];
        float s5 = lds[w0][l * 9 + 5] + lds[w0 + 1][l * 9 + 5];
        float s6 = lds[w0][l * 9 + 6] + lds[w0 + 1][l * 9 + 6];
        float s7 = lds[w0][l * 9 + 7] + lds[w0 + 1][l * 9 + 7];
        uint4 o;
        o.x = pack2(s0, s1);
        o.y = pack2(s2, s3);
        o.z = pack2(s4, s5);
        o.w = pack2(s6, s7);
        *(uint4*)&msgB[(size_t)(base2 + nodeSel) * DD + qoff + l * 8] = o;
    }
}

// ---------------------------------------------------------------------------
extern "C" void kernel_launch(void* const* d_in, const int* in_sizes, int n_in,
                              void* d_out, int out_size, void* d_ws, size_t ws_size,
                              hipStream_t stream) {
    (void)in_sizes; (void)n_in; (void)out_size; (void)ws_size;
    const float* inst_feat = (const float*)d_in[0];
    const float* phra_feat = (const float*)d_in[1];
    const int*   conn      = (const int*)d_in[2];
    const int*   clu       = (const int*)d_in[3];
    const float* psW = (const float*)d_in[4];  const float* psB = (const float*)d_in[5];
    const float* poW = (const float*)d_in[6];  const float* poB = (const float*)d_in[7];
    const float* opW = (const float*)d_in[8];  const float* opB = (const float*)d_in[9];
    const float* spW = (const float*)d_in[10]; const float* spB = (const float*)d_in[11];
    const float* iw1W = (const float*)d_in[12]; const float* iw1B = (const float*)d_in[13];
    const float* iw2W = (const float*)d_in[14]; const float* iw2B = (const float*)d_in[15];
    const float* pw1W = (const float*)d_in[16]; const float* pw1B = (const float*)d_in[17];
    const float* pw2W = (const float*)d_in[18]; const float* pw2B = (const float*)d_in[19];
    const int* s_idx = conn;
    const int* o_idx = conn + EE;

    char* ws = (char*)d_ws;
    size_t off = 0;
    auto alloc = [&](size_t bytes) {
        char* p = ws + off;
        off += (bytes + 255) & ~(size_t)255;
        return p;
    };
    ushort* instB = (ushort*)alloc((size_t)NN * DD * 2);
    ushort* phraB = (ushort*)alloc((size_t)PP * DD * 2);
    ushort* WiT   = (ushort*)alloc((size_t)G4 * DD * 2);
    ushort* WpT   = (ushort*)alloc((size_t)G4 * DD * 2);
    ushort* iw1T  = (ushort*)alloc((size_t)DD * DD * 2);
    ushort* iw2T  = (ushort*)alloc((size_t)DD * DD * 2);
    ushort* pw1T  = (ushort*)alloc((size_t)DD * DD * 2);
    ushort* pw2T  = (ushort*)alloc((size_t)DD * DD * 2);
    float* biascat = (float*)alloc(G4 * 4);
    ushort* TiB   = (ushort*)alloc((size_t)NN * G4 * 2);
    ushort* TpB   = (ushort*)alloc((size_t)PP * G4 * 2);
    int* cntBlock = (int*)alloc((size_t)NCNT * 4);
    int* cntS = cntBlock;      int* cntO = cntS + NN;  int* cntC = cntO + NN;
    int* curS = cntC + PP;     int* curO = curS + NN;  int* curC = curO + NN;
    int* startS = (int*)alloc((NN + 1) * 4);
    int* startO = (int*)alloc((NN + 1) * 4);
    int* startC = (int*)alloc((PP + 1) * 4);
    int2* pkS   = (int2*)alloc((size_t)EE * 8);
    int2* pkO   = (int2*)alloc((size_t)EE * 8);
    int4* pkC   = (int4*)alloc((size_t)EE * 16);
    ushort* imsgB = (ushort*)alloc((size_t)NN * DD * 2);
    ushort* pmsgB = (ushort*)alloc((size_t)PP * DD * 2);

    float* inst_out = (float*)d_out;
    float* phra_out = inst_out + (size_t)NN * DD;

    // Fused prep: counter zeroing + bf16 casts + weight pack/transpose
    prep_kernel<<<NB_ZERO + NB_F2B + NB_GW + NB_BIAS + NB_WT, 256, 0, stream>>>(
        cntBlock, inst_feat, phra_feat, instB, phraB,
        psW, poW, opW, spW, psB, poB, opB, spB, WiT, WpT, biascat,
        iw1W, iw2W, pw1W, pw2W, iw1T, iw2T, pw1T, pw2T);

    // CSR build (scatter fused into gate_kernel atomics)
    hist_kernel<<<EE / 256, 256, 0, stream>>>(s_idx, o_idx, clu, cntS, cntO, cntC);
    scan3_kernel<<<3, 1024, 0, stream>>>(cntS, cntO, cntC, startS, startO, startC);

    // Gate tables (bf16 MFMA, bias folded into Tp; 2-buffer pipeline)
    mfma_tables_kernel<<<dim3((NN + PP) / 128, G4 / 64), 256, 0, stream>>>(
        instB, WiT, phraB, WpT, biascat, TiB, TpB);

    // Gates -> packed CSR entries (one wave/edge, fast-rcp sigmoid)
    gate_kernel<<<(EE * 64) / 256, 256, 0, stream>>>(
        s_idx, o_idx, clu, startS, startO, startC, curS, curO, curC,
        TiB, TpB, pkS, pkO, pkC);

    // Segment means (quartered, XCD-pinned, LDS-staged, 2-deep prefetch)
    seg_kernel<<<(NN / 2 + PP / 2) * 4, 256, 0, stream>>>(
        phraB, instB, pkS, startS, pkO, startO, pkC, startC, imsgB, pmsgB);

    // Fused refine (128x64 tiles, 768 blocks, 2-buffer counted-vmcnt pipeline)
    mfma_refine_kernel<<<dim3((NN + PP) / 128, DD / 64), 256, 0, stream>>>(
        imsgB, instB, iw1T, iw2T, iw1B, iw2B, inst_out,
        pmsgB, phraB, pw1T, pw2T, pw1B, pw2B, phra_out);
}

// Round 18
// 135.064 us; speedup vs baseline: 1.4682x; 1.0258x over previous
//
#include <hip/hip_runtime.h>
#include <math.h>

// Problem constants (fixed by the reference)
constexpr int NN  = 4096;   // instances
constexpr int PP  = 2048;   // phrases
constexpr int EE  = 65536;  // edges
constexpr int DD  = 1024;   // feature dim
constexpr int OUTF = 128;   // gate MLP out dim
constexpr int G4  = 512;    // 4 gates * 128

typedef __attribute__((ext_vector_type(8))) short short8v;
typedef __attribute__((ext_vector_type(4))) float f32x4;

// sigmoid(relu(z)) with fast rcp (v_rcp_f32, ~1 ulp; bf16 rounding dominates).
__device__ __forceinline__ float sigmoid_relu(float z) {
    z = fmaxf(z, 0.0f);
    return __builtin_amdgcn_rcpf(1.0f + __expf(-z));
}
__device__ __forceinline__ float b2f(ushort u) {
    return __uint_as_float(((unsigned int)u) << 16);
}
__device__ __forceinline__ ushort f2b(float f) {  // RNE
    unsigned int x = __float_as_uint(f);
    return (ushort)((x + 0x7fffu + ((x >> 16) & 1u)) >> 16);
}
__device__ __forceinline__ unsigned int pack2(float a, float b) {
    return (unsigned int)f2b(a) | ((unsigned int)f2b(b) << 16);
}
__device__ __forceinline__ float lo16(unsigned int u) { return __uint_as_float(u << 16); }
__device__ __forceinline__ float hi16(unsigned int u) { return __uint_as_float(u & 0xffff0000u); }
__device__ __forceinline__ float pairSig(unsigned int a, unsigned int b) {
    return sigmoid_relu(lo16(a) + lo16(b)) + sigmoid_relu(hi16(a) + hi16(b));
}

#define GLD16(gptr, lptr) \
    __builtin_amdgcn_global_load_lds((__attribute__((address_space(1))) const void*)(gptr), \
                                     (__attribute__((address_space(3))) void*)(lptr), 16, 0, 0)
// Counted-vmcnt pipeline primitives (T4): keep just-issued loads in flight.
#define ASM_VMCNT(n) asm volatile("s_waitcnt vmcnt(" #n ")" ::: "memory")
#define BARRIER() do { asm volatile("" ::: "memory"); \
                       __builtin_amdgcn_s_barrier();  \
                       asm volatile("" ::: "memory"); } while (0)

// ---------------------------------------------------------------------------
// Fused prep: counter zeroing, f32->bf16 features, gate-weight pack
// (R16 coalesced 64x64 tile transpose), bias, refine-weight transpose.
constexpr int NCNT    = 2 * (NN + NN + PP);        // 20480 ints (cnt + cur)
constexpr int NB_ZERO = NCNT / 256;                // 80
constexpr int NB_F2B  = (NN + PP) * DD / 4 / 256;  // 6144
constexpr int NB_GW   = 4 * 32 * 2;                // 256: 4 mats x 32 ktiles x 2 jtiles
constexpr int NB_BIAS = 2;
constexpr int NB_WT   = 4 * (DD / 64) * (DD / 64); // 1024

__global__ __launch_bounds__(256) void prep_kernel(
        int* __restrict__ cntBlock,
        const float* __restrict__ instF, const float* __restrict__ phraF,
        ushort* __restrict__ instB, ushort* __restrict__ phraB,
        const float* __restrict__ psW, const float* __restrict__ poW,
        const float* __restrict__ opW, const float* __restrict__ spW,
        const float* __restrict__ psB, const float* __restrict__ poB,
        const float* __restrict__ opB, const float* __restrict__ spB,
        ushort* __restrict__ WiT, ushort* __restrict__ WpT,
        float* __restrict__ biascat,
        const float* __restrict__ W0, const float* __restrict__ W1,
        const float* __restrict__ W2, const float* __restrict__ W3,
        ushort* __restrict__ T0, ushort* __restrict__ T1,
        ushort* __restrict__ T2, ushort* __restrict__ T3) {
    __shared__ float tile[64][65];
    int b = blockIdx.x, t = threadIdx.x;
    if (b < NB_ZERO) {
        cntBlock[b * 256 + t] = 0;
        return;
    }
    b -= NB_ZERO;
    if (b < NB_F2B) {
        int i = b * 256 + t;
        constexpr int na4 = NN * DD / 4;
        if (i < na4) {
            float4 v = ((const float4*)instF)[i];
            ushort4 u; u.x = f2b(v.x); u.y = f2b(v.y); u.z = f2b(v.z); u.w = f2b(v.w);
            ((ushort4*)instB)[i] = u;
        } else {
            int j = i - na4;
            float4 v = ((const float4*)phraF)[j];
            ushort4 u; u.x = f2b(v.x); u.y = f2b(v.y); u.z = f2b(v.z); u.w = f2b(v.w);
            ((ushort4*)phraB)[j] = u;
        }
        return;
    }
    b -= NB_F2B;
    if (b < NB_GW) {
        int m  = b >> 6;            // source matrix 0..3 (ps,po,op,sp)
        int rest = b & 63;
        int kt = rest >> 1;         // source row-tile 0..31
        int jt = rest & 1;          // col-tile 0..1
        const float* W = (m == 0) ? psW : (m == 1) ? poW : (m == 2) ? opW : spW;
        int r0 = kt * 64, j0 = jt * 64;
        int tx = t & 63, ty = t >> 6;
        #pragma unroll
        for (int i = 0; i < 64; i += 4)
            tile[ty + i][tx] = W[(size_t)(r0 + ty + i) * OUTF + j0 + tx];
        __syncthreads();
        bool top = (r0 < DD);
        int kbase = top ? r0 : r0 - DD;
        ushort* T = top ? ((m < 2) ? WpT : WiT) : ((m < 2) ? WiT : WpT);
        #pragma unroll
        for (int i = 0; i < 64; i += 4)
            T[(size_t)(m * OUTF + j0 + ty + i) * DD + kbase + tx] = f2b(tile[tx][ty + i]);
        return;
    }
    b -= NB_GW;
    if (b < NB_BIAS) {
        int idx = b * 256 + t;      // 0..511
        int gg = idx >> 7, jj = idx & 127;
        biascat[idx] = (gg == 0) ? psB[jj] : (gg == 1) ? poB[jj]
                     : (gg == 2) ? opB[jj] : spB[jj];
        return;
    }
    b -= NB_BIAS;
    int z = b >> 8, rest = b & 255;
    const float* W = (z == 0) ? W0 : (z == 1) ? W1 : (z == 2) ? W2 : W3;
    ushort*      T = (z == 0) ? T0 : (z == 1) ? T1 : (z == 2) ? T2 : T3;
    int k0 = (rest & 15) * 64, n0 = (rest >> 4) * 64;
    int tx = t & 63, ty = t >> 6;
    #pragma unroll
    for (int i = 0; i < 64; i += 4)
        tile[ty + i][tx] = W[(size_t)(k0 + ty + i) * DD + n0 + tx];
    __syncthreads();
    #pragma unroll
    for (int i = 0; i < 64; i += 4)
        T[(size_t)(n0 + ty + i) * DD + k0 + tx] = f2b(tile[tx][ty + i]);
}

// ---------------------------------------------------------------------------
// MFMA GEMM building blocks (R10 proven). A-tile 128 rows; B-tile BROWS rows.
// BK=64, XOR-swizzled linear LDS (rule 21).
template<int BROWS>
__device__ __forceinline__ void stage_tiles(const ushort* __restrict__ A,
                                            const ushort* __restrict__ BT,
                                            int bm, int bn, int k0,
                                            ushort* Asl, ushort* Bsl, int t) {
    #pragma unroll
    for (int r = 0; r < 4; r++) {
        int ch = r * 256 + t;
        int row = ch >> 3;
        int sw = ((ch & 7) ^ (row & 7)) << 3;
        GLD16(A + (size_t)(bm + row) * DD + k0 + sw, &Asl[ch * 8]);
    }
    #pragma unroll
    for (int r = 0; r < BROWS / 32; r++) {
        int ch = r * 256 + t;
        int row = ch >> 3;
        int sw = ((ch & 7) ^ (row & 7)) << 3;
        GLD16(BT + (size_t)(bn + row) * DD + k0 + sw, &Bsl[ch * 8]);
    }
}

template<int NACC>
__device__ __forceinline__ void compute_tiles(const ushort* Asl, const ushort* Bsl,
                                              f32x4 (&acc)[4][NACC],
                                              int wr, int wc, int lr, int lk) {
    #pragma unroll
    for (int kk = 0; kk < 2; kk++) {
        int ch16 = kk * 4 + lk;
        short8v a[4], b[NACC];
        #pragma unroll
        for (int m = 0; m < 4; m++) {
            int ra = wr + m * 16 + lr;
            a[m] = *(const short8v*)&Asl[ra * 64 + ((ch16 ^ (ra & 7)) << 3)];
        }
        #pragma unroll
        for (int n = 0; n < NACC; n++) {
            int rb = wc + n * 16 + lr;
            b[n] = *(const short8v*)&Bsl[rb * 64 + ((ch16 ^ (rb & 7)) << 3)];
        }
        #pragma unroll
        for (int m = 0; m < 4; m++)
            #pragma unroll
            for (int n = 0; n < NACC; n++)
                acc[m][n] = __builtin_amdgcn_mfma_f32_16x16x32_bf16(a[m], b[n], acc[m][n], 0, 0, 0);
    }
}

// ---------------------------------------------------------------------------
// Gate tables + HIST fused (R18): 1D grid; blocks [0,384) = 128x64 MFMA table
// tiles (lin%48 -> bx, lin/48 -> by, preserving the dispatch-order locality of
// the original 2D launch); blocks [384, 640) = edge histogram (atomic-bound,
// no dependency on table output -- co-schedules into the MFMA blocks' memory
// slack and removes one graph-node boundary).
constexpr int NB_TBL = ((NN + PP) / 128) * (G4 / 64);  // 384

__global__ __launch_bounds__(256) void mfma_tables_kernel(
        const ushort* __restrict__ instB, const ushort* __restrict__ WiT,
        const ushort* __restrict__ phraB, const ushort* __restrict__ WpT,
        const float* __restrict__ biascat,
        ushort* __restrict__ TiB, ushort* __restrict__ TpB,
        const int* __restrict__ s_idx, const int* __restrict__ o_idx,
        const int* __restrict__ c_idx,
        int* __restrict__ cntS, int* __restrict__ cntO, int* __restrict__ cntC) {
    __shared__ ushort Asl[2][128 * 64];
    __shared__ ushort Bsl[2][64 * 64];
    int lin = blockIdx.x;
    if (lin >= NB_TBL) {
        int e = (lin - NB_TBL) * 256 + threadIdx.x;
        if (e < EE) {
            atomicAdd(&cntS[s_idx[e]], 1);
            atomicAdd(&cntO[o_idx[e]], 1);
            atomicAdd(&cntC[c_idx[e]], 1);
        }
        return;
    }
    int bx = lin % ((NN + PP) / 128);
    int by = lin / ((NN + PP) / 128);
    const ushort *A, *BT; ushort* C; const float* bias;
    if (bx < NN / 128) { A = instB; BT = WiT; C = TiB; bias = nullptr; }
    else { bx -= NN / 128; A = phraB; BT = WpT; C = TpB; bias = biascat; }
    int bm = bx * 128, bn = by * 64;
    int t = threadIdx.x;
    const int lane = t & 63, w = t >> 6;
    const int wr = (w >> 1) * 64, wc = (w & 1) * 32;
    const int lr = lane & 15, lk = lane >> 4;
    f32x4 acc[4][2] = {};

    int cur = 0;
    stage_tiles<64>(A, BT, bm, bn, 0, Asl[0], Bsl[0], t);
    for (int k0 = 0; k0 < DD; k0 += 64) {
        int nxt = cur ^ 1;
        if (k0 + 64 < DD) {
            stage_tiles<64>(A, BT, bm, bn, k0 + 64, Asl[nxt], Bsl[nxt], t);
            ASM_VMCNT(6);
        } else {
            ASM_VMCNT(0);
        }
        BARRIER();
        compute_tiles<2>(Asl[cur], Bsl[cur], acc, wr, wc, lr, lk);
        BARRIER();
        cur = nxt;
    }
    #pragma unroll
    for (int m = 0; m < 4; m++) {
        int row = bm + wr + m * 16 + lk * 4;
        #pragma unroll
        for (int n = 0; n < 2; n++) {
            int col = bn + wc + n * 16 + lr;
            float bv = bias ? bias[col] : 0.f;
            #pragma unroll
            for (int r = 0; r < 4; r++)
                C[(size_t)(row + r) * G4 + col] = f2b(acc[m][n][r] + bv);
        }
    }
}

// ---------------------------------------------------------------------------
// Fused refine: out = msg + relu(msg@W1+b1) + relu(feat@W2+b2).
// 128x64 tile (768 blocks), continuous counted-vmcnt pipeline (R10 proven).
__global__ __launch_bounds__(256) void mfma_refine_kernel(
        const ushort* __restrict__ imsgB, const ushort* __restrict__ instB,
        const ushort* __restrict__ iw1T, const ushort* __restrict__ iw2T,
        const float* __restrict__ ib1, const float* __restrict__ ib2,
        float* __restrict__ iout,
        const ushort* __restrict__ pmsgB, const ushort* __restrict__ phraB,
        const ushort* __restrict__ pw1T, const ushort* __restrict__ pw2T,
        const float* __restrict__ pb1, const float* __restrict__ pb2,
        float* __restrict__ pout) {
    __shared__ ushort Asl[2][128 * 64];
    __shared__ ushort Bsl[2][64 * 64];
    int bx = blockIdx.x;
    const ushort *Am, *Af, *W1, *W2; const float *b1, *b2; float* out;
    if (bx < NN / 128) {
        Am = imsgB; Af = instB; W1 = iw1T; W2 = iw2T; b1 = ib1; b2 = ib2; out = iout;
    } else {
        bx -= NN / 128;
        Am = pmsgB; Af = phraB; W1 = pw1T; W2 = pw2T; b1 = pb1; b2 = pb2; out = pout;
    }
    int bm = bx * 128, bn = blockIdx.y * 64;
    int t = threadIdx.x;
    const int lane = t & 63, w = t >> 6;
    const int wr = (w >> 1) * 64, wc = (w & 1) * 32;
    const int lr = lane & 15, lk = lane >> 4;
    f32x4 acc1[4][2] = {};
    f32x4 acc2[4][2] = {};

    int cur = 0;
    stage_tiles<64>(Am, W1, bm, bn, 0, Asl[0], Bsl[0], t);
    auto run = [&](const ushort* A, const ushort* B, f32x4 (&acc)[4][2],
                   const ushort* An, const ushort* Bn) {
        for (int k0 = 0; k0 < DD; k0 += 64) {
            int nxt = cur ^ 1;
            if (k0 + 64 < DD) {
                stage_tiles<64>(A, B, bm, bn, k0 + 64, Asl[nxt], Bsl[nxt], t);
                ASM_VMCNT(6);
            } else if (An) {
                stage_tiles<64>(An, Bn, bm, bn, 0, Asl[nxt], Bsl[nxt], t);
                ASM_VMCNT(6);
            } else {
                ASM_VMCNT(0);
            }
            BARRIER();
            compute_tiles<2>(Asl[cur], Bsl[cur], acc, wr, wc, lr, lk);
            BARRIER();
            cur = nxt;
        }
    };
    run(Am, W1, acc1, Af, W2);
    run(Af, W2, acc2, nullptr, nullptr);

    #pragma unroll
    for (int m = 0; m < 4; m++) {
        int row = bm + wr + m * 16 + lk * 4;
        #pragma unroll
        for (int n = 0; n < 2; n++) {
            int col = bn + wc + n * 16 + lr;
            float vb1 = b1[col], vb2 = b2[col];
            #pragma unroll
            for (int r = 0; r < 4; r++) {
                float v = b2f(Am[(size_t)(row + r) * DD + col])
                        + fmaxf(acc1[m][n][r] + vb1, 0.f)
                        + fmaxf(acc2[m][n][r] + vb2, 0.f);
                out[(size_t)(row + r) * DD + col] = v;
            }
        }
    }
}

// ---------------------------------------------------------------------------
__global__ __launch_bounds__(1024) void scan3_kernel(
        const int* __restrict__ cntS, const int* __restrict__ cntO,
        const int* __restrict__ cntC,
        int* __restrict__ startS, int* __restrict__ startO, int* __restrict__ startC) {
    const int* cnt; int* start; int n;
    if (blockIdx.x == 0)      { cnt = cntS; start = startS; n = NN; }
    else if (blockIdx.x == 1) { cnt = cntO; start = startO; n = NN; }
    else                      { cnt = cntC; start = startC; n = PP; }
    __shared__ int sh[1024];
    int t = threadIdx.x;
    int per = n >> 10;
    int base = t * per;
    int s = 0;
    for (int i = 0; i < per; i++) s += cnt[base + i];
    sh[t] = s;
    __syncthreads();
    for (int off = 1; off < 1024; off <<= 1) {
        int v = (t >= off) ? sh[t - off] : 0;
        __syncthreads();
        sh[t] += v;
        __syncthreads();
    }
    int ex = (t == 0) ? 0 : sh[t - 1];
    for (int i = 0; i < per; i++) { start[base + i] = ex; ex += cnt[base + i]; }
    if (t == 1023) start[n] = ex;
}

// ---------------------------------------------------------------------------
// Per-edge gates (R10 structure + R13 fast-rcp sigmoid, both proven).
__global__ __launch_bounds__(256) void gate_kernel(
        const int* __restrict__ s_idx, const int* __restrict__ o_idx,
        const int* __restrict__ c_idx,
        const int* __restrict__ startS, const int* __restrict__ startO,
        const int* __restrict__ startC,
        int* __restrict__ curS, int* __restrict__ curO, int* __restrict__ curC,
        const ushort* __restrict__ Ti, const ushort* __restrict__ Tp,
        int2* __restrict__ pkS, int2* __restrict__ pkO, int4* __restrict__ pkC) {
    int gid = blockIdx.x * 256 + threadIdx.x;
    int e = gid >> 6, lane = gid & 63;
    if (e >= EE) return;
    int s = s_idx[e], o = o_idx[e], c = c_idx[e];
    const unsigned int* tpc = (const unsigned int*)(Tp + (size_t)c * G4);
    const unsigned int* tis = (const unsigned int*)(Ti + (size_t)s * G4);
    const unsigned int* tio = (const unsigned int*)(Ti + (size_t)o * G4);
    float s0 = pairSig(tpc[lane],       tis[lane]);
    float s1 = pairSig(tpc[64 + lane],  tio[64 + lane]);
    float s2 = pairSig(tpc[128 + lane], tio[128 + lane]);
    float s3 = pairSig(tpc[192 + lane], tis[192 + lane]);
    #pragma unroll
    for (int off = 32; off; off >>= 1) {
        s0 += __shfl_xor(s0, off);
        s1 += __shfl_xor(s1, off);
        s2 += __shfl_xor(s2, off);
        s3 += __shfl_xor(s3, off);
    }
    if (lane == 0) {
        const float inv = 1.0f / 128.0f;
        int ps = startS[s] + atomicAdd(&curS[s], 1);
        int po = startO[o] + atomicAdd(&curO[o], 1);
        int pc = startC[c] + atomicAdd(&curC[c], 1);
        pkS[ps] = make_int2(c, __float_as_int(s0 * inv));
        pkO[po] = make_int2(c, __float_as_int(s1 * inv));
        pkC[pc] = make_int4(o, s, __float_as_int(s2 * inv), __float_as_int(s3 * inv));
    }
}

// ---------------------------------------------------------------------------
// Segment means, D-quartered + XCD-pinned (R8), LDS-staged zero-pad pk (R15),
// phra halves split per wave (R15), 2-deep row prefetch (R17).
__device__ __forceinline__ void acc8(float* a, uint4 v, float g) {
    a[0] += g * lo16(v.x); a[1] += g * hi16(v.x);
    a[2] += g * lo16(v.y); a[3] += g * hi16(v.y);
    a[4] += g * lo16(v.z); a[5] += g * hi16(v.z);
    a[6] += g * lo16(v.w); a[7] += g * hi16(v.w);
}

__global__ __launch_bounds__(256) void seg_kernel(
        const ushort* __restrict__ phraB, const ushort* __restrict__ instB,
        const int2* __restrict__ pkS, const int* __restrict__ startS,
        const int2* __restrict__ pkO, const int* __restrict__ startO,
        const int4* __restrict__ pkC, const int* __restrict__ startC,
        ushort* __restrict__ imsgB, ushort* __restrict__ pmsgB) {
    __shared__ float lds[4][32 * 9];
    __shared__ int4 pkLds[4][64];          // 1 KB per wave
    int bid = blockIdx.x;
    int x = bid & 7;
    int q = x >> 1;
    int sub = ((bid >> 3) << 1) + (x & 1);
    int qoff = q * 256;
    int w = threadIdx.x >> 6, lane = threadIdx.x & 63;
    int half = lane >> 5, l32 = lane & 31;
    float a[8];
    #pragma unroll
    for (int k = 0; k < 8; k++) a[k] = 0.f;
    bool instSide = sub < NN / 2;
    int lenScale;
    ushort* msgB;
    int base2;
    if (instSide) {
        int node = sub * 2 + (w >> 1);
        const int2* pk_list = (w & 1) ? pkO : pkS;
        const int*  start   = (w & 1) ? startO : startS;
        int b = start[node], e = start[node + 1];
        lenScale = e - b;
        int2* myPk = (int2*)&pkLds[w][0];
        for (int base = b; base < e; base += 64) {
            int n = min(64, e - base);
            int2 pkv = (lane < n) ? pk_list[base + lane] : make_int2(0, 0);
            myPk[lane] = pkv;
            int nst = (n + 1) & ~1;
            int2 pe0 = myPk[half];
            int2 pe1 = myPk[2 + half];
            uint4 v0 = *(const uint4*)(phraB + (size_t)pe0.x * DD + qoff + l32 * 8);
            uint4 v1 = *(const uint4*)(phraB + (size_t)pe1.x * DD + qoff + l32 * 8);
            for (int j = 4; j < nst; j += 2) {
                int2 pen = myPk[j + half];
                uint4 vn = *(const uint4*)(phraB + (size_t)pen.x * DD + qoff + l32 * 8);
                acc8(a, v0, __int_as_float(pe0.y));
                pe0 = pe1; v0 = v1;
                pe1 = pen; v1 = vn;
            }
            acc8(a, v0, __int_as_float(pe0.y));
            acc8(a, v1, __int_as_float(pe1.y));   // pad-safe (gate 0 if nst<=2)
        }
        msgB = imsgB; base2 = sub * 2;
    } else {
        int pbx = sub - NN / 2;
        int p = pbx * 2 + (w >> 1);
        int cb = startC[p], ce = startC[p + 1];
        lenScale = ce - cb;
        int mid = cb + ((ce - cb) >> 1);
        int mb = (w & 1) ? mid : cb;       // contiguous halves per wave
        int me = (w & 1) ? ce : mid;
        int4* myPk = &pkLds[w][0];
        for (int base = mb; base < me; base += 64) {
            int n = min(64, me - base);
            int4 pkv = (lane < n) ? pkC[base + lane] : make_int4(0, 0, 0, 0);
            myPk[lane] = pkv;
            int nst = (n + 1) & ~1;
            int4 pe0 = myPk[half];
            int4 pe1 = myPk[2 + half];
            uint4 vo0 = *(const uint4*)(instB + (size_t)pe0.x * DD + qoff + l32 * 8);
            uint4 vs0 = *(const uint4*)(instB + (size_t)pe0.y * DD + qoff + l32 * 8);
            uint4 vo1 = *(const uint4*)(instB + (size_t)pe1.x * DD + qoff + l32 * 8);
            uint4 vs1 = *(const uint4*)(instB + (size_t)pe1.y * DD + qoff + l32 * 8);
            for (int j = 4; j < nst; j += 2) {
                int4 pen = myPk[j + half];
                uint4 vno = *(const uint4*)(instB + (size_t)pen.x * DD + qoff + l32 * 8);
                uint4 vns = *(const uint4*)(instB + (size_t)pen.y * DD + qoff + l32 * 8);
                acc8(a, vo0, __int_as_float(pe0.z));
                acc8(a, vs0, __int_as_float(pe0.w));
                pe0 = pe1; vo0 = vo1; vs0 = vs1;
                pe1 = pen; vo1 = vno; vs1 = vns;
            }
            acc8(a, vo0, __int_as_float(pe0.z));
            acc8(a, vs0, __int_as_float(pe0.w));
            acc8(a, vo1, __int_as_float(pe1.z));  // pad-safe
            acc8(a, vs1, __int_as_float(pe1.w));
        }
        msgB = pmsgB; base2 = pbx * 2;
    }
    // combine lane halves (entries j and j+1 partial sums share dims)
    #pragma unroll
    for (int k = 0; k < 8; k++) a[k] += __shfl_xor(a[k], 32);
    float scale = 0.5f / (float)max(lenScale, 1);
    if (half == 0) {
        #pragma unroll
        for (int k = 0; k < 8; k++) lds[w][l32 * 9 + k] = a[k] * scale;
    }
    __syncthreads();
    if (threadIdx.x < 64) {
        int nodeSel = threadIdx.x >> 5;
        int l = threadIdx.x & 31;
        int w0 = nodeSel * 2;
        float s0 = lds[w0][l * 9 + 0] + lds[w0 + 1][l * 9 + 0];
        float s1 = lds[w0][l * 9 + 1] + lds[w0 + 1][l * 9 + 1];
        float s2 = lds[w0][l * 9 + 2] + lds[w0 + 1][l * 9 + 2];
        float s3 = lds[w0][l * 9 + 3] + lds[w0 + 1][l * 9 + 3];
        float s4 = lds[w0][l * 9 + 4] + lds[w0 + 1][l * 9 + 4];
        float s5 = lds[w0][l * 9 + 5] + lds[w0 + 1][l * 9 + 5];
        float s6 = lds[w0][l * 9 + 6] + lds[w0 + 1][l * 9 + 6];
        float s7 = lds[w0][l * 9 + 7] + lds[w0 + 1][l * 9 + 7];
        uint4 o;
        o.x = pack2(s0, s1);
        o.y = pack2(s2, s3);
        o.z = pack2(s4, s5);
        o.w = pack2(s6, s7);
        *(uint4*)&msgB[(size_t)(base2 + nodeSel) * DD + qoff + l * 8] = o;
    }
}

// ---------------------------------------------------------------------------
extern "C" void kernel_launch(void* const* d_in, const int* in_sizes, int n_in,
                              void* d_out, int out_size, void* d_ws, size_t ws_size,
                              hipStream_t stream) {
    (void)in_sizes; (void)n_in; (void)out_size; (void)ws_size;
    const float* inst_feat = (const float*)d_in[0];
    const float* phra_feat = (const float*)d_in[1];
    const int*   conn      = (const int*)d_in[2];
    const int*   clu       = (const int*)d_in[3];
    const float* psW = (const float*)d_in[4];  const float* psB = (const float*)d_in[5];
    const float* poW = (const float*)d_in[6];  const float* poB = (const float*)d_in[7];
    const float* opW = (const float*)d_in[8];  const float* opB = (const float*)d_in[9];
    const float* spW = (const float*)d_in[10]; const float* spB = (const float*)d_in[11];
    const float* iw1W = (const float*)d_in[12]; const float* iw1B = (const float*)d_in[13];
    const float* iw2W = (const float*)d_in[14]; const float* iw2B = (const float*)d_in[15];
    const float* pw1W = (const float*)d_in[16]; const float* pw1B = (const float*)d_in[17];
    const float* pw2W = (const float*)d_in[18]; const float* pw2B = (const float*)d_in[19];
    const int* s_idx = conn;
    const int* o_idx = conn + EE;

    char* ws = (char*)d_ws;
    size_t off = 0;
    auto alloc = [&](size_t bytes) {
        char* p = ws + off;
        off += (bytes + 255) & ~(size_t)255;
        return p;
    };
    ushort* instB = (ushort*)alloc((size_t)NN * DD * 2);
    ushort* phraB = (ushort*)alloc((size_t)PP * DD * 2);
    ushort* WiT   = (ushort*)alloc((size_t)G4 * DD * 2);
    ushort* WpT   = (ushort*)alloc((size_t)G4 * DD * 2);
    ushort* iw1T  = (ushort*)alloc((size_t)DD * DD * 2);
    ushort* iw2T  = (ushort*)alloc((size_t)DD * DD * 2);
    ushort* pw1T  = (ushort*)alloc((size_t)DD * DD * 2);
    ushort* pw2T  = (ushort*)alloc((size_t)DD * DD * 2);
    float* biascat = (float*)alloc(G4 * 4);
    ushort* TiB   = (ushort*)alloc((size_t)NN * G4 * 2);
    ushort* TpB   = (ushort*)alloc((size_t)PP * G4 * 2);
    int* cntBlock = (int*)alloc((size_t)NCNT * 4);
    int* cntS = cntBlock;      int* cntO = cntS + NN;  int* cntC = cntO + NN;
    int* curS = cntC + PP;     int* curO = curS + NN;  int* curC = curO + NN;
    int* startS = (int*)alloc((NN + 1) * 4);
    int* startO = (int*)alloc((NN + 1) * 4);
    int* startC = (int*)alloc((PP + 1) * 4);
    int2* pkS   = (int2*)alloc((size_t)EE * 8);
    int2* pkO   = (int2*)alloc((size_t)EE * 8);
    int4* pkC   = (int4*)alloc((size_t)EE * 16);
    ushort* imsgB = (ushort*)alloc((size_t)NN * DD * 2);
    ushort* pmsgB = (ushort*)alloc((size_t)PP * DD * 2);

    float* inst_out = (float*)d_out;
    float* phra_out = inst_out + (size_t)NN * DD;

    // Fused prep: counter zeroing + bf16 casts + weight pack/transpose
    prep_kernel<<<NB_ZERO + NB_F2B + NB_GW + NB_BIAS + NB_WT, 256, 0, stream>>>(
        cntBlock, inst_feat, phra_feat, instB, phraB,
        psW, poW, opW, spW, psB, poB, opB, spB, WiT, WpT, biascat,
        iw1W, iw2W, pw1W, pw2W, iw1T, iw2T, pw1T, pw2T);

    // Gate tables + hist fused (cnt zeroed by prep; hist blocks co-scheduled)
    mfma_tables_kernel<<<NB_TBL + EE / 256, 256, 0, stream>>>(
        instB, WiT, phraB, WpT, biascat, TiB, TpB,
        s_idx, o_idx, clu, cntS, cntO, cntC);

    scan3_kernel<<<3, 1024, 0, stream>>>(cntS, cntO, cntC, startS, startO, startC);

    // Gates -> packed CSR entries (one wave/edge, fast-rcp sigmoid)
    gate_kernel<<<(EE * 64) / 256, 256, 0, stream>>>(
        s_idx, o_idx, clu, startS, startO, startC, curS, curO, curC,
        TiB, TpB, pkS, pkO, pkC);

    // Segment means (quartered, XCD-pinned, LDS-staged, 2-deep prefetch)
    seg_kernel<<<(NN / 2 + PP / 2) * 4, 256, 0, stream>>>(
        phraB, instB, pkS, startS, pkO, startO, pkC, startC, imsgB, pmsgB);

    // Fused refine (128x64 tiles, 768 blocks, 2-buffer counted-vmcnt pipeline)
    mfma_refine_kernel<<<dim3((NN + PP) / 128, DD / 64), 256, 0, stream>>>(
        imsgB, instB, iw1T, iw2T, iw1B, iw2B, inst_out,
        pmsgB, phraB, pw1T, pw2T, pw1B, pw2B, phra_out);
}